// Round 7
// baseline (5781.206 us; speedup 1.0000x reference)
//
#include <hip/hip_runtime.h>
#include <cstdint>
#include <cstddef>

// Problem constants (from reference)
#define NGg   128     // 2*B
#define Bb    64
#define Nn    48
#define Ee    192
#define Sdim  64
#define VNn   6144    // NGg*Nn
#define VEe   24576   // NGg*Ee
#define INV_TEMP 10.0f

typedef unsigned short u16;
typedef __attribute__((ext_vector_type(8))) short short8;
typedef __attribute__((ext_vector_type(4))) float floatx4;

__device__ __forceinline__ u16 f2bf(float f)
{
    unsigned int u = __float_as_uint(f);
    u += 0x7FFFu + ((u >> 16) & 1u);
    return (u16)(u >> 16);
}
__device__ __forceinline__ float bf2f(u16 h)
{
    return __uint_as_float(((unsigned int)h) << 16);
}
// reconstruct split activation
__device__ __forceinline__ float recs(const u16* p, size_t o, long pl)
{
    return bf2f(p[o]) + bf2f(p[o + pl]);
}
__device__ __forceinline__ void wsplit(u16* p, size_t o, long pl, float v)
{
    u16 h = f2bf(v);
    p[o] = h;
    p[o + pl] = f2bf(v - bf2f(h));
}

// ---------------------------------------------------------------------------
// Split-precision bf16x3 MFMA GEMM. A is either fp32 (SPLITA=0, converted in
// staging) or planar split-bf16 activations (SPLITA=1, staged with pure
// copies). Weights pre-split planar bf16 Wt[n][k]. Output written as planar
// split bf16 (hi at C, lo at C+cplane). 128x128 tile, BK=32, 4 waves 2x2,
// wave = 4x4 mfma_f32_16x16x32_bf16 x3 (hi*lo + lo*hi + hi*hi).
// Requires: M%128==0, Ngrid%128==0, K%32==0, K1%16==0, row offsets %8.
// ---------------------------------------------------------------------------
#define TW 40
template <int SPLITA>
__global__ __launch_bounds__(256) void gemm_mfma_kernel(
    const void* __restrict__ A1v, long pl1, int lda1, int K1,
    const void* __restrict__ A2v, long pl2, int lda2, int K2,
    const u16* __restrict__ Wh, const u16* __restrict__ Wl, int ldwt,
    const float* __restrict__ bias,
    u16* __restrict__ C, long cplane, int ldc,
    int Ncap, int relu)
{
    __shared__ __align__(16) u16 Ah[128 * TW];
    __shared__ __align__(16) u16 Al[128 * TW];
    __shared__ __align__(16) u16 Bh[128 * TW];
    __shared__ __align__(16) u16 Bl[128 * TW];
    const int tid = threadIdx.x;
    const int lane = tid & 63, wave = tid >> 6;
    const int wm = wave >> 1, wn = wave & 1;
    const int bm = blockIdx.y * 128, bn = blockIdx.x * 128;
    const int K = K1 + K2;
    const int srow = tid >> 1;
    const int skoff = (tid & 1) * 16;

    floatx4 acc[4][4];
    #pragma unroll
    for (int i = 0; i < 4; i++)
        #pragma unroll
        for (int j = 0; j < 4; j++) acc[i][j] = (floatx4){0.f, 0.f, 0.f, 0.f};

    const int arow = bm + srow;
    const int brow = bn + srow;
    const int l15 = lane & 15, lq = lane >> 4;

    for (int k0 = 0; k0 < K; k0 += 32) {
        const int kk = k0 + skoff;
        if (SPLITA) {
            const u16* base = (kk < K1)
                ? ((const u16*)A1v + (size_t)arow * lda1 + kk)
                : ((const u16*)A2v + (size_t)arow * lda2 + (kk - K1));
            const long pl = (kk < K1) ? pl1 : pl2;
            *(uint4*)&Ah[srow * TW + skoff]     = ((const uint4*)base)[0];
            *(uint4*)&Ah[srow * TW + skoff + 8] = ((const uint4*)base)[1];
            const u16* basel = base + pl;
            *(uint4*)&Al[srow * TW + skoff]     = ((const uint4*)basel)[0];
            *(uint4*)&Al[srow * TW + skoff + 8] = ((const uint4*)basel)[1];
        } else {
            const float* asrc = (kk < K1)
                ? ((const float*)A1v + (size_t)arow * lda1 + kk)
                : ((const float*)A2v + (size_t)arow * lda2 + (kk - K1));
            float f[16];
            ((float4*)f)[0] = ((const float4*)asrc)[0];
            ((float4*)f)[1] = ((const float4*)asrc)[1];
            ((float4*)f)[2] = ((const float4*)asrc)[2];
            ((float4*)f)[3] = ((const float4*)asrc)[3];
            u16 ph[16], pl8[16];
            #pragma unroll
            for (int q = 0; q < 16; q++) {
                u16 h = f2bf(f[q]);
                ph[q] = h;
                pl8[q] = f2bf(f[q] - bf2f(h));
            }
            *(uint4*)&Ah[srow * TW + skoff]     = *(const uint4*)&ph[0];
            *(uint4*)&Ah[srow * TW + skoff + 8] = *(const uint4*)&ph[8];
            *(uint4*)&Al[srow * TW + skoff]     = *(const uint4*)&pl8[0];
            *(uint4*)&Al[srow * TW + skoff + 8] = *(const uint4*)&pl8[8];
        }
        const u16* bh = Wh + (size_t)brow * ldwt + kk;
        const u16* bl = Wl + (size_t)brow * ldwt + kk;
        *(uint4*)&Bh[srow * TW + skoff]     = ((const uint4*)bh)[0];
        *(uint4*)&Bh[srow * TW + skoff + 8] = ((const uint4*)bh)[1];
        *(uint4*)&Bl[srow * TW + skoff]     = ((const uint4*)bl)[0];
        *(uint4*)&Bl[srow * TW + skoff + 8] = ((const uint4*)bl)[1];
        __syncthreads();
        short8 afh[4], afl[4], bfh[4], bfl[4];
        #pragma unroll
        for (int i = 0; i < 4; i++) {
            const int ro = (wm * 64 + i * 16 + l15) * TW + lq * 8;
            afh[i] = *(const short8*)&Ah[ro];
            afl[i] = *(const short8*)&Al[ro];
        }
        #pragma unroll
        for (int j = 0; j < 4; j++) {
            const int ro = (wn * 64 + j * 16 + l15) * TW + lq * 8;
            bfh[j] = *(const short8*)&Bh[ro];
            bfl[j] = *(const short8*)&Bl[ro];
        }
        #pragma unroll
        for (int i = 0; i < 4; i++)
            #pragma unroll
            for (int j = 0; j < 4; j++) {
                acc[i][j] = __builtin_amdgcn_mfma_f32_16x16x32_bf16(afh[i], bfl[j], acc[i][j], 0, 0, 0);
                acc[i][j] = __builtin_amdgcn_mfma_f32_16x16x32_bf16(afl[i], bfh[j], acc[i][j], 0, 0, 0);
                acc[i][j] = __builtin_amdgcn_mfma_f32_16x16x32_bf16(afh[i], bfh[j], acc[i][j], 0, 0, 0);
            }
        __syncthreads();
    }
    #pragma unroll
    for (int j = 0; j < 4; j++) {
        const int col = bn + wn * 64 + j * 16 + l15;
        const bool cok = (col < Ncap);
        const float bv = (bias && cok) ? bias[col] : 0.f;
        #pragma unroll
        for (int i = 0; i < 4; i++) {
            const int row0 = bm + wm * 64 + i * 16 + lq * 4;
            #pragma unroll
            for (int r = 0; r < 4; r++) {
                float v = acc[i][j][r] + bv;
                if (relu) v = fmaxf(v, 0.f);
                if (cok) wsplit(C, (size_t)(row0 + r) * ldc + col, cplane, v);
            }
        }
    }
}

// split-activation A
static inline void gemmS(hipStream_t s,
                         const u16* A1, long pl1, int lda1, int K1,
                         const u16* A2, long pl2, int lda2, int K2,
                         const u16* Wh, const u16* Wl, int ldwt,
                         const float* bias,
                         u16* C, long cpl, int ldc, int M, int Ngrid, int Ncap, bool relu)
{
    dim3 grid(Ngrid / 128, M / 128);
    gemm_mfma_kernel<1><<<grid, 256, 0, s>>>(A1, pl1, lda1, K1, A2, pl2, lda2, K2,
                                             Wh, Wl, ldwt, bias, C, cpl, ldc, Ncap, relu ? 1 : 0);
}
// fp32 A (graph inputs)
static inline void gemmF(hipStream_t s,
                         const float* A1, int lda1, int K1,
                         const u16* Wh, const u16* Wl, int ldwt,
                         const float* bias,
                         u16* C, long cpl, int ldc, int M, int Ngrid, int Ncap, bool relu)
{
    dim3 grid(Ngrid / 128, M / 128);
    gemm_mfma_kernel<0><<<grid, 256, 0, s>>>(A1, 0, lda1, K1, nullptr, 0, 0, 0,
                                             Wh, Wl, ldwt, bias, C, cpl, ldc, Ncap, relu ? 1 : 0);
}

// dst_{hi,lo}[(noff+n)*ldk + k] = split bf16 of src[k*N + n]; n>=N pads zero.
__global__ void transpose_cvt_kernel(const float* __restrict__ src, int K, int N,
                                     int Npad,
                                     u16* __restrict__ dst_hi, u16* __restrict__ dst_lo,
                                     int ldk, int noff)
{
    int idx = blockIdx.x * 256 + threadIdx.x;
    if (idx >= K * Npad) return;
    int k = idx / Npad, n = idx % Npad;
    float v = (n < N) ? src[(size_t)k * N + n] : 0.f;
    u16 h = f2bf(v);
    size_t o = (size_t)(noff + n) * ldk + k;
    dst_hi[o] = h;
    dst_lo[o] = f2bf(v - bf2f(h));
}

// ---------------------------------------------------------------------------
// Batched MFMA plan-GEMM: plan fp32 (split at staging), U planar split,
// C planar split. 64x128 tile, BK=32, wave tile 32x64.
// ---------------------------------------------------------------------------
template <int TRANSP>
__global__ __launch_bounds__(256) void bgemm_mfma_kernel(
    const float* __restrict__ P, int ms, int n_per,
    const u16* __restrict__ U, long uplane, int ldu,
    u16* __restrict__ C, long cplane, int ldc)
{
    __shared__ __align__(16) u16 Ah[64 * TW];
    __shared__ __align__(16) u16 Al[64 * TW];
    __shared__ __align__(16) u16 Bh[128 * TW];
    __shared__ __align__(16) u16 Bl[128 * TW];
    const int b = blockIdx.z;
    const float* Pb = P + (size_t)b * ms * ms;
    const int qbase = (2 * b) * n_per, cbase = (2 * b + 1) * n_per;
    const int obase = TRANSP ? cbase : qbase;
    const int ibase = TRANSP ? qbase : cbase;
    const int bm = blockIdx.y * 64, bn = blockIdx.x * 128;
    const int tid = threadIdx.x, lane = tid & 63, wave = tid >> 6;
    const int wm = wave >> 1, wn = wave & 1;
    const int l15 = lane & 15, lq = lane >> 4;
    const int sar = tid >> 2, sak = (tid & 3) * 8;
    const int sbn = tid >> 1, sbk = (tid & 1) * 16;
    const int Kpad = (n_per + 31) & ~31;

    floatx4 acc[2][4];
    #pragma unroll
    for (int i = 0; i < 2; i++)
        #pragma unroll
        for (int j = 0; j < 4; j++) acc[i][j] = (floatx4){0.f, 0.f, 0.f, 0.f};

    for (int k0 = 0; k0 < Kpad; k0 += 32) {
        {
            u16 ph[8], pl8[8];
            const int m = bm + sar;
            #pragma unroll
            for (int i = 0; i < 8; i++) {
                int kk = k0 + sak + i;
                float v = 0.f;
                if (kk < n_per && m < n_per)
                    v = TRANSP ? Pb[(size_t)kk * ms + m] : Pb[(size_t)m * ms + kk];
                u16 h = f2bf(v);
                ph[i] = h; pl8[i] = f2bf(v - bf2f(h));
            }
            *(uint4*)&Ah[sar * TW + sak] = *(const uint4*)&ph[0];
            *(uint4*)&Al[sar * TW + sak] = *(const uint4*)&pl8[0];
        }
        {
            u16 qh[16], ql[16];
            #pragma unroll
            for (int i = 0; i < 16; i++) {
                int kk = k0 + sbk + i;
                u16 h = 0, l = 0;
                if (kk < n_per) {
                    size_t o = (size_t)(ibase + kk) * ldu + bn + sbn;
                    h = U[o]; l = U[o + uplane];
                }
                qh[i] = h; ql[i] = l;
            }
            *(uint4*)&Bh[sbn * TW + sbk]     = *(const uint4*)&qh[0];
            *(uint4*)&Bh[sbn * TW + sbk + 8] = *(const uint4*)&qh[8];
            *(uint4*)&Bl[sbn * TW + sbk]     = *(const uint4*)&ql[0];
            *(uint4*)&Bl[sbn * TW + sbk + 8] = *(const uint4*)&ql[8];
        }
        __syncthreads();
        short8 afh[2], afl[2], bfh[4], bfl[4];
        #pragma unroll
        for (int i = 0; i < 2; i++) {
            const int ro = (wm * 32 + i * 16 + l15) * TW + lq * 8;
            afh[i] = *(const short8*)&Ah[ro];
            afl[i] = *(const short8*)&Al[ro];
        }
        #pragma unroll
        for (int j = 0; j < 4; j++) {
            const int ro = (wn * 64 + j * 16 + l15) * TW + lq * 8;
            bfh[j] = *(const short8*)&Bh[ro];
            bfl[j] = *(const short8*)&Bl[ro];
        }
        #pragma unroll
        for (int i = 0; i < 2; i++)
            #pragma unroll
            for (int j = 0; j < 4; j++) {
                acc[i][j] = __builtin_amdgcn_mfma_f32_16x16x32_bf16(afh[i], bfl[j], acc[i][j], 0, 0, 0);
                acc[i][j] = __builtin_amdgcn_mfma_f32_16x16x32_bf16(afl[i], bfh[j], acc[i][j], 0, 0, 0);
                acc[i][j] = __builtin_amdgcn_mfma_f32_16x16x32_bf16(afh[i], bfh[j], acc[i][j], 0, 0, 0);
            }
        __syncthreads();
    }
    #pragma unroll
    for (int j = 0; j < 4; j++) {
        const int col = bn + wn * 64 + j * 16 + l15;
        #pragma unroll
        for (int i = 0; i < 2; i++) {
            const int row0 = bm + wm * 32 + i * 16 + lq * 4;
            #pragma unroll
            for (int r = 0; r < 4; r++) {
                const int m = row0 + r;
                if (m < n_per)
                    wsplit(C, (size_t)(obase + m) * ldc + col, cplane, acc[i][j][r]);
            }
        }
    }
}

static inline void bgemmM(hipStream_t s, bool transp, const float* P, int ms, int n_per,
                          const u16* U, long uplane, int ldu,
                          u16* C, long cplane, int ldc, int N)
{
    dim3 grid(N / 128, (n_per + 63) / 64, Bb);
    if (transp) bgemm_mfma_kernel<1><<<grid, 256, 0, s>>>(P, ms, n_per, U, uplane, ldu, C, cplane, ldc);
    else        bgemm_mfma_kernel<0><<<grid, 256, 0, s>>>(P, ms, n_per, U, uplane, ldu, C, cplane, ldc);
}

// ---------------------------------------------------------------------------
// Fused node transport: la (64x64 from split ttreal, padded-row guards) +
// 10 Sinkhorn iters in LDS + plan=exp write. One block per graph pair.
// ---------------------------------------------------------------------------
__global__ __launch_bounds__(256) void la_sinkhorn64_kernel(
    const u16* __restrict__ tt, long plane, float* __restrict__ n_la)
{
    const int b = blockIdx.x;
    __shared__ float Aq[64][65];
    __shared__ float Ac[64][65];
    __shared__ float m[64][65];
    __shared__ float red[64];
    const int tid = threadIdx.x;
    for (int idx = tid; idx < 4096; idx += 256) {
        int r = idx >> 6, s = idx & 63;
        float vq = 0.f, vc = 0.f;
        if (r < Nn) {
            size_t oq = ((size_t)(2 * b) * Nn + r) * Sdim + s;
            size_t oc = ((size_t)(2 * b + 1) * Nn + r) * Sdim + s;
            vq = recs(tt, oq, plane);
            vc = recs(tt, oc, plane);
        }
        Aq[r][s] = vq;
        Ac[r][s] = vc;
    }
    __syncthreads();
    {
        const int tx = tid & 15, ty = tid >> 4;
        float acc[4][4] = {};
        for (int s = 0; s < 64; s++) {
            float a[4], c[4];
            #pragma unroll
            for (int i = 0; i < 4; i++) a[i] = Aq[ty * 4 + i][s];
            #pragma unroll
            for (int j = 0; j < 4; j++) c[j] = Ac[tx * 4 + j][s];
            #pragma unroll
            for (int i = 0; i < 4; i++)
                #pragma unroll
                for (int j = 0; j < 4; j++)
                    acc[i][j] = fmaf(a[i], c[j], acc[i][j]);
        }
        #pragma unroll
        for (int i = 0; i < 4; i++)
            #pragma unroll
            for (int j = 0; j < 4; j++)
                m[ty * 4 + i][tx * 4 + j] = acc[i][j] * INV_TEMP;
    }
    __syncthreads();
    for (int it = 0; it < 10; it++) {
        if (tid < 64) {
            float mx = -1e30f;
            for (int c = 0; c < 64; c++) mx = fmaxf(mx, m[tid][c]);
            float s = 0.f;
            for (int c = 0; c < 64; c++) s += __expf(m[tid][c] - mx);
            red[tid] = mx + __logf(s);
        }
        __syncthreads();
        for (int idx = tid; idx < 4096; idx += 256) m[idx >> 6][idx & 63] -= red[idx >> 6];
        __syncthreads();
        if (tid < 64) {
            float mx = -1e30f;
            for (int r = 0; r < 64; r++) mx = fmaxf(mx, m[r][tid]);
            float s = 0.f;
            for (int r = 0; r < 64; r++) s += __expf(m[r][tid] - mx);
            red[tid] = mx + __logf(s);
        }
        __syncthreads();
        for (int idx = tid; idx < 4096; idx += 256) m[idx >> 6][idx & 63] -= red[idx & 63];
        __syncthreads();
    }
    float* g = n_la + (size_t)b * 4096;
    for (int idx = tid; idx < 4096; idx += 256) g[idx] = __expf(m[idx >> 6][idx & 63]);
}

// la for edges (256x256), reading split ttreal_e with padded-row guards.
__global__ __launch_bounds__(256) void la_gemm256_kernel(
    const u16* __restrict__ tt, long plane, float* __restrict__ la)
{
    const int b = blockIdx.z;
    const int bm = blockIdx.y * 64, bn = blockIdx.x * 64;
    __shared__ float Aq[64][65];
    __shared__ float Ac[64][65];
    const int tid = threadIdx.x;
    for (int idx = tid; idx < 4096; idx += 256) {
        int r = idx >> 6, s = idx & 63;
        float vq = 0.f, vc = 0.f;
        int qr = bm + r, cr = bn + r;
        if (qr < Ee) vq = recs(tt, ((size_t)(2 * b) * Ee + qr) * Sdim + s, plane);
        if (cr < Ee) vc = recs(tt, ((size_t)(2 * b + 1) * Ee + cr) * Sdim + s, plane);
        Aq[r][s] = vq;
        Ac[r][s] = vc;
    }
    __syncthreads();
    const int tx = tid & 15, ty = tid >> 4;
    float acc[4][4] = {};
    for (int s = 0; s < 64; s++) {
        float a[4], c[4];
        #pragma unroll
        for (int i = 0; i < 4; i++) a[i] = Aq[ty * 4 + i][s];
        #pragma unroll
        for (int j = 0; j < 4; j++) c[j] = Ac[tx * 4 + j][s];
        #pragma unroll
        for (int i = 0; i < 4; i++)
            #pragma unroll
            for (int j = 0; j < 4; j++)
                acc[i][j] = fmaf(a[i], c[j], acc[i][j]);
    }
    #pragma unroll
    for (int i = 0; i < 4; i++)
        #pragma unroll
        for (int j = 0; j < 4; j++)
            la[((size_t)b * 256 + bm + ty * 4 + i) * 256 + bn + tx * 4 + j] = acc[i][j] * INV_TEMP;
}

// ---------------------------------------------------------------------------
// Sinkhorn 256x256 (edges), log-potential form, max-stabilized both phases.
// ---------------------------------------------------------------------------
__global__ __launch_bounds__(1024) void sinkhorn256_kernel(float* __restrict__ la)
{
    const int b = blockIdx.x;
    float* g = la + (size_t)b * 65536;
    const int tid = threadIdx.x;
    const int r = tid >> 2, cg = tid & 3;
    const int lane = tid & 63;
    const int wv = tid >> 6;
    const float4* rowp = (const float4*)(g + (size_t)r * 256 + cg * 64);
    __shared__ float u_s[256], vv_s[256], colmx[256];
    __shared__ float part[16][256];
    if (tid < 256) { u_s[tid] = 0.f; vv_s[tid] = 0.f; }
    __syncthreads();
    for (int it = 0; it < 10; it++) {
        float mx = -1e30f;
        #pragma unroll
        for (int i = 0; i < 16; i++) {
            float4 x = rowp[i];
            int c0 = cg * 64 + i * 4;
            mx = fmaxf(mx, fmaxf(fmaxf(x.x - vv_s[c0], x.y - vv_s[c0 + 1]),
                                 fmaxf(x.z - vv_s[c0 + 2], x.w - vv_s[c0 + 3])));
        }
        mx = fmaxf(mx, __shfl_xor(mx, 1));
        mx = fmaxf(mx, __shfl_xor(mx, 2));
        float s = 0.f;
        #pragma unroll
        for (int i = 0; i < 16; i++) {
            float4 x = rowp[i];
            int c0 = cg * 64 + i * 4;
            s += __expf(x.x - vv_s[c0]     - mx) + __expf(x.y - vv_s[c0 + 1] - mx)
               + __expf(x.z - vv_s[c0 + 2] - mx) + __expf(x.w - vv_s[c0 + 3] - mx);
        }
        s += __shfl_xor(s, 1);
        s += __shfl_xor(s, 2);
        if (cg == 0) u_s[r] = mx + __logf(s);
        __syncthreads();
        float ur = u_s[r];
        #pragma unroll
        for (int i = 0; i < 16; i++) {
            float4 x = rowp[i];
            int c0 = cg * 64 + i * 4;
            float m0 = x.x - ur - vv_s[c0];
            float m1 = x.y - ur - vv_s[c0 + 1];
            float m2 = x.z - ur - vv_s[c0 + 2];
            float m3 = x.w - ur - vv_s[c0 + 3];
            #pragma unroll
            for (int d = 4; d < 64; d <<= 1) {
                m0 = fmaxf(m0, __shfl_xor(m0, d));
                m1 = fmaxf(m1, __shfl_xor(m1, d));
                m2 = fmaxf(m2, __shfl_xor(m2, d));
                m3 = fmaxf(m3, __shfl_xor(m3, d));
            }
            if ((lane >> 2) == 0) {
                part[wv][c0]     = m0;
                part[wv][c0 + 1] = m1;
                part[wv][c0 + 2] = m2;
                part[wv][c0 + 3] = m3;
            }
        }
        __syncthreads();
        if (tid < 256) {
            float mm = -1e30f;
            #pragma unroll
            for (int w = 0; w < 16; w++) mm = fmaxf(mm, part[w][tid]);
            colmx[tid] = mm;
        }
        __syncthreads();
        #pragma unroll
        for (int i = 0; i < 16; i++) {
            float4 x = rowp[i];
            int c0 = cg * 64 + i * 4;
            float e0 = __expf(x.x - ur - vv_s[c0]     - colmx[c0]);
            float e1 = __expf(x.y - ur - vv_s[c0 + 1] - colmx[c0 + 1]);
            float e2 = __expf(x.z - ur - vv_s[c0 + 2] - colmx[c0 + 2]);
            float e3 = __expf(x.w - ur - vv_s[c0 + 3] - colmx[c0 + 3]);
            #pragma unroll
            for (int d = 4; d < 64; d <<= 1) {
                e0 += __shfl_xor(e0, d);
                e1 += __shfl_xor(e1, d);
                e2 += __shfl_xor(e2, d);
                e3 += __shfl_xor(e3, d);
            }
            if ((lane >> 2) == 0) {
                part[wv][c0]     = e0;
                part[wv][c0 + 1] = e1;
                part[wv][c0 + 2] = e2;
                part[wv][c0 + 3] = e3;
            }
        }
        __syncthreads();
        if (tid < 256) {
            float ssum = 0.f;
            #pragma unroll
            for (int w = 0; w < 16; w++) ssum += part[w][tid];
            vv_s[tid] += colmx[tid] + __logf(ssum);
        }
        __syncthreads();
    }
    float ur = u_s[r];
    float4* outp = (float4*)(g + (size_t)r * 256 + cg * 64);
    #pragma unroll
    for (int i = 0; i < 16; i++) {
        float4 x = rowp[i];
        int c0 = cg * 64 + i * 4;
        float4 o;
        o.x = __expf(x.x - ur - vv_s[c0]);
        o.y = __expf(x.y - ur - vv_s[c0 + 1]);
        o.z = __expf(x.z - ur - vv_s[c0 + 2]);
        o.w = __expf(x.w - ur - vv_s[c0 + 3]);
        outp[i] = o;
    }
}

// ---------------------------------------------------------------------------
// Group-local message aggregation; all operands planar split.
// ---------------------------------------------------------------------------
__global__ __launch_bounds__(256) void agg_kernel(
    const u16* __restrict__ P01, long p01pl,
    const u16* __restrict__ ec2, long ec2pl,
    const int* __restrict__ from_idx, const int* __restrict__ to_idx,
    u16* __restrict__ agg, long aggpl)
{
    const int gblk = blockIdx.x;
    const int d = threadIdx.x;
    __shared__ float acc[48][256];
    __shared__ int fr[192], to[192];
    #pragma unroll
    for (int n = 0; n < 48; n++) acc[n][d] = 0.f;
    if (d < 192) {
        fr[d] = from_idx[gblk * 192 + d] - gblk * 48;
        to[d] = to_idx[gblk * 192 + d] - gblk * 48;
    }
    __syncthreads();
    const int nb = gblk * 48;
    const int eb = gblk * 192;
    for (int e = 0; e < 192; e++) {
        int f = fr[e], t = to[e];
        float ee  = recs(ec2, (size_t)(eb + e) * 256 + d, ec2pl);
        float p0f = recs(P01, (size_t)(nb + f) * 512 + d, p01pl);
        float p1f = recs(P01, (size_t)(nb + f) * 512 + 256 + d, p01pl);
        float p0t = recs(P01, (size_t)(nb + t) * 512 + d, p01pl);
        float p1t = recs(P01, (size_t)(nb + t) * 512 + 256 + d, p01pl);
        acc[t][d] += p0f + p1t + ee;
        acc[f][d] += p0t + p1f + ee;
    }
    __syncthreads();
    for (int n = 0; n < 48; n++)
        wsplit(agg, (size_t)(nb + n) * 256 + d, aggpl, acc[n][d]);
}

// In-place messages (planar split): m[e] <- Qs[from]+Qs[to]+2*m[e]
__global__ __launch_bounds__(256) void msgs_inplace_kernel(
    u16* __restrict__ m, long mpl,
    const u16* __restrict__ Qs, long qpl,
    const int* __restrict__ from_idx, const int* __restrict__ to_idx)
{
    const int e = blockIdx.x;
    const int d = threadIdx.x;
    const int f = from_idx[e], t = to_idx[e];
    size_t o = (size_t)e * 256 + d;
    float v = recs(Qs, (size_t)f * 256 + d, qpl) + recs(Qs, (size_t)t * 256 + d, qpl)
            + 2.f * recs(m, o, mpl);
    wsplit(m, o, mpl, v);
}

// Wsum = msg_W[0:128] + msg_W[128:256]
__global__ void wsum_kernel(const float* __restrict__ msg_W, float* __restrict__ Wsum)
{
    int idx = blockIdx.x * 256 + threadIdx.x;
    Wsum[idx] = msg_W[idx] + msg_W[32768 + idx];
}

__global__ void diag_kernel(float* __restrict__ out, float v)
{
    out[threadIdx.x] = v;
}

// score[b] = -sum relu( ffq - plan@ffc ); upd_node planar split, plan fp32.
__global__ __launch_bounds__(128) void score_kernel(
    const u16* __restrict__ upd, long updpl,
    const float* __restrict__ plan, float* __restrict__ out)
{
    const int b = blockIdx.x;
    const int tid = threadIdx.x;
    __shared__ float ffc[48][128];
    __shared__ float pl[64][48];
    __shared__ float red[128];
    for (int c = 0; c < 48; c++)
        ffc[c][tid] = recs(upd, (size_t)((2 * b + 1) * 48 + c) * 640 + 512 + tid, updpl);
    for (int idx = tid; idx < 64 * 48; idx += 128) {
        int q = idx / 48, c = idx % 48;
        pl[q][c] = plan[(size_t)b * 4096 + q * 64 + c];
    }
    __syncthreads();
    float accv = 0.f;
    for (int q = 0; q < 64; q++) {
        float rsum = 0.f;
        #pragma unroll 8
        for (int c = 0; c < 48; c++) rsum = fmaf(pl[q][c], ffc[c][tid], rsum);
        float fq = 0.f;
        if (q < 48) fq = recs(upd, (size_t)((2 * b) * 48 + q) * 640 + 512 + tid, updpl);
        accv += fmaxf(fq - rsum, 0.f);
    }
    red[tid] = accv;
    __syncthreads();
    for (int sft = 64; sft > 0; sft >>= 1) {
        if (tid < sft) red[tid] += red[tid + sft];
        __syncthreads();
    }
    if (tid == 0) out[b] = -red[0];
}

// ---------------------------------------------------------------------------
// Workspace layout (float units; split buffers = 2 bf16 planes, same bytes).
// ---------------------------------------------------------------------------
#define OFF_UPD_NODE   0ULL
#define OFF_NODE_STORE 3932160ULL
#define OFF_EDGE_STORE 7077888ULL
#define OFF_ECOMB      32243712ULL
#define OFF_ENC_N      47972352ULL
#define OFF_ENC_E      48758784ULL
#define OFF_N_LA       51904512ULL
#define OFF_WSUM       52166656ULL
#define OFF_WT         52199424ULL
#define OFF_WTL        52547584ULL
#define OFF_ARENA      52895744ULL
#define TOTAL_FLOATS   66265088ULL

// plane sizes (u16 element counts)
#define PLN_UPD   3932160L
#define PLN_NST   3145728L
#define PLN_EST   25165824L
#define PLN_ECOMB 15728640L
#define PLN_ENCN  786432L
#define PLN_ENCE  3145728L
#define PLN_HID   1572864L
#define PLN_HCOMB 786432L
#define PLN_EHID  9437184L
#define PLN_EC2   6291456L
#define PLN_P01   3145728L
#define PLN_AGG   1572864L
#define PLN_MSGS  6291456L
#define PLN_QS    1572864L
#define PLN_THN   393216L
#define PLN_TTN   393216L
#define PLN_TTE   1572864L

// bf16 weight sub-offsets (u16 from WT/WTL base)
#define WT_NIW1   0
#define WT_NIW2   65536
#define WT_EIW1   98304
#define WT_EIW2   245760
#define WT_MSG    294912
#define WT_P01    393216
#define WT_NUW1   458752
#define WT_NUW2   557056
#define WT_WSUM   589824
#define WT_ENCN   622592
#define WT_ENCE   626688
#define WT_NS1    630784
#define WT_NS2    647168
#define WT_ES1    655360
#define WT_ES2    688128

extern "C" void kernel_launch(void* const* d_in, const int* in_sizes, int n_in,
                              void* d_out, int out_size, void* d_ws, size_t ws_size,
                              hipStream_t stream)
{
    (void)in_sizes; (void)n_in; (void)out_size;
    if (ws_size < TOTAL_FLOATS * sizeof(float)) {
        diag_kernel<<<1, 64, 0, stream>>>((float*)d_out, (float)ws_size);
        return;
    }

    const float* node_features = (const float*)d_in[0];
    const float* edge_features = (const float*)d_in[1];
    const int*   from_idx      = (const int*)d_in[2];
    const int*   to_idx        = (const int*)d_in[3];
    const float* enc_node_W = (const float*)d_in[4];
    const float* enc_node_b = (const float*)d_in[5];
    const float* enc_edge_W = (const float*)d_in[6];
    const float* enc_edge_b = (const float*)d_in[7];
    const float* ni_W1 = (const float*)d_in[8];
    const float* ni_b1 = (const float*)d_in[9];
    const float* ni_W2 = (const float*)d_in[10];
    const float* ni_b2 = (const float*)d_in[11];
    const float* ei_W1 = (const float*)d_in[12];
    const float* ei_b1 = (const float*)d_in[13];
    const float* ei_W2 = (const float*)d_in[14];
    const float* ei_b2 = (const float*)d_in[15];
    const float* msg_W = (const float*)d_in[16];
    const float* msg_b = (const float*)d_in[17];
    const float* nu_W1 = (const float*)d_in[18];
    const float* nu_b1 = (const float*)d_in[19];
    const float* nu_W2 = (const float*)d_in[20];
    const float* nu_b2 = (const float*)d_in[21];
    const float* ns_W1 = (const float*)d_in[22];
    const float* ns_b1 = (const float*)d_in[23];
    const float* ns_W2 = (const float*)d_in[24];
    const float* ns_b2 = (const float*)d_in[25];
    const float* es_W1 = (const float*)d_in[26];
    const float* es_b1 = (const float*)d_in[27];
    const float* es_W2 = (const float*)d_in[28];
    const float* es_b2 = (const float*)d_in[29];

    float* ws = (float*)d_ws;
    u16* UPD   = (u16*)(ws + OFF_UPD_NODE);    // VN x 640 split
    u16* NST   = (u16*)(ws + OFF_NODE_STORE);  // VN x 512 split
    u16* EST   = (u16*)(ws + OFF_EDGE_STORE);  // VE x 1024 split
    u16* ECOMB = (u16*)(ws + OFF_ECOMB);       // 5*VE x 128 split
    u16* ENCN  = (u16*)(ws + OFF_ENC_N);
    u16* ENCE  = (u16*)(ws + OFF_ENC_E);
    float* n_la = ws + OFF_N_LA;
    float* Wsum = ws + OFF_WSUM;
    u16* WT  = (u16*)(ws + OFF_WT);
    u16* WTL = (u16*)(ws + OFF_WTL);
    float* arena = ws + OFF_ARENA;

    // Phase-A arena carve
    u16* A_hidden = (u16*)(arena);             // VN x 256
    u16* A_hcomb  = (u16*)(arena + 1572864);   // VN x 128
    u16* A_ehid   = (u16*)(arena + 2359296);   // VE x 384
    u16* A_ec2    = (u16*)(arena + 2359296);   // VE x 256 (alias, ehid dead)
    u16* A_P01    = (u16*)(arena + 8650752);   // VN x 512
    u16* A_aggb   = (u16*)(arena + 11796480);  // VN x 256
    // Phase-B arena carve
    u16* B_msgs   = (u16*)(arena);             // VE x 256
    u16* B_tte    = (u16*)(arena);             // VE x 64 (after msgs dead)
    u16* B_Qs     = (u16*)(arena + 6291456);   // VN x 256 / thid_e VE x 64
    float* B_ela  = arena + 7864320;           // 64 x 256 x 256 fp32
    u16* B_thn    = (u16*)(arena + 12058624);  // VN x 64
    u16* B_ttn    = (u16*)(arena + 12451840);  // VN x 64

    // --- one-time weight prep ---
    auto tcv = [&](const float* src, int K, int N, int Npad, int wtoff, int ldk, int noff) {
        transpose_cvt_kernel<<<(K * Npad + 255) / 256, 256, 0, stream>>>(
            src, K, N, Npad, WT + wtoff, WTL + wtoff, ldk, noff);
    };
    wsum_kernel<<<32768 / 256, 256, 0, stream>>>(msg_W, Wsum);
    tcv(ni_W1, 256, 256, 256, WT_NIW1, 256, 0);
    tcv(ni_W2, 256, 128, 128, WT_NIW2, 256, 0);
    tcv(ei_W1, 384, 384, 384, WT_EIW1, 384, 0);
    tcv(ei_W2, 384, 128, 128, WT_EIW2, 384, 0);
    tcv(msg_W, 384, 256, 256, WT_MSG, 384, 0);
    tcv(msg_W, 128, 256, 256, WT_P01, 128, 0);
    tcv(msg_W + (size_t)128 * 256, 128, 256, 256, WT_P01, 128, 256);
    tcv(nu_W1, 384, 256, 256, WT_NUW1, 384, 0);
    tcv(nu_W2, 256, 128, 128, WT_NUW2, 256, 0);
    tcv(Wsum, 128, 256, 256, WT_WSUM, 128, 0);
    tcv(enc_node_W, 32, 128, 128, WT_ENCN, 32, 0);
    tcv(enc_edge_W, 32, 128, 128, WT_ENCE, 32, 0);
    tcv(ns_W1, 128, 64, 128, WT_NS1, 128, 0);
    tcv(ns_W2, 64, 64, 128, WT_NS2, 64, 0);
    tcv(es_W1, 256, 64, 128, WT_ES1, 256, 0);
    tcv(es_W2, 64, 64, 128, WT_ES2, 64, 0);

    // --- encoders (fp32 A) ---
    gemmF(stream, node_features, 32, 32, WT + WT_ENCN, WTL + WT_ENCN, 32,
          enc_node_b, ENCN, PLN_ENCN, 128, VNn, 128, 128, false);
    gemmF(stream, edge_features, 32, 32, WT + WT_ENCE, WTL + WT_ENCE, 32,
          enc_edge_b, ENCE, PLN_ENCE, 128, VEe, 128, 128, false);

    for (int k = 0; k < 3; k++) {
        for (int p = 1; p <= 5; p++) {
            const bool hs = (k > 0) && (p > 1);
            const u16* hprev = (p == 1) ? ENCN : (UPD + (size_t)(p - 2) * 128);
            const long hpl   = (p == 1) ? PLN_ENCN : PLN_UPD;
            const int  hld   = (p == 1) ? 128 : 640;
            // h_comb = mlp2([h, node_store slot p-1], ni)
            gemmS(stream, hprev, hpl, hld, 128,
                  hs ? (NST + (size_t)(p - 2) * 128) : nullptr, PLN_NST, 512, hs ? 128 : 0,
                  WT + WT_NIW1, WTL + WT_NIW1, 256, ni_b1,
                  A_hidden, PLN_HID, 256, VNn, 256, 256, true);
            gemmS(stream, A_hidden, PLN_HID, 256, 256, nullptr, 0, 0, 0,
                  WT + WT_NIW2, WTL + WT_NIW2, 256, ni_b2,
                  A_hcomb, PLN_HCOMB, 128, VNn, 128, 128, false);
            // e_comb -> ecomb slot p
            u16* ec_slot = ECOMB + (size_t)(p - 1) * VEe * 128;
            gemmS(stream, ENCE, PLN_ENCE, 128, 128,
                  hs ? (EST + (size_t)(p - 2) * 256) : nullptr, PLN_EST, 1024, hs ? 256 : 0,
                  WT + WT_EIW1, WTL + WT_EIW1, 384, ei_b1,
                  A_ehid, PLN_EHID, 384, VEe, 384, 384, true);
            gemmS(stream, A_ehid, PLN_EHID, 384, 384, nullptr, 0, 0, 0,
                  WT + WT_EIW2, WTL + WT_EIW2, 384, ei_b2,
                  ec_slot, PLN_ECOMB, 128, VEe, 128, 128, false);
            // ec2 = e_comb @ msg_W[256:384] + msg_b   (aliases dead ehid)
            gemmS(stream, ec_slot, PLN_ECOMB, 128, 128, nullptr, 0, 0, 0,
                  WT + WT_MSG + 256, WTL + WT_MSG + 256, 384, msg_b,
                  A_ec2, PLN_EC2, 256, VEe, 256, 256, false);
            // P01 = h_comb @ [W0|W1]
            gemmS(stream, A_hcomb, PLN_HCOMB, 128, 128, nullptr, 0, 0, 0,
                  WT + WT_P01, WTL + WT_P01, 128, nullptr,
                  A_P01, PLN_P01, 512, VNn, 512, 512, false);
            agg_kernel<<<NGg, 256, 0, stream>>>(A_P01, PLN_P01, A_ec2, PLN_EC2,
                                                from_idx, to_idx, A_aggb, PLN_AGG);
            // h = mlp2([h_comb, agg], nu) -> upd_node slot p
            gemmS(stream, A_hcomb, PLN_HCOMB, 128, 128, A_aggb, PLN_AGG, 256, 256,
                  WT + WT_NUW1, WTL + WT_NUW1, 384, nu_b1,
                  A_hidden, PLN_HID, 256, VNn, 256, 256, true);
            gemmS(stream, A_hidden, PLN_HID, 256, 256, nullptr, 0, 0, 0,
                  WT + WT_NUW2, WTL + WT_NUW2, 256, nu_b2,
                  UPD + (size_t)(p - 1) * 128, PLN_UPD, 640, VNn, 128, 128, false);
        }
        // ---- node transport (fused la+sinkhorn) ----
        gemmS(stream, UPD + 512, PLN_UPD, 640, 128, nullptr, 0, 0, 0,
              WT + WT_NS1, WTL + WT_NS1, 128, ns_b1,
              B_thn, PLN_THN, 64, VNn, 128, 64, true);
        gemmS(stream, B_thn, PLN_THN, 64, 64, nullptr, 0, 0, 0,
              WT + WT_NS2, WTL + WT_NS2, 64, ns_b2,
              B_ttn, PLN_TTN, 64, VNn, 128, 64, false);
        la_sinkhorn64_kernel<<<Bb, 256, 0, stream>>>(B_ttn, PLN_TTN, n_la);
        if (k < 2) {
            bgemmM(stream, false, n_la, 64, 48, UPD, PLN_UPD, 640, NST, PLN_NST, 512, 512);
            bgemmM(stream, true,  n_la, 64, 48, UPD, PLN_UPD, 640, NST, PLN_NST, 512, 512);
            // ---- edge transport: msgs slot 5 for es features ----
            gemmS(stream, ECOMB + (size_t)4 * VEe * 128, PLN_ECOMB, 128, 128, nullptr, 0, 0, 0,
                  WT + WT_MSG + 256, WTL + WT_MSG + 256, 384, msg_b,
                  B_msgs, PLN_MSGS, 256, VEe, 256, 256, false);
            gemmS(stream, UPD + 512, PLN_UPD, 640, 128, nullptr, 0, 0, 0,
                  WT + WT_WSUM, WTL + WT_WSUM, 128, nullptr,
                  B_Qs, PLN_QS, 256, VNn, 256, 256, false);
            msgs_inplace_kernel<<<VEe, 256, 0, stream>>>(B_msgs, PLN_MSGS, B_Qs, PLN_QS,
                                                         from_idx, to_idx);
            gemmS(stream, B_msgs, PLN_MSGS, 256, 256, nullptr, 0, 0, 0,
                  WT + WT_ES1, WTL + WT_ES1, 256, es_b1,
                  B_Qs /*thid_e*/, PLN_QS, 64, VEe, 128, 64, true);
            gemmS(stream, B_Qs, PLN_QS, 64, 64, nullptr, 0, 0, 0,
                  WT + WT_ES2, WTL + WT_ES2, 64, es_b2,
                  B_tte, PLN_TTE, 64, VEe, 128, 64, false);
            la_gemm256_kernel<<<dim3(4, 4, Bb), 256, 0, stream>>>(B_tte, PLN_TTE, B_ela);
            sinkhorn256_kernel<<<Bb, 1024, 0, stream>>>(B_ela);
            for (int sl = 1; sl <= 4; sl++) {
                gemmS(stream, ECOMB + (size_t)(sl - 1) * VEe * 128, PLN_ECOMB, 128, 128,
                      nullptr, 0, 0, 0,
                      WT + WT_MSG + 256, WTL + WT_MSG + 256, 384, msg_b,
                      B_msgs, PLN_MSGS, 256, VEe, 256, 256, false);
                gemmS(stream, UPD + (size_t)(sl - 1) * 128, PLN_UPD, 640, 128, nullptr, 0, 0, 0,
                      WT + WT_WSUM, WTL + WT_WSUM, 128, nullptr,
                      B_Qs, PLN_QS, 256, VNn, 256, 256, false);
                msgs_inplace_kernel<<<VEe, 256, 0, stream>>>(B_msgs, PLN_MSGS, B_Qs, PLN_QS,
                                                             from_idx, to_idx);
                bgemmM(stream, false, B_ela, 256, 192, B_msgs, PLN_MSGS, 256,
                       EST + (size_t)(sl - 1) * 256, PLN_EST, 1024, 256);
                bgemmM(stream, true,  B_ela, 256, 192, B_msgs, PLN_MSGS, 256,
                       EST + (size_t)(sl - 1) * 256, PLN_EST, 1024, 256);
            }
        }
    }
    score_kernel<<<Bb, 128, 0, stream>>>(UPD, PLN_UPD, n_la, (float*)d_out);
}

// Round 8
// 4878.061 us; speedup vs baseline: 1.1851x; 1.1851x over previous
//
#include <hip/hip_runtime.h>
#include <cstdint>
#include <cstddef>

// Problem constants (from reference)
#define NGg   128     // 2*B
#define Bb    64
#define Nn    48
#define Ee    192
#define Sdim  64
#define VNn   6144    // NGg*Nn
#define VEe   24576   // NGg*Ee
#define INV_TEMP 10.0f

typedef unsigned short u16;
typedef __attribute__((ext_vector_type(8))) short short8;
typedef __attribute__((ext_vector_type(4))) float floatx4;

// round-to-nearest-even fp32 -> bf16
__device__ __forceinline__ u16 f2bf(float f)
{
    unsigned int u = __float_as_uint(f);
    u += 0x7FFFu + ((u >> 16) & 1u);
    return (u16)(u >> 16);
}
__device__ __forceinline__ float bf2f(u16 h)
{
    return __uint_as_float(((unsigned int)h) << 16);
}

// ---------------------------------------------------------------------------
// Split-precision bf16x3 MFMA GEMM ("emulated fp32"):
//   C = maybeReLU( (A_hi+A_lo) @ (W_hi+W_lo) + bias ),  dropping lo*lo.
// A fp32 row-major, split to hi/lo bf16 during LDS staging; weights pre-split
// into Wt_hi/Wt_lo bf16, transposed as Wt[n][k].
// 128x128 tile, BK=32, 256 thr = 4 waves (2x2), wave = 4x4 mfma 16x16x32,
// 3 MFMAs per tile. Ncap guards stores/bias for N<128 pads.
// Requires: M%128==0, Ngrid%128==0, K%32==0, K1%32==0, lda%4==0.
// ---------------------------------------------------------------------------
#define TW 40
__global__ __launch_bounds__(256) void gemm_mfma_kernel(
    const float* __restrict__ A1, int lda1, int K1,
    const float* __restrict__ A2, int lda2, int K2,
    const u16* __restrict__ Wh, const u16* __restrict__ Wl, int ldwt,
    const float* __restrict__ bias,
    float* __restrict__ C, int ldc,
    int Ncap, int relu)
{
    __shared__ __align__(16) u16 Ah[128 * TW];
    __shared__ __align__(16) u16 Al[128 * TW];
    __shared__ __align__(16) u16 Bh[128 * TW];
    __shared__ __align__(16) u16 Bl[128 * TW];
    const int tid = threadIdx.x;
    const int lane = tid & 63, wave = tid >> 6;
    const int wm = wave >> 1, wn = wave & 1;
    const int bm = blockIdx.y * 128, bn = blockIdx.x * 128;
    const int K = K1 + K2;
    const int srow = tid >> 1;
    const int skoff = (tid & 1) * 16;

    floatx4 acc[4][4];
    #pragma unroll
    for (int i = 0; i < 4; i++)
        #pragma unroll
        for (int j = 0; j < 4; j++) acc[i][j] = (floatx4){0.f, 0.f, 0.f, 0.f};

    const int arow = bm + srow;
    const int brow = bn + srow;
    const int l15 = lane & 15, lq = lane >> 4;

    for (int k0 = 0; k0 < K; k0 += 32) {
        const int kk = k0 + skoff;
        const float* asrc = (kk < K1) ? (A1 + (size_t)arow * lda1 + kk)
                                      : (A2 + (size_t)arow * lda2 + (kk - K1));
        float f[16];
        ((float4*)f)[0] = ((const float4*)asrc)[0];
        ((float4*)f)[1] = ((const float4*)asrc)[1];
        ((float4*)f)[2] = ((const float4*)asrc)[2];
        ((float4*)f)[3] = ((const float4*)asrc)[3];
        u16 ph[16], pl8[16];
        #pragma unroll
        for (int q = 0; q < 16; q++) {
            u16 h = f2bf(f[q]);
            ph[q] = h;
            pl8[q] = f2bf(f[q] - bf2f(h));
        }
        *(uint4*)&Ah[srow * TW + skoff]     = *(const uint4*)&ph[0];
        *(uint4*)&Ah[srow * TW + skoff + 8] = *(const uint4*)&ph[8];
        *(uint4*)&Al[srow * TW + skoff]     = *(const uint4*)&pl8[0];
        *(uint4*)&Al[srow * TW + skoff + 8] = *(const uint4*)&pl8[8];
        const u16* bh = Wh + (size_t)brow * ldwt + kk;
        const u16* bl = Wl + (size_t)brow * ldwt + kk;
        *(uint4*)&Bh[srow * TW + skoff]     = ((const uint4*)bh)[0];
        *(uint4*)&Bh[srow * TW + skoff + 8] = ((const uint4*)bh)[1];
        *(uint4*)&Bl[srow * TW + skoff]     = ((const uint4*)bl)[0];
        *(uint4*)&Bl[srow * TW + skoff + 8] = ((const uint4*)bl)[1];
        __syncthreads();
        short8 afh[4], afl[4], bfh[4], bfl[4];
        #pragma unroll
        for (int i = 0; i < 4; i++) {
            const int ro = (wm * 64 + i * 16 + l15) * TW + lq * 8;
            afh[i] = *(const short8*)&Ah[ro];
            afl[i] = *(const short8*)&Al[ro];
        }
        #pragma unroll
        for (int j = 0; j < 4; j++) {
            const int ro = (wn * 64 + j * 16 + l15) * TW + lq * 8;
            bfh[j] = *(const short8*)&Bh[ro];
            bfl[j] = *(const short8*)&Bl[ro];
        }
        #pragma unroll
        for (int i = 0; i < 4; i++)
            #pragma unroll
            for (int j = 0; j < 4; j++) {
                acc[i][j] = __builtin_amdgcn_mfma_f32_16x16x32_bf16(afh[i], bfl[j], acc[i][j], 0, 0, 0);
                acc[i][j] = __builtin_amdgcn_mfma_f32_16x16x32_bf16(afl[i], bfh[j], acc[i][j], 0, 0, 0);
                acc[i][j] = __builtin_amdgcn_mfma_f32_16x16x32_bf16(afh[i], bfh[j], acc[i][j], 0, 0, 0);
            }
        __syncthreads();
    }
    #pragma unroll
    for (int j = 0; j < 4; j++) {
        const int col = bn + wn * 64 + j * 16 + l15;
        const bool cok = (col < Ncap);
        const float bv = (bias && cok) ? bias[col] : 0.f;
        #pragma unroll
        for (int i = 0; i < 4; i++) {
            const int row0 = bm + wm * 64 + i * 16 + lq * 4;
            #pragma unroll
            for (int r = 0; r < 4; r++) {
                float v = acc[i][j][r] + bv;
                if (relu) v = fmaxf(v, 0.f);
                if (cok) C[(size_t)(row0 + r) * ldc + col] = v;
            }
        }
    }
}

static inline void gemmM(hipStream_t s,
                         const float* A1, int lda1, int K1,
                         const float* A2, int lda2, int K2,
                         const u16* Wh, const u16* Wl, int ldwt,
                         const float* bias,
                         float* C, int ldc, int M, int Ngrid, int Ncap, bool relu)
{
    dim3 grid(Ngrid / 128, M / 128);
    gemm_mfma_kernel<<<grid, 256, 0, s>>>(A1, lda1, K1, A2, lda2, K2, Wh, Wl, ldwt,
                                          bias, C, ldc, Ncap, relu ? 1 : 0);
}

// dst_{hi,lo}[(noff+n)*ldk + k] = split bf16 of src[k*N + n]; n>=N pads zero.
__global__ void transpose_cvt_kernel(const float* __restrict__ src, int K, int N,
                                     int Npad,
                                     u16* __restrict__ dst_hi, u16* __restrict__ dst_lo,
                                     int ldk, int noff)
{
    int idx = blockIdx.x * 256 + threadIdx.x;
    if (idx >= K * Npad) return;
    int k = idx / Npad, n = idx % Npad;
    float v = (n < N) ? src[(size_t)k * N + n] : 0.f;
    u16 h = f2bf(v);
    size_t o = (size_t)(noff + n) * ldk + k;
    dst_hi[o] = h;
    dst_lo[o] = f2bf(v - bf2f(h));
}

// ---------------------------------------------------------------------------
// Batched MFMA plan-GEMM (bf16x3 split on both operands, fp32 in/out):
//   TRANSP=0 (qi): C[obase+m, :] = sum_{k<n_per} P[b][m][k] * U[ibase+k, :]
//   TRANSP=1 (ci): C[obase+m, :] = sum_{k<n_per} P[b][k][m] * U[ibase+k, :]
// 64x128 tile, BK=32 (K zero-padded), 4 waves 2x2 (wave tile 32x64).
// ---------------------------------------------------------------------------
template <int TRANSP>
__global__ __launch_bounds__(256) void bgemm_mfma_kernel(
    const float* __restrict__ P, int ms, int n_per,
    const float* __restrict__ U, int ldu,
    float* __restrict__ C, int ldc)
{
    __shared__ __align__(16) u16 Ah[64 * TW];
    __shared__ __align__(16) u16 Al[64 * TW];
    __shared__ __align__(16) u16 Bh[128 * TW];
    __shared__ __align__(16) u16 Bl[128 * TW];
    const int b = blockIdx.z;
    const float* Pb = P + (size_t)b * ms * ms;
    const int qbase = (2 * b) * n_per, cbase = (2 * b + 1) * n_per;
    const int obase = TRANSP ? cbase : qbase;
    const int ibase = TRANSP ? qbase : cbase;
    const int bm = blockIdx.y * 64, bn = blockIdx.x * 128;
    const int tid = threadIdx.x, lane = tid & 63, wave = tid >> 6;
    const int wm = wave >> 1, wn = wave & 1;
    const int l15 = lane & 15, lq = lane >> 4;
    const int sar = tid >> 2, sak = (tid & 3) * 8;
    const int sbn = tid >> 1, sbk = (tid & 1) * 16;
    const int Kpad = (n_per + 31) & ~31;

    floatx4 acc[2][4];
    #pragma unroll
    for (int i = 0; i < 2; i++)
        #pragma unroll
        for (int j = 0; j < 4; j++) acc[i][j] = (floatx4){0.f, 0.f, 0.f, 0.f};

    for (int k0 = 0; k0 < Kpad; k0 += 32) {
        {
            u16 ph[8], pl8[8];
            const int m = bm + sar;
            #pragma unroll
            for (int i = 0; i < 8; i++) {
                int kk = k0 + sak + i;
                float v = 0.f;
                if (kk < n_per && m < n_per)
                    v = TRANSP ? Pb[(size_t)kk * ms + m] : Pb[(size_t)m * ms + kk];
                u16 h = f2bf(v);
                ph[i] = h; pl8[i] = f2bf(v - bf2f(h));
            }
            *(uint4*)&Ah[sar * TW + sak] = *(const uint4*)&ph[0];
            *(uint4*)&Al[sar * TW + sak] = *(const uint4*)&pl8[0];
        }
        {
            u16 qh[16], ql[16];
            #pragma unroll
            for (int i = 0; i < 16; i++) {
                int kk = k0 + sbk + i;
                float v = 0.f;
                if (kk < n_per) v = U[(size_t)(ibase + kk) * ldu + bn + sbn];
                u16 h = f2bf(v);
                qh[i] = h; ql[i] = f2bf(v - bf2f(h));
            }
            *(uint4*)&Bh[sbn * TW + sbk]     = *(const uint4*)&qh[0];
            *(uint4*)&Bh[sbn * TW + sbk + 8] = *(const uint4*)&qh[8];
            *(uint4*)&Bl[sbn * TW + sbk]     = *(const uint4*)&ql[0];
            *(uint4*)&Bl[sbn * TW + sbk + 8] = *(const uint4*)&ql[8];
        }
        __syncthreads();
        short8 afh[2], afl[2], bfh[4], bfl[4];
        #pragma unroll
        for (int i = 0; i < 2; i++) {
            const int ro = (wm * 32 + i * 16 + l15) * TW + lq * 8;
            afh[i] = *(const short8*)&Ah[ro];
            afl[i] = *(const short8*)&Al[ro];
        }
        #pragma unroll
        for (int j = 0; j < 4; j++) {
            const int ro = (wn * 64 + j * 16 + l15) * TW + lq * 8;
            bfh[j] = *(const short8*)&Bh[ro];
            bfl[j] = *(const short8*)&Bl[ro];
        }
        #pragma unroll
        for (int i = 0; i < 2; i++)
            #pragma unroll
            for (int j = 0; j < 4; j++) {
                acc[i][j] = __builtin_amdgcn_mfma_f32_16x16x32_bf16(afh[i], bfl[j], acc[i][j], 0, 0, 0);
                acc[i][j] = __builtin_amdgcn_mfma_f32_16x16x32_bf16(afl[i], bfh[j], acc[i][j], 0, 0, 0);
                acc[i][j] = __builtin_amdgcn_mfma_f32_16x16x32_bf16(afh[i], bfh[j], acc[i][j], 0, 0, 0);
            }
        __syncthreads();
    }
    #pragma unroll
    for (int j = 0; j < 4; j++) {
        const int col = bn + wn * 64 + j * 16 + l15;
        #pragma unroll
        for (int i = 0; i < 2; i++) {
            const int row0 = bm + wm * 32 + i * 16 + lq * 4;
            #pragma unroll
            for (int r = 0; r < 4; r++) {
                const int m = row0 + r;
                if (m < n_per)
                    C[(size_t)(obase + m) * ldc + col] = acc[i][j][r];
            }
        }
    }
}

static inline void bgemmM(hipStream_t s, bool transp, const float* P, int ms, int n_per,
                          const float* U, int ldu, float* C, int ldc, int N)
{
    dim3 grid(N / 128, (n_per + 63) / 64, Bb);
    if (transp) bgemm_mfma_kernel<1><<<grid, 256, 0, s>>>(P, ms, n_per, U, ldu, C, ldc);
    else        bgemm_mfma_kernel<0><<<grid, 256, 0, s>>>(P, ms, n_per, U, ldu, C, ldc);
}

// ---------------------------------------------------------------------------
// Fused node transport: la (64x64 from fp32 ttreal, padded-row guards) +
// 10 Sinkhorn iters in LDS + plan=exp write. One block per graph pair.
// ---------------------------------------------------------------------------
__global__ __launch_bounds__(256) void la_sinkhorn64_kernel(
    const float* __restrict__ tt, float* __restrict__ n_la)
{
    const int b = blockIdx.x;
    __shared__ float Aq[64][65];
    __shared__ float Ac[64][65];
    __shared__ float m[64][65];
    __shared__ float red[64];
    const int tid = threadIdx.x;
    for (int idx = tid; idx < 4096; idx += 256) {
        int r = idx >> 6, s = idx & 63;
        float vq = 0.f, vc = 0.f;
        if (r < Nn) {
            vq = tt[((size_t)(2 * b) * Nn + r) * Sdim + s];
            vc = tt[((size_t)(2 * b + 1) * Nn + r) * Sdim + s];
        }
        Aq[r][s] = vq;
        Ac[r][s] = vc;
    }
    __syncthreads();
    {
        const int tx = tid & 15, ty = tid >> 4;
        float acc[4][4] = {};
        for (int s = 0; s < 64; s++) {
            float a[4], c[4];
            #pragma unroll
            for (int i = 0; i < 4; i++) a[i] = Aq[ty * 4 + i][s];
            #pragma unroll
            for (int j = 0; j < 4; j++) c[j] = Ac[tx * 4 + j][s];
            #pragma unroll
            for (int i = 0; i < 4; i++)
                #pragma unroll
                for (int j = 0; j < 4; j++)
                    acc[i][j] = fmaf(a[i], c[j], acc[i][j]);
        }
        #pragma unroll
        for (int i = 0; i < 4; i++)
            #pragma unroll
            for (int j = 0; j < 4; j++)
                m[ty * 4 + i][tx * 4 + j] = acc[i][j] * INV_TEMP;
    }
    __syncthreads();
    for (int it = 0; it < 10; it++) {
        if (tid < 64) {
            float mx = -1e30f;
            for (int c = 0; c < 64; c++) mx = fmaxf(mx, m[tid][c]);
            float s = 0.f;
            for (int c = 0; c < 64; c++) s += __expf(m[tid][c] - mx);
            red[tid] = mx + __logf(s);
        }
        __syncthreads();
        for (int idx = tid; idx < 4096; idx += 256) m[idx >> 6][idx & 63] -= red[idx >> 6];
        __syncthreads();
        if (tid < 64) {
            float mx = -1e30f;
            for (int r = 0; r < 64; r++) mx = fmaxf(mx, m[r][tid]);
            float s = 0.f;
            for (int r = 0; r < 64; r++) s += __expf(m[r][tid] - mx);
            red[tid] = mx + __logf(s);
        }
        __syncthreads();
        for (int idx = tid; idx < 4096; idx += 256) m[idx >> 6][idx & 63] -= red[idx & 63];
        __syncthreads();
    }
    float* g = n_la + (size_t)b * 4096;
    for (int idx = tid; idx < 4096; idx += 256) g[idx] = __expf(m[idx >> 6][idx & 63]);
}

// la for edges (256x256): la[b][q][c] = 10 * tq[q]·tc[c], fp32 ttreal guarded.
__global__ __launch_bounds__(256) void la_gemm256_kernel(
    const float* __restrict__ tt, float* __restrict__ la)
{
    const int b = blockIdx.z;
    const int bm = blockIdx.y * 64, bn = blockIdx.x * 64;
    __shared__ float Aq[64][65];
    __shared__ float Ac[64][65];
    const int tid = threadIdx.x;
    for (int idx = tid; idx < 4096; idx += 256) {
        int r = idx >> 6, s = idx & 63;
        float vq = 0.f, vc = 0.f;
        int qr = bm + r, cr = bn + r;
        if (qr < Ee) vq = tt[((size_t)(2 * b) * Ee + qr) * Sdim + s];
        if (cr < Ee) vc = tt[((size_t)(2 * b + 1) * Ee + cr) * Sdim + s];
        Aq[r][s] = vq;
        Ac[r][s] = vc;
    }
    __syncthreads();
    const int tx = tid & 15, ty = tid >> 4;
    float acc[4][4] = {};
    for (int s = 0; s < 64; s++) {
        float a[4], c[4];
        #pragma unroll
        for (int i = 0; i < 4; i++) a[i] = Aq[ty * 4 + i][s];
        #pragma unroll
        for (int j = 0; j < 4; j++) c[j] = Ac[tx * 4 + j][s];
        #pragma unroll
        for (int i = 0; i < 4; i++)
            #pragma unroll
            for (int j = 0; j < 4; j++)
                acc[i][j] = fmaf(a[i], c[j], acc[i][j]);
    }
    #pragma unroll
    for (int i = 0; i < 4; i++)
        #pragma unroll
        for (int j = 0; j < 4; j++)
            la[((size_t)b * 256 + bm + ty * 4 + i) * 256 + bn + tx * 4 + j] = acc[i][j] * INV_TEMP;
}

// ---------------------------------------------------------------------------
// Sinkhorn 256x256, register-resident rows. Thread t: row r=t>>2, col-group
// cg=t&3 (64 cols in x[64] regs, loaded ONCE). u held in registers (4-lane
// butterfly gives the full row LSE to all 4 row-threads). Partials in
// part[16][4][68] / vv,cmx[4][68]: active lanes hit banks 0/4/8/12 -> no
// conflicts. Writes plan = exp(la - u - v) in-place at the end.
// ---------------------------------------------------------------------------
__global__ __launch_bounds__(1024) void sinkhorn256_kernel(float* __restrict__ la)
{
    const int b = blockIdx.x;
    float* g = la + (size_t)b * 65536;
    const int tid = threadIdx.x;
    const int r = tid >> 2, cg = tid & 3;
    const int lane = tid & 63;
    const int wv = tid >> 6;
    __shared__ float vv[4][68];
    __shared__ float cmx[4][68];
    __shared__ float part[16][4][68];

    // load row segment once
    float x[64];
    {
        const float4* rp = (const float4*)(g + (size_t)r * 256 + cg * 64);
        #pragma unroll
        for (int i = 0; i < 16; i++) {
            float4 v = rp[i];
            x[i * 4]     = v.x;
            x[i * 4 + 1] = v.y;
            x[i * 4 + 2] = v.z;
            x[i * 4 + 3] = v.w;
        }
    }
    if (tid < 272) ((float*)vv)[tid] = 0.f;
    __syncthreads();

    float ur = 0.f;
    for (int it = 0; it < 10; it++) {
        // ---- row phase: ur = LSE_c( x[c] - v[c] ), all in regs + 2 shuffles
        float mx = -1e30f;
        #pragma unroll
        for (int i = 0; i < 64; i++) mx = fmaxf(mx, x[i] - vv[cg][i]);
        mx = fmaxf(mx, __shfl_xor(mx, 1));
        mx = fmaxf(mx, __shfl_xor(mx, 2));
        float s = 0.f;
        #pragma unroll
        for (int i = 0; i < 64; i++) s += __expf(x[i] - vv[cg][i] - mx);
        s += __shfl_xor(s, 1);
        s += __shfl_xor(s, 2);
        ur = mx + __logf(s);
        // ---- col pass 1: column max of (x - ur - v)
        #pragma unroll
        for (int i = 0; i < 64; i += 4) {
            float m0 = x[i]     - ur - vv[cg][i];
            float m1 = x[i + 1] - ur - vv[cg][i + 1];
            float m2 = x[i + 2] - ur - vv[cg][i + 2];
            float m3 = x[i + 3] - ur - vv[cg][i + 3];
            #pragma unroll
            for (int d = 4; d < 64; d <<= 1) {
                m0 = fmaxf(m0, __shfl_xor(m0, d));
                m1 = fmaxf(m1, __shfl_xor(m1, d));
                m2 = fmaxf(m2, __shfl_xor(m2, d));
                m3 = fmaxf(m3, __shfl_xor(m3, d));
            }
            if (lane < 4)
                *(float4*)&part[wv][cg][i] = (float4){m0, m1, m2, m3};
        }
        __syncthreads();
        if (tid < 256) {
            const int c6 = tid >> 6, c0 = tid & 63;
            float mm = part[0][c6][c0];
            #pragma unroll
            for (int w = 1; w < 16; w++) mm = fmaxf(mm, part[w][c6][c0]);
            cmx[c6][c0] = mm;
        }
        __syncthreads();
        // ---- col pass 2: v[c] += cmx + log( sum_r exp(x - u - v - cmx) )
        #pragma unroll
        for (int i = 0; i < 64; i += 4) {
            float e0 = __expf(x[i]     - ur - vv[cg][i]     - cmx[cg][i]);
            float e1 = __expf(x[i + 1] - ur - vv[cg][i + 1] - cmx[cg][i + 1]);
            float e2 = __expf(x[i + 2] - ur - vv[cg][i + 2] - cmx[cg][i + 2]);
            float e3 = __expf(x[i + 3] - ur - vv[cg][i + 3] - cmx[cg][i + 3]);
            #pragma unroll
            for (int d = 4; d < 64; d <<= 1) {
                e0 += __shfl_xor(e0, d);
                e1 += __shfl_xor(e1, d);
                e2 += __shfl_xor(e2, d);
                e3 += __shfl_xor(e3, d);
            }
            if (lane < 4)
                *(float4*)&part[wv][cg][i] = (float4){e0, e1, e2, e3};
        }
        __syncthreads();
        if (tid < 256) {
            const int c6 = tid >> 6, c0 = tid & 63;
            float ss = part[0][c6][c0];
            #pragma unroll
            for (int w = 1; w < 16; w++) ss += part[w][c6][c0];
            vv[c6][c0] += cmx[c6][c0] + __logf(ss);
        }
        __syncthreads();
    }
    // plan = exp(x - u - v)
    float4* op = (float4*)(g + (size_t)r * 256 + cg * 64);
    #pragma unroll
    for (int i = 0; i < 16; i++) {
        float4 o;
        o.x = __expf(x[i * 4]     - ur - vv[cg][i * 4]);
        o.y = __expf(x[i * 4 + 1] - ur - vv[cg][i * 4 + 1]);
        o.z = __expf(x[i * 4 + 2] - ur - vv[cg][i * 4 + 2]);
        o.w = __expf(x[i * 4 + 3] - ur - vv[cg][i * 4 + 3]);
        op[i] = o;
    }
}

// ---------------------------------------------------------------------------
// Group-local message aggregation; P0/P1 packed in P01 (ld 512), fp32.
// ---------------------------------------------------------------------------
__global__ __launch_bounds__(256) void agg_kernel(
    const float* __restrict__ P01,
    const float* __restrict__ ec2,
    const int* __restrict__ from_idx, const int* __restrict__ to_idx,
    float* __restrict__ agg)
{
    const int gblk = blockIdx.x;
    const int d = threadIdx.x;
    __shared__ float acc[48][256];
    __shared__ int fr[192], to[192];
    #pragma unroll
    for (int n = 0; n < 48; n++) acc[n][d] = 0.f;
    if (d < 192) {
        fr[d] = from_idx[gblk * 192 + d] - gblk * 48;
        to[d] = to_idx[gblk * 192 + d] - gblk * 48;
    }
    __syncthreads();
    const int nb = gblk * 48;
    const int eb = gblk * 192;
    for (int e = 0; e < 192; e++) {
        int f = fr[e], t = to[e];
        float ee  = ec2[(size_t)(eb + e) * 256 + d];
        float p0f = P01[(size_t)(nb + f) * 512 + d];
        float p1f = P01[(size_t)(nb + f) * 512 + 256 + d];
        float p0t = P01[(size_t)(nb + t) * 512 + d];
        float p1t = P01[(size_t)(nb + t) * 512 + 256 + d];
        acc[t][d] += p0f + p1t + ee;
        acc[f][d] += p0t + p1f + ee;
    }
    __syncthreads();
    for (int n = 0; n < 48; n++) agg[(size_t)(nb + n) * 256 + d] = acc[n][d];
}

// In-place messages: m[e] <- Qs[from]+Qs[to]+2*m[e]
__global__ __launch_bounds__(256) void msgs_inplace_kernel(
    float* __restrict__ m, const float* __restrict__ Qs,
    const int* __restrict__ from_idx, const int* __restrict__ to_idx)
{
    const int e = blockIdx.x;
    const int d = threadIdx.x;
    const int f = from_idx[e], t = to_idx[e];
    size_t o = (size_t)e * 256 + d;
    m[o] = Qs[(size_t)f * 256 + d] + Qs[(size_t)t * 256 + d] + 2.f * m[o];
}

// Wsum = msg_W[0:128] + msg_W[128:256]
__global__ void wsum_kernel(const float* __restrict__ msg_W, float* __restrict__ Wsum)
{
    int idx = blockIdx.x * 256 + threadIdx.x;
    Wsum[idx] = msg_W[idx] + msg_W[32768 + idx];
}

__global__ void diag_kernel(float* __restrict__ out, float v)
{
    out[threadIdx.x] = v;
}

// score[b] = -sum relu( ffq - plan@ffc )
__global__ __launch_bounds__(128) void score_kernel(
    const float* __restrict__ upd_node, const float* __restrict__ plan,
    float* __restrict__ out)
{
    const int b = blockIdx.x;
    const int tid = threadIdx.x;
    __shared__ float ffc[48][128];
    __shared__ float pl[64][48];
    __shared__ float red[128];
    for (int c = 0; c < 48; c++)
        ffc[c][tid] = upd_node[(size_t)((2 * b + 1) * 48 + c) * 640 + 512 + tid];
    for (int idx = tid; idx < 64 * 48; idx += 128) {
        int q = idx / 48, c = idx % 48;
        pl[q][c] = plan[(size_t)b * 4096 + q * 64 + c];
    }
    __syncthreads();
    float accv = 0.f;
    for (int q = 0; q < 64; q++) {
        float rsum = 0.f;
        #pragma unroll 8
        for (int c = 0; c < 48; c++) rsum = fmaf(pl[q][c], ffc[c][tid], rsum);
        float fq = 0.f;
        if (q < 48) fq = upd_node[(size_t)((2 * b) * 48 + q) * 640 + 512 + tid];
        accv += fmaxf(fq - rsum, 0.f);
    }
    red[tid] = accv;
    __syncthreads();
    for (int sft = 64; sft > 0; sft >>= 1) {
        if (tid < sft) red[tid] += red[tid + sft];
        __syncthreads();
    }
    if (tid == 0) out[b] = -red[0];
}

// ---------------------------------------------------------------------------
// Workspace layout (floats). Total 66,265,088 floats = 265.1 MB <= 268.4 MB.
// ---------------------------------------------------------------------------
#define OFF_UPD_NODE   0ULL
#define OFF_NODE_STORE 3932160ULL
#define OFF_EDGE_STORE 7077888ULL
#define OFF_ECOMB      32243712ULL
#define OFF_ENC_N      47972352ULL
#define OFF_ENC_E      48758784ULL
#define OFF_N_LA       51904512ULL
#define OFF_WSUM       52166656ULL
#define OFF_WT         52199424ULL
#define OFF_WTL        52547584ULL
#define OFF_ARENA      52895744ULL
#define TOTAL_FLOATS   66265088ULL

// bf16 weight sub-offsets (u16 from WT/WTL base)
#define WT_NIW1   0
#define WT_NIW2   65536
#define WT_EIW1   98304
#define WT_EIW2   245760
#define WT_MSG    294912
#define WT_P01    393216
#define WT_NUW1   458752
#define WT_NUW2   557056
#define WT_WSUM   589824
#define WT_ENCN   622592
#define WT_ENCE   626688
#define WT_NS1    630784
#define WT_NS2    647168
#define WT_ES1    655360
#define WT_ES2    688128

extern "C" void kernel_launch(void* const* d_in, const int* in_sizes, int n_in,
                              void* d_out, int out_size, void* d_ws, size_t ws_size,
                              hipStream_t stream)
{
    (void)in_sizes; (void)n_in; (void)out_size;
    if (ws_size < TOTAL_FLOATS * sizeof(float)) {
        diag_kernel<<<1, 64, 0, stream>>>((float*)d_out, (float)ws_size);
        return;
    }

    const float* node_features = (const float*)d_in[0];
    const float* edge_features = (const float*)d_in[1];
    const int*   from_idx      = (const int*)d_in[2];
    const int*   to_idx        = (const int*)d_in[3];
    const float* enc_node_W = (const float*)d_in[4];
    const float* enc_node_b = (const float*)d_in[5];
    const float* enc_edge_W = (const float*)d_in[6];
    const float* enc_edge_b = (const float*)d_in[7];
    const float* ni_W1 = (const float*)d_in[8];
    const float* ni_b1 = (const float*)d_in[9];
    const float* ni_W2 = (const float*)d_in[10];
    const float* ni_b2 = (const float*)d_in[11];
    const float* ei_W1 = (const float*)d_in[12];
    const float* ei_b1 = (const float*)d_in[13];
    const float* ei_W2 = (const float*)d_in[14];
    const float* ei_b2 = (const float*)d_in[15];
    const float* msg_W = (const float*)d_in[16];
    const float* msg_b = (const float*)d_in[17];
    const float* nu_W1 = (const float*)d_in[18];
    const float* nu_b1 = (const float*)d_in[19];
    const float* nu_W2 = (const float*)d_in[20];
    const float* nu_b2 = (const float*)d_in[21];
    const float* ns_W1 = (const float*)d_in[22];
    const float* ns_b1 = (const float*)d_in[23];
    const float* ns_W2 = (const float*)d_in[24];
    const float* ns_b2 = (const float*)d_in[25];
    const float* es_W1 = (const float*)d_in[26];
    const float* es_b1 = (const float*)d_in[27];
    const float* es_W2 = (const float*)d_in[28];
    const float* es_b2 = (const float*)d_in[29];

    float* ws = (float*)d_ws;
    float* upd_node   = ws + OFF_UPD_NODE;
    float* node_store = ws + OFF_NODE_STORE;
    float* edge_store = ws + OFF_EDGE_STORE;
    float* ecomb      = ws + OFF_ECOMB;
    float* enc_n      = ws + OFF_ENC_N;
    float* enc_e      = ws + OFF_ENC_E;
    float* n_la       = ws + OFF_N_LA;
    float* Wsum       = ws + OFF_WSUM;
    u16* WT  = (u16*)(ws + OFF_WT);
    u16* WTL = (u16*)(ws + OFF_WTL);
    float* arena      = ws + OFF_ARENA;

    // Phase-A arena carve (ehid dead before ec2 is written -> alias)
    float* A_hidden = arena;                  // VN x 256
    float* A_hcomb  = arena + 1572864;        // VN x 128
    float* A_ehid   = arena + 2359296;        // VE x 384
    float* A_ec2    = arena + 2359296;        // VE x 256 (alias)
    float* A_P01    = arena + 8650752;        // VN x 512
    float* A_aggb   = arena + 11796480;       // VN x 256
    // Phase-B arena carve
    float* B_ec2msgs  = arena;                // VE x 256
    float* B_ttreal_e = arena;                // VE x 64 (after msgs consumed)
    float* B_Qs       = arena + 6291456;      // VN x 256 (also thid_e VE x 64)
    float* B_ela      = arena + 7864320;      // 64 x 256 x 256
    float* B_thid_n   = arena + 12058624;     // VN x 64
    float* B_ttreal_n = arena + 12451840;     // VN x 64

    // --- one-time weight prep ---
    auto tcv = [&](const float* src, int K, int N, int Npad, int wtoff, int ldk, int noff) {
        transpose_cvt_kernel<<<(K * Npad + 255) / 256, 256, 0, stream>>>(
            src, K, N, Npad, WT + wtoff, WTL + wtoff, ldk, noff);
    };
    wsum_kernel<<<32768 / 256, 256, 0, stream>>>(msg_W, Wsum);
    tcv(ni_W1, 256, 256, 256, WT_NIW1, 256, 0);
    tcv(ni_W2, 256, 128, 128, WT_NIW2, 256, 0);
    tcv(ei_W1, 384, 384, 384, WT_EIW1, 384, 0);
    tcv(ei_W2, 384, 128, 128, WT_EIW2, 384, 0);
    tcv(msg_W, 384, 256, 256, WT_MSG, 384, 0);
    tcv(msg_W, 128, 256, 256, WT_P01, 128, 0);
    tcv(msg_W + (size_t)128 * 256, 128, 256, 256, WT_P01, 128, 256);
    tcv(nu_W1, 384, 256, 256, WT_NUW1, 384, 0);
    tcv(nu_W2, 256, 128, 128, WT_NUW2, 256, 0);
    tcv(Wsum, 128, 256, 256, WT_WSUM, 128, 0);
    tcv(enc_node_W, 32, 128, 128, WT_ENCN, 32, 0);
    tcv(enc_edge_W, 32, 128, 128, WT_ENCE, 32, 0);
    tcv(ns_W1, 128, 64, 128, WT_NS1, 128, 0);
    tcv(ns_W2, 64, 64, 128, WT_NS2, 64, 0);
    tcv(es_W1, 256, 64, 128, WT_ES1, 256, 0);
    tcv(es_W2, 64, 64, 128, WT_ES2, 64, 0);

    // --- encoders ---
    gemmM(stream, node_features, 32, 32, nullptr, 0, 0, WT + WT_ENCN, WTL + WT_ENCN, 32,
          enc_node_b, enc_n, 128, VNn, 128, 128, false);
    gemmM(stream, edge_features, 32, 32, nullptr, 0, 0, WT + WT_ENCE, WTL + WT_ENCE, 32,
          enc_edge_b, enc_e, 128, VEe, 128, 128, false);

    for (int k = 0; k < 3; k++) {
        for (int p = 1; p <= 5; p++) {
            const bool hs = (k > 0) && (p > 1);
            // h_comb = mlp2([h, node_store slot p-1], ni)
            if (p == 1)
                gemmM(stream, enc_n, 128, 128,
                      hs ? node_store + (size_t)(p - 2) * 128 : nullptr, 512, hs ? 128 : 0,
                      WT + WT_NIW1, WTL + WT_NIW1, 256, ni_b1,
                      A_hidden, 256, VNn, 256, 256, true);
            else
                gemmM(stream, upd_node + (size_t)(p - 2) * 128, 640, 128,
                      hs ? node_store + (size_t)(p - 2) * 128 : nullptr, 512, hs ? 128 : 0,
                      WT + WT_NIW1, WTL + WT_NIW1, 256, ni_b1,
                      A_hidden, 256, VNn, 256, 256, true);
            gemmM(stream, A_hidden, 256, 256, nullptr, 0, 0, WT + WT_NIW2, WTL + WT_NIW2, 256,
                  ni_b2, A_hcomb, 128, VNn, 128, 128, false);
            // e_comb = mlp2([enc_e, edge_store slot p-1], ei) -> ecomb slot p
            float* ec_slot = ecomb + (size_t)(p - 1) * VEe * 128;
            gemmM(stream, enc_e, 128, 128,
                  hs ? edge_store + (size_t)(p - 2) * 256 : nullptr, 1024, hs ? 256 : 0,
                  WT + WT_EIW1, WTL + WT_EIW1, 384, ei_b1,
                  A_ehid, 384, VEe, 384, 384, true);
            gemmM(stream, A_ehid, 384, 384, nullptr, 0, 0, WT + WT_EIW2, WTL + WT_EIW2, 384,
                  ei_b2, ec_slot, 128, VEe, 128, 128, false);
            // ec2 = e_comb @ msg_W[256:384] + msg_b (aliases dead ehid)
            gemmM(stream, ec_slot, 128, 128, nullptr, 0, 0,
                  WT + WT_MSG + 256, WTL + WT_MSG + 256, 384,
                  msg_b, A_ec2, 256, VEe, 256, 256, false);
            // P01 = h_comb @ [W0|W1]
            gemmM(stream, A_hcomb, 128, 128, nullptr, 0, 0, WT + WT_P01, WTL + WT_P01, 128,
                  nullptr, A_P01, 512, VNn, 512, 512, false);
            agg_kernel<<<NGg, 256, 0, stream>>>(A_P01, A_ec2, from_idx, to_idx, A_aggb);
            // h = mlp2([h_comb, agg], nu) -> upd_node slot p
            gemmM(stream, A_hcomb, 128, 128, A_aggb, 256, 256, WT + WT_NUW1, WTL + WT_NUW1, 384,
                  nu_b1, A_hidden, 256, VNn, 256, 256, true);
            gemmM(stream, A_hidden, 256, 256, nullptr, 0, 0, WT + WT_NUW2, WTL + WT_NUW2, 256,
                  nu_b2, upd_node + (size_t)(p - 1) * 128, 640, VNn, 128, 128, false);
        }
        // ---- node transport (fused la + sinkhorn) ----
        gemmM(stream, upd_node + 512, 640, 128, nullptr, 0, 0, WT + WT_NS1, WTL + WT_NS1, 128,
              ns_b1, B_thid_n, 64, VNn, 128, 64, true);
        gemmM(stream, B_thid_n, 64, 64, nullptr, 0, 0, WT + WT_NS2, WTL + WT_NS2, 64,
              ns_b2, B_ttreal_n, 64, VNn, 128, 64, false);
        la_sinkhorn64_kernel<<<Bb, 256, 0, stream>>>(B_ttreal_n, n_la);
        if (k < 2) {
            bgemmM(stream, false, n_la, 64, 48, upd_node, 640, node_store, 512, 512);
            bgemmM(stream, true,  n_la, 64, 48, upd_node, 640, node_store, 512, 512);
            // ---- edge transport: msgs slot 5 for es features ----
            gemmM(stream, ecomb + (size_t)4 * VEe * 128, 128, 128, nullptr, 0, 0,
                  WT + WT_MSG + 256, WTL + WT_MSG + 256, 384,
                  msg_b, B_ec2msgs, 256, VEe, 256, 256, false);
            gemmM(stream, upd_node + 512, 640, 128, nullptr, 0, 0,
                  WT + WT_WSUM, WTL + WT_WSUM, 128,
                  nullptr, B_Qs, 256, VNn, 256, 256, false);
            msgs_inplace_kernel<<<VEe, 256, 0, stream>>>(B_ec2msgs, B_Qs, from_idx, to_idx);
            gemmM(stream, B_ec2msgs, 256, 256, nullptr, 0, 0, WT + WT_ES1, WTL + WT_ES1, 256,
                  es_b1, B_Qs /*thid_e*/, 64, VEe, 128, 64, true);
            gemmM(stream, B_Qs, 64, 64, nullptr, 0, 0, WT + WT_ES2, WTL + WT_ES2, 64,
                  es_b2, B_ttreal_e, 64, VEe, 128, 64, false);
            la_gemm256_kernel<<<dim3(4, 4, Bb), 256, 0, stream>>>(B_ttreal_e, B_ela);
            sinkhorn256_kernel<<<Bb, 1024, 0, stream>>>(B_ela);
            for (int sl = 1; sl <= 4; sl++) {
                gemmM(stream, ecomb + (size_t)(sl - 1) * VEe * 128, 128, 128, nullptr, 0, 0,
                      WT + WT_MSG + 256, WTL + WT_MSG + 256, 384,
                      msg_b, B_ec2msgs, 256, VEe, 256, 256, false);
                gemmM(stream, upd_node + (size_t)(sl - 1) * 128, 640, 128, nullptr, 0, 0,
                      WT + WT_WSUM, WTL + WT_WSUM, 128,
                      nullptr, B_Qs, 256, VNn, 256, 256, false);
                msgs_inplace_kernel<<<VEe, 256, 0, stream>>>(B_ec2msgs, B_Qs, from_idx, to_idx);
                bgemmM(stream, false, B_ela, 256, 192, B_ec2msgs, 256,
                       edge_store + (size_t)(sl - 1) * 256, 1024, 256);
                bgemmM(stream, true,  B_ela, 256, 192, B_ec2msgs, 256,
                       edge_store + (size_t)(sl - 1) * 256, 1024, 256);
            }
        }
    }
    score_kernel<<<Bb, 128, 0, stream>>>(upd_node, n_la, (float*)d_out);
}

// Round 9
// 4395.303 us; speedup vs baseline: 1.3153x; 1.1098x over previous
//
#include <hip/hip_runtime.h>
#include <cstdint>
#include <cstddef>

// Problem constants (from reference)
#define NGg   128     // 2*B
#define Bb    64
#define Nn    48
#define Ee    192
#define Sdim  64
#define VNn   6144    // NGg*Nn
#define VEe   24576   // NGg*Ee
#define INV_TEMP 10.0f

typedef unsigned short u16;
typedef __attribute__((ext_vector_type(8))) short short8;
typedef __attribute__((ext_vector_type(4))) float floatx4;

// round-to-nearest-even fp32 -> bf16
__device__ __forceinline__ u16 f2bf(float f)
{
    unsigned int u = __float_as_uint(f);
    u += 0x7FFFu + ((u >> 16) & 1u);
    return (u16)(u >> 16);
}
__device__ __forceinline__ float bf2f(u16 h)
{
    return __uint_as_float(((unsigned int)h) << 16);
}

// ---------------------------------------------------------------------------
// Split-precision bf16x3 MFMA GEMM ("emulated fp32"):
//   C = maybeReLU( (A_hi+A_lo) @ (W_hi+W_lo) + bias ),  dropping lo*lo.
// 128x128 tile, BK=32, 4 waves 2x2, wave = 4x4 mfma 16x16x32 x3.
// ---------------------------------------------------------------------------
#define TW 40
__global__ __launch_bounds__(256) void gemm_mfma_kernel(
    const float* __restrict__ A1, int lda1, int K1,
    const float* __restrict__ A2, int lda2, int K2,
    const u16* __restrict__ Wh, const u16* __restrict__ Wl, int ldwt,
    const float* __restrict__ bias,
    float* __restrict__ C, int ldc,
    int Ncap, int relu)
{
    __shared__ __align__(16) u16 Ah[128 * TW];
    __shared__ __align__(16) u16 Al[128 * TW];
    __shared__ __align__(16) u16 Bh[128 * TW];
    __shared__ __align__(16) u16 Bl[128 * TW];
    const int tid = threadIdx.x;
    const int lane = tid & 63, wave = tid >> 6;
    const int wm = wave >> 1, wn = wave & 1;
    const int bm = blockIdx.y * 128, bn = blockIdx.x * 128;
    const int K = K1 + K2;
    const int srow = tid >> 1;
    const int skoff = (tid & 1) * 16;

    floatx4 acc[4][4];
    #pragma unroll
    for (int i = 0; i < 4; i++)
        #pragma unroll
        for (int j = 0; j < 4; j++) acc[i][j] = (floatx4){0.f, 0.f, 0.f, 0.f};

    const int arow = bm + srow;
    const int brow = bn + srow;
    const int l15 = lane & 15, lq = lane >> 4;

    for (int k0 = 0; k0 < K; k0 += 32) {
        const int kk = k0 + skoff;
        const float* asrc = (kk < K1) ? (A1 + (size_t)arow * lda1 + kk)
                                      : (A2 + (size_t)arow * lda2 + (kk - K1));
        float f[16];
        ((float4*)f)[0] = ((const float4*)asrc)[0];
        ((float4*)f)[1] = ((const float4*)asrc)[1];
        ((float4*)f)[2] = ((const float4*)asrc)[2];
        ((float4*)f)[3] = ((const float4*)asrc)[3];
        u16 ph[16], pl8[16];
        #pragma unroll
        for (int q = 0; q < 16; q++) {
            u16 h = f2bf(f[q]);
            ph[q] = h;
            pl8[q] = f2bf(f[q] - bf2f(h));
        }
        *(uint4*)&Ah[srow * TW + skoff]     = *(const uint4*)&ph[0];
        *(uint4*)&Ah[srow * TW + skoff + 8] = *(const uint4*)&ph[8];
        *(uint4*)&Al[srow * TW + skoff]     = *(const uint4*)&pl8[0];
        *(uint4*)&Al[srow * TW + skoff + 8] = *(const uint4*)&pl8[8];
        const u16* bh = Wh + (size_t)brow * ldwt + kk;
        const u16* bl = Wl + (size_t)brow * ldwt + kk;
        *(uint4*)&Bh[srow * TW + skoff]     = ((const uint4*)bh)[0];
        *(uint4*)&Bh[srow * TW + skoff + 8] = ((const uint4*)bh)[1];
        *(uint4*)&Bl[srow * TW + skoff]     = ((const uint4*)bl)[0];
        *(uint4*)&Bl[srow * TW + skoff + 8] = ((const uint4*)bl)[1];
        __syncthreads();
        short8 afh[4], afl[4], bfh[4], bfl[4];
        #pragma unroll
        for (int i = 0; i < 4; i++) {
            const int ro = (wm * 64 + i * 16 + l15) * TW + lq * 8;
            afh[i] = *(const short8*)&Ah[ro];
            afl[i] = *(const short8*)&Al[ro];
        }
        #pragma unroll
        for (int j = 0; j < 4; j++) {
            const int ro = (wn * 64 + j * 16 + l15) * TW + lq * 8;
            bfh[j] = *(const short8*)&Bh[ro];
            bfl[j] = *(const short8*)&Bl[ro];
        }
        #pragma unroll
        for (int i = 0; i < 4; i++)
            #pragma unroll
            for (int j = 0; j < 4; j++) {
                acc[i][j] = __builtin_amdgcn_mfma_f32_16x16x32_bf16(afh[i], bfl[j], acc[i][j], 0, 0, 0);
                acc[i][j] = __builtin_amdgcn_mfma_f32_16x16x32_bf16(afl[i], bfh[j], acc[i][j], 0, 0, 0);
                acc[i][j] = __builtin_amdgcn_mfma_f32_16x16x32_bf16(afh[i], bfh[j], acc[i][j], 0, 0, 0);
            }
        __syncthreads();
    }
    #pragma unroll
    for (int j = 0; j < 4; j++) {
        const int col = bn + wn * 64 + j * 16 + l15;
        const bool cok = (col < Ncap);
        const float bv = (bias && cok) ? bias[col] : 0.f;
        #pragma unroll
        for (int i = 0; i < 4; i++) {
            const int row0 = bm + wm * 64 + i * 16 + lq * 4;
            #pragma unroll
            for (int r = 0; r < 4; r++) {
                float v = acc[i][j][r] + bv;
                if (relu) v = fmaxf(v, 0.f);
                if (cok) C[(size_t)(row0 + r) * ldc + col] = v;
            }
        }
    }
}

static inline void gemmM(hipStream_t s,
                         const float* A1, int lda1, int K1,
                         const float* A2, int lda2, int K2,
                         const u16* Wh, const u16* Wl, int ldwt,
                         const float* bias,
                         float* C, int ldc, int M, int Ngrid, int Ncap, bool relu)
{
    dim3 grid(Ngrid / 128, M / 128);
    gemm_mfma_kernel<<<grid, 256, 0, s>>>(A1, lda1, K1, A2, lda2, K2, Wh, Wl, ldwt,
                                          bias, C, ldc, Ncap, relu ? 1 : 0);
}

// dst_{hi,lo}[(noff+n)*ldk + k] = split bf16 of src[k*N + n]; n>=N pads zero.
__global__ void transpose_cvt_kernel(const float* __restrict__ src, int K, int N,
                                     int Npad,
                                     u16* __restrict__ dst_hi, u16* __restrict__ dst_lo,
                                     int ldk, int noff)
{
    int idx = blockIdx.x * 256 + threadIdx.x;
    if (idx >= K * Npad) return;
    int k = idx / Npad, n = idx % Npad;
    float v = (n < N) ? src[(size_t)k * N + n] : 0.f;
    u16 h = f2bf(v);
    size_t o = (size_t)(noff + n) * ldk + k;
    dst_hi[o] = h;
    dst_lo[o] = f2bf(v - bf2f(h));
}

// ---------------------------------------------------------------------------
// Dual batched MFMA plan-GEMM: one launch does qi (transp=0) and ci
// (transp=1) halves of the x-grid. bf16x3 split; fp32 in/out.
// 64x128 tile, BK=32, wave tile 32x64.
// ---------------------------------------------------------------------------
__global__ __launch_bounds__(256) void bgemm_dual_kernel(
    const float* __restrict__ P, int ms, int n_per,
    const float* __restrict__ U, int ldu,
    float* __restrict__ C, int ldc, int nxh)
{
    __shared__ __align__(16) u16 Ah[64 * TW];
    __shared__ __align__(16) u16 Al[64 * TW];
    __shared__ __align__(16) u16 Bh[128 * TW];
    __shared__ __align__(16) u16 Bl[128 * TW];
    const int b = blockIdx.z;
    const float* Pb = P + (size_t)b * ms * ms;
    const int bxr = blockIdx.x;
    const int transp = (bxr >= nxh) ? 1 : 0;
    const int bn = (bxr - transp * nxh) * 128;
    const int qbase = (2 * b) * n_per, cbase = (2 * b + 1) * n_per;
    const int obase = transp ? cbase : qbase;
    const int ibase = transp ? qbase : cbase;
    const int bm = blockIdx.y * 64;
    const int tid = threadIdx.x, lane = tid & 63, wave = tid >> 6;
    const int wm = wave >> 1, wn = wave & 1;
    const int l15 = lane & 15, lq = lane >> 4;
    const int sar = tid >> 2, sak = (tid & 3) * 8;
    const int sbn = tid >> 1, sbk = (tid & 1) * 16;
    const int Kpad = (n_per + 31) & ~31;

    floatx4 acc[2][4];
    #pragma unroll
    for (int i = 0; i < 2; i++)
        #pragma unroll
        for (int j = 0; j < 4; j++) acc[i][j] = (floatx4){0.f, 0.f, 0.f, 0.f};

    for (int k0 = 0; k0 < Kpad; k0 += 32) {
        {
            u16 ph[8], pl8[8];
            const int m = bm + sar;
            #pragma unroll
            for (int i = 0; i < 8; i++) {
                int kk = k0 + sak + i;
                float v = 0.f;
                if (kk < n_per && m < n_per)
                    v = transp ? Pb[(size_t)kk * ms + m] : Pb[(size_t)m * ms + kk];
                u16 h = f2bf(v);
                ph[i] = h; pl8[i] = f2bf(v - bf2f(h));
            }
            *(uint4*)&Ah[sar * TW + sak] = *(const uint4*)&ph[0];
            *(uint4*)&Al[sar * TW + sak] = *(const uint4*)&pl8[0];
        }
        {
            u16 qh[16], ql[16];
            #pragma unroll
            for (int i = 0; i < 16; i++) {
                int kk = k0 + sbk + i;
                float v = 0.f;
                if (kk < n_per) v = U[(size_t)(ibase + kk) * ldu + bn + sbn];
                u16 h = f2bf(v);
                qh[i] = h; ql[i] = f2bf(v - bf2f(h));
            }
            *(uint4*)&Bh[sbn * TW + sbk]     = *(const uint4*)&qh[0];
            *(uint4*)&Bh[sbn * TW + sbk + 8] = *(const uint4*)&qh[8];
            *(uint4*)&Bl[sbn * TW + sbk]     = *(const uint4*)&ql[0];
            *(uint4*)&Bl[sbn * TW + sbk + 8] = *(const uint4*)&ql[8];
        }
        __syncthreads();
        short8 afh[2], afl[2], bfh[4], bfl[4];
        #pragma unroll
        for (int i = 0; i < 2; i++) {
            const int ro = (wm * 32 + i * 16 + l15) * TW + lq * 8;
            afh[i] = *(const short8*)&Ah[ro];
            afl[i] = *(const short8*)&Al[ro];
        }
        #pragma unroll
        for (int j = 0; j < 4; j++) {
            const int ro = (wn * 64 + j * 16 + l15) * TW + lq * 8;
            bfh[j] = *(const short8*)&Bh[ro];
            bfl[j] = *(const short8*)&Bl[ro];
        }
        #pragma unroll
        for (int i = 0; i < 2; i++)
            #pragma unroll
            for (int j = 0; j < 4; j++) {
                acc[i][j] = __builtin_amdgcn_mfma_f32_16x16x32_bf16(afh[i], bfl[j], acc[i][j], 0, 0, 0);
                acc[i][j] = __builtin_amdgcn_mfma_f32_16x16x32_bf16(afl[i], bfh[j], acc[i][j], 0, 0, 0);
                acc[i][j] = __builtin_amdgcn_mfma_f32_16x16x32_bf16(afh[i], bfh[j], acc[i][j], 0, 0, 0);
            }
        __syncthreads();
    }
    #pragma unroll
    for (int j = 0; j < 4; j++) {
        const int col = bn + wn * 64 + j * 16 + l15;
        #pragma unroll
        for (int i = 0; i < 2; i++) {
            const int row0 = bm + wm * 32 + i * 16 + lq * 4;
            #pragma unroll
            for (int r = 0; r < 4; r++) {
                const int m = row0 + r;
                if (m < n_per)
                    C[(size_t)(obase + m) * ldc + col] = acc[i][j][r];
            }
        }
    }
}

static inline void bgemmDual(hipStream_t s, const float* P, int ms, int n_per,
                             const float* U, int ldu, float* C, int ldc, int N)
{
    int nxh = N / 128;
    dim3 grid(nxh * 2, (n_per + 63) / 64, Bb);
    bgemm_dual_kernel<<<grid, 256, 0, s>>>(P, ms, n_per, U, ldu, C, ldc, nxh);
}

// ---------------------------------------------------------------------------
// Fused node transport: la (64x64) + 10 Sinkhorn iters (potential form,
// register-resident, shift = previous potential) + plan=exp write.
// 256 thr = 4 waves; wave w owns rows 16w..16w+15; lane owns col `lane`.
// ---------------------------------------------------------------------------
__global__ __launch_bounds__(256) void la_sinkhorn64_kernel(
    const float* __restrict__ tt, float* __restrict__ n_la)
{
    const int b = blockIdx.x;
    __shared__ float Aq[64][65];
    __shared__ float Ac[64][65];
    __shared__ float m[64][65];
    __shared__ float v_s[64];
    __shared__ float part[4][64];
    const int tid = threadIdx.x;
    const int lane = tid & 63, w = tid >> 6;
    for (int idx = tid; idx < 4096; idx += 256) {
        int r = idx >> 6, s = idx & 63;
        float vq = 0.f, vc = 0.f;
        if (r < Nn) {
            vq = tt[((size_t)(2 * b) * Nn + r) * Sdim + s];
            vc = tt[((size_t)(2 * b + 1) * Nn + r) * Sdim + s];
        }
        Aq[r][s] = vq;
        Ac[r][s] = vc;
    }
    __syncthreads();
    {
        const int tx = tid & 15, ty = tid >> 4;
        float acc[4][4] = {};
        for (int s = 0; s < 64; s++) {
            float a[4], c[4];
            #pragma unroll
            for (int i = 0; i < 4; i++) a[i] = Aq[ty * 4 + i][s];
            #pragma unroll
            for (int j = 0; j < 4; j++) c[j] = Ac[tx * 4 + j][s];
            #pragma unroll
            for (int i = 0; i < 4; i++)
                #pragma unroll
                for (int j = 0; j < 4; j++)
                    acc[i][j] = fmaf(a[i], c[j], acc[i][j]);
        }
        #pragma unroll
        for (int i = 0; i < 4; i++)
            #pragma unroll
            for (int j = 0; j < 4; j++)
                m[ty * 4 + i][tx * 4 + j] = acc[i][j] * INV_TEMP;
    }
    if (tid < 64) v_s[tid] = 0.f;
    __syncthreads();
    // registers: x[j] = m[w*16+j][lane]
    float x[16], u[16];
    #pragma unroll
    for (int j = 0; j < 16; j++) x[j] = m[w * 16 + j][lane];
    #pragma unroll
    for (int j = 0; j < 16; j++) {
        float mx = x[j];
        #pragma unroll
        for (int d = 1; d < 64; d <<= 1) mx = fmaxf(mx, __shfl_xor(mx, d));
        u[j] = mx;  // iter-0 shift = rowmax
    }
    for (int it = 0; it < 10; it++) {
        float vr = v_s[lane];
        // row: u[j] += log( sum_c exp(x - v - u[j]) )
        #pragma unroll
        for (int j = 0; j < 16; j++) {
            float s = __expf(x[j] - vr - u[j]);
            #pragma unroll
            for (int d = 1; d < 64; d <<= 1) s += __shfl_xor(s, d);
            u[j] += __logf(s);
        }
        // col: v[c] += log( sum_r exp(x - u - v[c]) )
        float s = 0.f;
        #pragma unroll
        for (int j = 0; j < 16; j++) s += __expf(x[j] - u[j] - vr);
        part[w][lane] = s;
        __syncthreads();
        if (tid < 64) {
            float ss = part[0][tid] + part[1][tid] + part[2][tid] + part[3][tid];
            v_s[tid] += __logf(ss);
        }
        __syncthreads();
    }
    float vr = v_s[lane];
    float* g = n_la + (size_t)b * 4096;
    #pragma unroll
    for (int j = 0; j < 16; j++)
        g[(size_t)(w * 16 + j) * 64 + lane] = __expf(x[j] - u[j] - vr);
}

// la for edges (256x256): la[b][q][c] = 10 * tq[q]·tc[c], fp32 ttreal guarded.
__global__ __launch_bounds__(256) void la_gemm256_kernel(
    const float* __restrict__ tt, float* __restrict__ la)
{
    const int b = blockIdx.z;
    const int bm = blockIdx.y * 64, bn = blockIdx.x * 64;
    __shared__ float Aq[64][65];
    __shared__ float Ac[64][65];
    const int tid = threadIdx.x;
    for (int idx = tid; idx < 4096; idx += 256) {
        int r = idx >> 6, s = idx & 63;
        float vq = 0.f, vc = 0.f;
        int qr = bm + r, cr = bn + r;
        if (qr < Ee) vq = tt[((size_t)(2 * b) * Ee + qr) * Sdim + s];
        if (cr < Ee) vc = tt[((size_t)(2 * b + 1) * Ee + cr) * Sdim + s];
        Aq[r][s] = vq;
        Ac[r][s] = vc;
    }
    __syncthreads();
    const int tx = tid & 15, ty = tid >> 4;
    float acc[4][4] = {};
    for (int s = 0; s < 64; s++) {
        float a[4], c[4];
        #pragma unroll
        for (int i = 0; i < 4; i++) a[i] = Aq[ty * 4 + i][s];
        #pragma unroll
        for (int j = 0; j < 4; j++) c[j] = Ac[tx * 4 + j][s];
        #pragma unroll
        for (int i = 0; i < 4; i++)
            #pragma unroll
            for (int j = 0; j < 4; j++)
                acc[i][j] = fmaf(a[i], c[j], acc[i][j]);
    }
    #pragma unroll
    for (int i = 0; i < 4; i++)
        #pragma unroll
        for (int j = 0; j < 4; j++)
            la[((size_t)b * 256 + bm + ty * 4 + i) * 256 + bn + tx * 4 + j] = acc[i][j] * INV_TEMP;
}

// ---------------------------------------------------------------------------
// Sinkhorn 256x256, potential form with previous-potential shifts.
// 1024 thr = 16 waves; wave w owns rows 16w..16w+15; lane owns cols
// {lane, lane+64, lane+128, lane+192} (x[4][16] in regs, loaded once).
// u[16] per-wave in registers; v broadcast via LDS; col partials via one
// conflict-free LDS write per lane + 256-thread stage 2.
// ---------------------------------------------------------------------------
__global__ __launch_bounds__(1024) void sinkhorn256_kernel(float* __restrict__ la)
{
    const int b = blockIdx.x;
    float* g = la + (size_t)b * 65536;
    const int tid = threadIdx.x;
    const int lane = tid & 63, w = tid >> 6;
    __shared__ float v_s[256];
    __shared__ float part[16][64][5];  // [wave][lane][cc] stride-5 pad

    float x[4][16];
    #pragma unroll
    for (int cc = 0; cc < 4; cc++)
        #pragma unroll
        for (int j = 0; j < 16; j++)
            x[cc][j] = g[(size_t)(w * 16 + j) * 256 + cc * 64 + lane];

    float u[16];
    #pragma unroll
    for (int j = 0; j < 16; j++) {
        float mx = fmaxf(fmaxf(x[0][j], x[1][j]), fmaxf(x[2][j], x[3][j]));
        #pragma unroll
        for (int d = 1; d < 64; d <<= 1) mx = fmaxf(mx, __shfl_xor(mx, d));
        u[j] = mx;  // iter-0 shift = rowmax
    }
    if (tid < 256) v_s[tid] = 0.f;
    __syncthreads();

    for (int it = 0; it < 10; it++) {
        float vr[4];
        #pragma unroll
        for (int cc = 0; cc < 4; cc++) vr[cc] = v_s[cc * 64 + lane];
        // row: u[j] += log( sum_c exp(x - v - u[j]) )
        #pragma unroll
        for (int j = 0; j < 16; j++) {
            float s = __expf(x[0][j] - vr[0] - u[j]) + __expf(x[1][j] - vr[1] - u[j])
                    + __expf(x[2][j] - vr[2] - u[j]) + __expf(x[3][j] - vr[3] - u[j]);
            #pragma unroll
            for (int d = 1; d < 64; d <<= 1) s += __shfl_xor(s, d);
            u[j] += __logf(s);
        }
        // col partials: sum over this wave's 16 rows (pure registers)
        #pragma unroll
        for (int cc = 0; cc < 4; cc++) {
            float s = 0.f;
            #pragma unroll
            for (int j = 0; j < 16; j++) s += __expf(x[cc][j] - u[j] - vr[cc]);
            part[w][lane][cc] = s;
        }
        __syncthreads();
        if (tid < 256) {
            const int cl = tid & 63, cc = tid >> 6;
            float ss = 0.f;
            #pragma unroll
            for (int w2 = 0; w2 < 16; w2++) ss += part[w2][cl][cc];
            v_s[tid] += __logf(ss);
        }
        __syncthreads();
    }
    float vr[4];
    #pragma unroll
    for (int cc = 0; cc < 4; cc++) vr[cc] = v_s[cc * 64 + lane];
    #pragma unroll
    for (int cc = 0; cc < 4; cc++)
        #pragma unroll
        for (int j = 0; j < 16; j++)
            g[(size_t)(w * 16 + j) * 256 + cc * 64 + lane] = __expf(x[cc][j] - u[j] - vr[cc]);
}

// ---------------------------------------------------------------------------
// Group-local message aggregation; P0/P1 packed in P01 (ld 512), fp32.
// ---------------------------------------------------------------------------
__global__ __launch_bounds__(256) void agg_kernel(
    const float* __restrict__ P01,
    const float* __restrict__ ec2,
    const int* __restrict__ from_idx, const int* __restrict__ to_idx,
    float* __restrict__ agg)
{
    const int gblk = blockIdx.x;
    const int d = threadIdx.x;
    __shared__ float acc[48][256];
    __shared__ int fr[192], to[192];
    #pragma unroll
    for (int n = 0; n < 48; n++) acc[n][d] = 0.f;
    if (d < 192) {
        fr[d] = from_idx[gblk * 192 + d] - gblk * 48;
        to[d] = to_idx[gblk * 192 + d] - gblk * 48;
    }
    __syncthreads();
    const int nb = gblk * 48;
    const int eb = gblk * 192;
    for (int e = 0; e < 192; e++) {
        int f = fr[e], t = to[e];
        float ee  = ec2[(size_t)(eb + e) * 256 + d];
        float p0f = P01[(size_t)(nb + f) * 512 + d];
        float p1f = P01[(size_t)(nb + f) * 512 + 256 + d];
        float p0t = P01[(size_t)(nb + t) * 512 + d];
        float p1t = P01[(size_t)(nb + t) * 512 + 256 + d];
        acc[t][d] += p0f + p1t + ee;
        acc[f][d] += p0t + p1f + ee;
    }
    __syncthreads();
    for (int n = 0; n < 48; n++) agg[(size_t)(nb + n) * 256 + d] = acc[n][d];
}

// In-place messages: m[e] <- Qs[from]+Qs[to]+2*m[e]
__global__ __launch_bounds__(256) void msgs_inplace_kernel(
    float* __restrict__ m, const float* __restrict__ Qs,
    const int* __restrict__ from_idx, const int* __restrict__ to_idx)
{
    const int e = blockIdx.x;
    const int d = threadIdx.x;
    const int f = from_idx[e], t = to_idx[e];
    size_t o = (size_t)e * 256 + d;
    m[o] = Qs[(size_t)f * 256 + d] + Qs[(size_t)t * 256 + d] + 2.f * m[o];
}

// Wsum = msg_W[0:128] + msg_W[128:256]
__global__ void wsum_kernel(const float* __restrict__ msg_W, float* __restrict__ Wsum)
{
    int idx = blockIdx.x * 256 + threadIdx.x;
    Wsum[idx] = msg_W[idx] + msg_W[32768 + idx];
}

__global__ void diag_kernel(float* __restrict__ out, float v)
{
    out[threadIdx.x] = v;
}

// score[b] = -sum relu( ffq - plan@ffc )
__global__ __launch_bounds__(128) void score_kernel(
    const float* __restrict__ upd_node, const float* __restrict__ plan,
    float* __restrict__ out)
{
    const int b = blockIdx.x;
    const int tid = threadIdx.x;
    __shared__ float ffc[48][128];
    __shared__ float pl[64][48];
    __shared__ float red[128];
    for (int c = 0; c < 48; c++)
        ffc[c][tid] = upd_node[(size_t)((2 * b + 1) * 48 + c) * 640 + 512 + tid];
    for (int idx = tid; idx < 64 * 48; idx += 128) {
        int q = idx / 48, c = idx % 48;
        pl[q][c] = plan[(size_t)b * 4096 + q * 64 + c];
    }
    __syncthreads();
    float accv = 0.f;
    for (int q = 0; q < 64; q++) {
        float rsum = 0.f;
        #pragma unroll 8
        for (int c = 0; c < 48; c++) rsum = fmaf(pl[q][c], ffc[c][tid], rsum);
        float fq = 0.f;
        if (q < 48) fq = upd_node[(size_t)((2 * b) * 48 + q) * 640 + 512 + tid];
        accv += fmaxf(fq - rsum, 0.f);
    }
    red[tid] = accv;
    __syncthreads();
    for (int sft = 64; sft > 0; sft >>= 1) {
        if (tid < sft) red[tid] += red[tid + sft];
        __syncthreads();
    }
    if (tid == 0) out[b] = -red[0];
}

// ---------------------------------------------------------------------------
// Workspace layout (floats). Total 66,265,088 floats = 265.1 MB <= 268.4 MB.
// ---------------------------------------------------------------------------
#define OFF_UPD_NODE   0ULL
#define OFF_NODE_STORE 3932160ULL
#define OFF_EDGE_STORE 7077888ULL
#define OFF_ECOMB      32243712ULL
#define OFF_ENC_N      47972352ULL
#define OFF_ENC_E      48758784ULL
#define OFF_N_LA       51904512ULL
#define OFF_WSUM       52166656ULL
#define OFF_WT         52199424ULL
#define OFF_WTL        52547584ULL
#define OFF_ARENA      52895744ULL
#define TOTAL_FLOATS   66265088ULL

// bf16 weight sub-offsets (u16 from WT/WTL base)
#define WT_NIW1   0
#define WT_NIW2   65536
#define WT_EIW1   98304
#define WT_EIW2   245760
#define WT_MSG    294912
#define WT_P01    393216
#define WT_NUW1   458752
#define WT_NUW2   557056
#define WT_WSUM   589824
#define WT_ENCN   622592
#define WT_ENCE   626688
#define WT_NS1    630784
#define WT_NS2    647168
#define WT_ES1    655360
#define WT_ES2    688128

extern "C" void kernel_launch(void* const* d_in, const int* in_sizes, int n_in,
                              void* d_out, int out_size, void* d_ws, size_t ws_size,
                              hipStream_t stream)
{
    (void)in_sizes; (void)n_in; (void)out_size;
    if (ws_size < TOTAL_FLOATS * sizeof(float)) {
        diag_kernel<<<1, 64, 0, stream>>>((float*)d_out, (float)ws_size);
        return;
    }

    const float* node_features = (const float*)d_in[0];
    const float* edge_features = (const float*)d_in[1];
    const int*   from_idx      = (const int*)d_in[2];
    const int*   to_idx        = (const int*)d_in[3];
    const float* enc_node_W = (const float*)d_in[4];
    const float* enc_node_b = (const float*)d_in[5];
    const float* enc_edge_W = (const float*)d_in[6];
    const float* enc_edge_b = (const float*)d_in[7];
    const float* ni_W1 = (const float*)d_in[8];
    const float* ni_b1 = (const float*)d_in[9];
    const float* ni_W2 = (const float*)d_in[10];
    const float* ni_b2 = (const float*)d_in[11];
    const float* ei_W1 = (const float*)d_in[12];
    const float* ei_b1 = (const float*)d_in[13];
    const float* ei_W2 = (const float*)d_in[14];
    const float* ei_b2 = (const float*)d_in[15];
    const float* msg_W = (const float*)d_in[16];
    const float* msg_b = (const float*)d_in[17];
    const float* nu_W1 = (const float*)d_in[18];
    const float* nu_b1 = (const float*)d_in[19];
    const float* nu_W2 = (const float*)d_in[20];
    const float* nu_b2 = (const float*)d_in[21];
    const float* ns_W1 = (const float*)d_in[22];
    const float* ns_b1 = (const float*)d_in[23];
    const float* ns_W2 = (const float*)d_in[24];
    const float* ns_b2 = (const float*)d_in[25];
    const float* es_W1 = (const float*)d_in[26];
    const float* es_b1 = (const float*)d_in[27];
    const float* es_W2 = (const float*)d_in[28];
    const float* es_b2 = (const float*)d_in[29];

    float* ws = (float*)d_ws;
    float* upd_node   = ws + OFF_UPD_NODE;
    float* node_store = ws + OFF_NODE_STORE;
    float* edge_store = ws + OFF_EDGE_STORE;
    float* ecomb      = ws + OFF_ECOMB;
    float* enc_n      = ws + OFF_ENC_N;
    float* enc_e      = ws + OFF_ENC_E;
    float* n_la       = ws + OFF_N_LA;
    float* Wsum       = ws + OFF_WSUM;
    u16* WT  = (u16*)(ws + OFF_WT);
    u16* WTL = (u16*)(ws + OFF_WTL);
    float* arena      = ws + OFF_ARENA;

    // Phase-A arena carve (ehid dead before ec2 is written -> alias)
    float* A_hidden = arena;                  // VN x 256
    float* A_hcomb  = arena + 1572864;        // VN x 128
    float* A_ehid   = arena + 2359296;        // VE x 384
    float* A_ec2    = arena + 2359296;        // VE x 256 (alias)
    float* A_P01    = arena + 8650752;        // VN x 512
    float* A_aggb   = arena + 11796480;       // VN x 256
    // Phase-B arena carve
    float* B_ec2msgs  = arena;                // VE x 256
    float* B_ttreal_e = arena;                // VE x 64 (after msgs consumed)
    float* B_Qs       = arena + 6291456;      // VN x 256 (also thid_e VE x 64)
    float* B_ela      = arena + 7864320;      // 64 x 256 x 256
    float* B_thid_n   = arena + 12058624;     // VN x 64
    float* B_ttreal_n = arena + 12451840;     // VN x 64

    // --- one-time weight prep ---
    auto tcv = [&](const float* src, int K, int N, int Npad, int wtoff, int ldk, int noff) {
        transpose_cvt_kernel<<<(K * Npad + 255) / 256, 256, 0, stream>>>(
            src, K, N, Npad, WT + wtoff, WTL + wtoff, ldk, noff);
    };
    wsum_kernel<<<32768 / 256, 256, 0, stream>>>(msg_W, Wsum);
    tcv(ni_W1, 256, 256, 256, WT_NIW1, 256, 0);
    tcv(ni_W2, 256, 128, 128, WT_NIW2, 256, 0);
    tcv(ei_W1, 384, 384, 384, WT_EIW1, 384, 0);
    tcv(ei_W2, 384, 128, 128, WT_EIW2, 384, 0);
    tcv(msg_W, 384, 256, 256, WT_MSG, 384, 0);
    tcv(msg_W, 128, 256, 256, WT_P01, 128, 0);
    tcv(msg_W + (size_t)128 * 256, 128, 256, 256, WT_P01, 128, 256);
    tcv(nu_W1, 384, 256, 256, WT_NUW1, 384, 0);
    tcv(nu_W2, 256, 128, 128, WT_NUW2, 256, 0);
    tcv(Wsum, 128, 256, 256, WT_WSUM, 128, 0);
    tcv(enc_node_W, 32, 128, 128, WT_ENCN, 32, 0);
    tcv(enc_edge_W, 32, 128, 128, WT_ENCE, 32, 0);
    tcv(ns_W1, 128, 64, 128, WT_NS1, 128, 0);
    tcv(ns_W2, 64, 64, 128, WT_NS2, 64, 0);
    tcv(es_W1, 256, 64, 128, WT_ES1, 256, 0);
    tcv(es_W2, 64, 64, 128, WT_ES2, 64, 0);

    // --- encoders ---
    gemmM(stream, node_features, 32, 32, nullptr, 0, 0, WT + WT_ENCN, WTL + WT_ENCN, 32,
          enc_node_b, enc_n, 128, VNn, 128, 128, false);
    gemmM(stream, edge_features, 32, 32, nullptr, 0, 0, WT + WT_ENCE, WTL + WT_ENCE, 32,
          enc_edge_b, enc_e, 128, VEe, 128, 128, false);

    for (int k = 0; k < 3; k++) {
        for (int p = 1; p <= 5; p++) {
            const bool hs = (k > 0) && (p > 1);
            // h_comb = mlp2([h, node_store slot p-1], ni)
            if (p == 1)
                gemmM(stream, enc_n, 128, 128,
                      hs ? node_store + (size_t)(p - 2) * 128 : nullptr, 512, hs ? 128 : 0,
                      WT + WT_NIW1, WTL + WT_NIW1, 256, ni_b1,
                      A_hidden, 256, VNn, 256, 256, true);
            else
                gemmM(stream, upd_node + (size_t)(p - 2) * 128, 640, 128,
                      hs ? node_store + (size_t)(p - 2) * 128 : nullptr, 512, hs ? 128 : 0,
                      WT + WT_NIW1, WTL + WT_NIW1, 256, ni_b1,
                      A_hidden, 256, VNn, 256, 256, true);
            gemmM(stream, A_hidden, 256, 256, nullptr, 0, 0, WT + WT_NIW2, WTL + WT_NIW2, 256,
                  ni_b2, A_hcomb, 128, VNn, 128, 128, false);
            // e_comb = mlp2([enc_e, edge_store slot p-1], ei) -> ecomb slot p
            float* ec_slot = ecomb + (size_t)(p - 1) * VEe * 128;
            gemmM(stream, enc_e, 128, 128,
                  hs ? edge_store + (size_t)(p - 2) * 256 : nullptr, 1024, hs ? 256 : 0,
                  WT + WT_EIW1, WTL + WT_EIW1, 384, ei_b1,
                  A_ehid, 384, VEe, 384, 384, true);
            gemmM(stream, A_ehid, 384, 384, nullptr, 0, 0, WT + WT_EIW2, WTL + WT_EIW2, 384,
                  ei_b2, ec_slot, 128, VEe, 128, 128, false);
            // ec2 = e_comb @ msg_W[256:384] + msg_b (aliases dead ehid)
            gemmM(stream, ec_slot, 128, 128, nullptr, 0, 0,
                  WT + WT_MSG + 256, WTL + WT_MSG + 256, 384,
                  msg_b, A_ec2, 256, VEe, 256, 256, false);
            // P01 = h_comb @ [W0|W1]
            gemmM(stream, A_hcomb, 128, 128, nullptr, 0, 0, WT + WT_P01, WTL + WT_P01, 128,
                  nullptr, A_P01, 512, VNn, 512, 512, false);
            agg_kernel<<<NGg, 256, 0, stream>>>(A_P01, A_ec2, from_idx, to_idx, A_aggb);
            // h = mlp2([h_comb, agg], nu) -> upd_node slot p
            gemmM(stream, A_hcomb, 128, 128, A_aggb, 256, 256, WT + WT_NUW1, WTL + WT_NUW1, 384,
                  nu_b1, A_hidden, 256, VNn, 256, 256, true);
            gemmM(stream, A_hidden, 256, 256, nullptr, 0, 0, WT + WT_NUW2, WTL + WT_NUW2, 256,
                  nu_b2, upd_node + (size_t)(p - 1) * 128, 640, VNn, 128, 128, false);
        }
        // ---- node transport (fused la + sinkhorn) ----
        gemmM(stream, upd_node + 512, 640, 128, nullptr, 0, 0, WT + WT_NS1, WTL + WT_NS1, 128,
              ns_b1, B_thid_n, 64, VNn, 128, 64, true);
        gemmM(stream, B_thid_n, 64, 64, nullptr, 0, 0, WT + WT_NS2, WTL + WT_NS2, 64,
              ns_b2, B_ttreal_n, 64, VNn, 128, 64, false);
        la_sinkhorn64_kernel<<<Bb, 256, 0, stream>>>(B_ttreal_n, n_la);
        if (k < 2) {
            bgemmDual(stream, n_la, 64, 48, upd_node, 640, node_store, 512, 512);
            // ---- edge transport: msgs slot 5 for es features ----
            gemmM(stream, ecomb + (size_t)4 * VEe * 128, 128, 128, nullptr, 0, 0,
                  WT + WT_MSG + 256, WTL + WT_MSG + 256, 384,
                  msg_b, B_ec2msgs, 256, VEe, 256, 256, false);
            gemmM(stream, upd_node + 512, 640, 128, nullptr, 0, 0,
                  WT + WT_WSUM, WTL + WT_WSUM, 128,
                  nullptr, B_Qs, 256, VNn, 256, 256, false);
            msgs_inplace_kernel<<<VEe, 256, 0, stream>>>(B_ec2msgs, B_Qs, from_idx, to_idx);
            gemmM(stream, B_ec2msgs, 256, 256, nullptr, 0, 0, WT + WT_ES1, WTL + WT_ES1, 256,
                  es_b1, B_Qs /*thid_e*/, 64, VEe, 128, 64, true);
            gemmM(stream, B_Qs, 64, 64, nullptr, 0, 0, WT + WT_ES2, WTL + WT_ES2, 64,
                  es_b2, B_ttreal_e, 64, VEe, 128, 64, false);
            la_gemm256_kernel<<<dim3(4, 4, Bb), 256, 0, stream>>>(B_ttreal_e, B_ela);
            sinkhorn256_kernel<<<Bb, 1024, 0, stream>>>(B_ela);
            for (int sl = 1; sl <= 4; sl++) {
                gemmM(stream, ecomb + (size_t)(sl - 1) * VEe * 128, 128, 128, nullptr, 0, 0,
                      WT + WT_MSG + 256, WTL + WT_MSG + 256, 384,
                      msg_b, B_ec2msgs, 256, VEe, 256, 256, false);
                gemmM(stream, upd_node + (size_t)(sl - 1) * 128, 640, 128, nullptr, 0, 0,
                      WT + WT_WSUM, WTL + WT_WSUM, 128,
                      nullptr, B_Qs, 256, VNn, 256, 256, false);
                msgs_inplace_kernel<<<VEe, 256, 0, stream>>>(B_ec2msgs, B_Qs, from_idx, to_idx);
                bgemmDual(stream, B_ela, 256, 192, B_ec2msgs, 256,
                          edge_store + (size_t)(sl - 1) * 256, 1024, 256);
            }
        }
    }
    score_kernel<<<Bb, 128, 0, stream>>>(upd_node, n_la, (float*)d_out);
}

// Round 11
// 4012.814 us; speedup vs baseline: 1.4407x; 1.0953x over previous
//
#include <hip/hip_runtime.h>
#include <cstdint>
#include <cstddef>

// Problem constants (from reference)
#define NGg   128     // 2*B
#define Bb    64
#define Nn    48
#define Ee    192
#define Sdim  64
#define VNn   6144    // NGg*Nn
#define VEe   24576   // NGg*Ee
#define INV_TEMP 10.0f

typedef unsigned short u16;
typedef __attribute__((ext_vector_type(8))) short short8;
typedef __attribute__((ext_vector_type(4))) float floatx4;

// round-to-nearest-even fp32 -> bf16
__device__ __forceinline__ u16 f2bf(float f)
{
    unsigned int u = __float_as_uint(f);
    u += 0x7FFFu + ((u >> 16) & 1u);
    return (u16)(u >> 16);
}
__device__ __forceinline__ float bf2f(u16 h)
{
    return __uint_as_float(((unsigned int)h) << 16);
}

// ---------------------------------------------------------------------------
// Split-precision bf16x3 MFMA GEMM ("emulated fp32"):
//   C = maybeReLU( (A_hi+A_lo) @ (W_hi+W_lo) + bias ),  dropping lo*lo.
// 128x128 tile, BK=32, 4 waves 2x2, wave = 4x4 mfma 16x16x32 x3.
// ---------------------------------------------------------------------------
#define TW 40
__global__ __launch_bounds__(256) void gemm_mfma_kernel(
    const float* __restrict__ A1, int lda1, int K1,
    const float* __restrict__ A2, int lda2, int K2,
    const u16* __restrict__ Wh, const u16* __restrict__ Wl, int ldwt,
    const float* __restrict__ bias,
    float* __restrict__ C, int ldc,
    int Ncap, int relu)
{
    __shared__ __align__(16) u16 Ah[128 * TW];
    __shared__ __align__(16) u16 Al[128 * TW];
    __shared__ __align__(16) u16 Bh[128 * TW];
    __shared__ __align__(16) u16 Bl[128 * TW];
    const int tid = threadIdx.x;
    const int lane = tid & 63, wave = tid >> 6;
    const int wm = wave >> 1, wn = wave & 1;
    const int bm = blockIdx.y * 128, bn = blockIdx.x * 128;
    const int K = K1 + K2;
    const int srow = tid >> 1;
    const int skoff = (tid & 1) * 16;

    floatx4 acc[4][4];
    #pragma unroll
    for (int i = 0; i < 4; i++)
        #pragma unroll
        for (int j = 0; j < 4; j++) acc[i][j] = (floatx4){0.f, 0.f, 0.f, 0.f};

    const int arow = bm + srow;
    const int brow = bn + srow;
    const int l15 = lane & 15, lq = lane >> 4;

    for (int k0 = 0; k0 < K; k0 += 32) {
        const int kk = k0 + skoff;
        const float* asrc = (kk < K1) ? (A1 + (size_t)arow * lda1 + kk)
                                      : (A2 + (size_t)arow * lda2 + (kk - K1));
        float f[16];
        ((float4*)f)[0] = ((const float4*)asrc)[0];
        ((float4*)f)[1] = ((const float4*)asrc)[1];
        ((float4*)f)[2] = ((const float4*)asrc)[2];
        ((float4*)f)[3] = ((const float4*)asrc)[3];
        u16 ph[16], pl8[16];
        #pragma unroll
        for (int q = 0; q < 16; q++) {
            u16 h = f2bf(f[q]);
            ph[q] = h;
            pl8[q] = f2bf(f[q] - bf2f(h));
        }
        *(uint4*)&Ah[srow * TW + skoff]     = *(const uint4*)&ph[0];
        *(uint4*)&Ah[srow * TW + skoff + 8] = *(const uint4*)&ph[8];
        *(uint4*)&Al[srow * TW + skoff]     = *(const uint4*)&pl8[0];
        *(uint4*)&Al[srow * TW + skoff + 8] = *(const uint4*)&pl8[8];
        const u16* bh = Wh + (size_t)brow * ldwt + kk;
        const u16* bl = Wl + (size_t)brow * ldwt + kk;
        *(uint4*)&Bh[srow * TW + skoff]     = ((const uint4*)bh)[0];
        *(uint4*)&Bh[srow * TW + skoff + 8] = ((const uint4*)bh)[1];
        *(uint4*)&Bl[srow * TW + skoff]     = ((const uint4*)bl)[0];
        *(uint4*)&Bl[srow * TW + skoff + 8] = ((const uint4*)bl)[1];
        __syncthreads();
        short8 afh[4], afl[4], bfh[4], bfl[4];
        #pragma unroll
        for (int i = 0; i < 4; i++) {
            const int ro = (wm * 64 + i * 16 + l15) * TW + lq * 8;
            afh[i] = *(const short8*)&Ah[ro];
            afl[i] = *(const short8*)&Al[ro];
        }
        #pragma unroll
        for (int j = 0; j < 4; j++) {
            const int ro = (wn * 64 + j * 16 + l15) * TW + lq * 8;
            bfh[j] = *(const short8*)&Bh[ro];
            bfl[j] = *(const short8*)&Bl[ro];
        }
        #pragma unroll
        for (int i = 0; i < 4; i++)
            #pragma unroll
            for (int j = 0; j < 4; j++) {
                acc[i][j] = __builtin_amdgcn_mfma_f32_16x16x32_bf16(afh[i], bfl[j], acc[i][j], 0, 0, 0);
                acc[i][j] = __builtin_amdgcn_mfma_f32_16x16x32_bf16(afl[i], bfh[j], acc[i][j], 0, 0, 0);
                acc[i][j] = __builtin_amdgcn_mfma_f32_16x16x32_bf16(afh[i], bfh[j], acc[i][j], 0, 0, 0);
            }
        __syncthreads();
    }
    #pragma unroll
    for (int j = 0; j < 4; j++) {
        const int col = bn + wn * 64 + j * 16 + l15;
        const bool cok = (col < Ncap);
        const float bv = (bias && cok) ? bias[col] : 0.f;
        #pragma unroll
        for (int i = 0; i < 4; i++) {
            const int row0 = bm + wm * 64 + i * 16 + lq * 4;
            #pragma unroll
            for (int r = 0; r < 4; r++) {
                float v = acc[i][j][r] + bv;
                if (relu) v = fmaxf(v, 0.f);
                if (cok) C[(size_t)(row0 + r) * ldc + col] = v;
            }
        }
    }
}

static inline void gemmM(hipStream_t s,
                         const float* A1, int lda1, int K1,
                         const float* A2, int lda2, int K2,
                         const u16* Wh, const u16* Wl, int ldwt,
                         const float* bias,
                         float* C, int ldc, int M, int Ngrid, int Ncap, bool relu)
{
    dim3 grid(Ngrid / 128, M / 128);
    gemm_mfma_kernel<<<grid, 256, 0, s>>>(A1, lda1, K1, A2, lda2, K2, Wh, Wl, ldwt,
                                          bias, C, ldc, Ncap, relu ? 1 : 0);
}

// ---------------------------------------------------------------------------
// One-shot weight prep: all transposed hi/lo bf16 weight planes in a single
// kernel (segment table compile-time; Wsum computed inline from msg_W).
// ---------------------------------------------------------------------------
__global__ __launch_bounds__(256) void prep_kernel(
    const float* __restrict__ niW1, const float* __restrict__ niW2,
    const float* __restrict__ eiW1, const float* __restrict__ eiW2,
    const float* __restrict__ msgW, const float* __restrict__ nuW1,
    const float* __restrict__ nuW2, const float* __restrict__ encnW,
    const float* __restrict__ enceW, const float* __restrict__ nsW1,
    const float* __restrict__ nsW2, const float* __restrict__ esW1,
    const float* __restrict__ esW2,
    u16* __restrict__ WT, u16* __restrict__ WTL)
{
    int idx = blockIdx.x * 256 + threadIdx.x;
    if (idx >= 696320) return;
    const float* src; int base, N, Npad, ldk, noff = 0, wtoff;
    int wsum = 0;
    if      (idx < 65536)  { src = niW1;  base = 0;      N = 256; Npad = 256; ldk = 256; wtoff = 0; }
    else if (idx < 98304)  { src = niW2;  base = 65536;  N = 128; Npad = 128; ldk = 256; wtoff = 65536; }
    else if (idx < 245760) { src = eiW1;  base = 98304;  N = 384; Npad = 384; ldk = 384; wtoff = 98304; }
    else if (idx < 294912) { src = eiW2;  base = 245760; N = 128; Npad = 128; ldk = 384; wtoff = 245760; }
    else if (idx < 393216) { src = msgW;  base = 294912; N = 256; Npad = 256; ldk = 384; wtoff = 294912; }
    else if (idx < 425984) { src = msgW;  base = 393216; N = 256; Npad = 256; ldk = 128; wtoff = 393216; }
    else if (idx < 458752) { src = msgW + 32768; base = 425984; N = 256; Npad = 256; ldk = 128; noff = 256; wtoff = 393216; }
    else if (idx < 557056) { src = nuW1;  base = 458752; N = 256; Npad = 256; ldk = 384; wtoff = 458752; }
    else if (idx < 589824) { src = nuW2;  base = 557056; N = 128; Npad = 128; ldk = 256; wtoff = 557056; }
    else if (idx < 622592) { src = msgW;  base = 589824; N = 256; Npad = 256; ldk = 128; wtoff = 589824; wsum = 1; }
    else if (idx < 626688) { src = encnW; base = 622592; N = 128; Npad = 128; ldk = 32;  wtoff = 622592; }
    else if (idx < 630784) { src = enceW; base = 626688; N = 128; Npad = 128; ldk = 32;  wtoff = 626688; }
    else if (idx < 647168) { src = nsW1;  base = 630784; N = 64;  Npad = 128; ldk = 128; wtoff = 630784; }
    else if (idx < 655360) { src = nsW2;  base = 647168; N = 64;  Npad = 128; ldk = 64;  wtoff = 647168; }
    else if (idx < 688128) { src = esW1;  base = 655360; N = 64;  Npad = 128; ldk = 256; wtoff = 655360; }
    else                   { src = esW2;  base = 688128; N = 64;  Npad = 128; ldk = 64;  wtoff = 688128; }
    int rel = idx - base;
    int k = rel / Npad, n = rel % Npad;
    float v = 0.f;
    if (n < N) {
        v = src[(size_t)k * N + n];
        if (wsum) v += src[32768 + (size_t)k * N + n];
    }
    u16 h = f2bf(v);
    size_t o = (size_t)wtoff + (size_t)(noff + n) * ldk + k;
    WT[o] = h;
    WTL[o] = f2bf(v - bf2f(h));
}

// ---------------------------------------------------------------------------
// Dual batched MFMA plan-GEMM: qi (transp=0) + ci (transp=1) in one launch.
// ---------------------------------------------------------------------------
__global__ __launch_bounds__(256) void bgemm_dual_kernel(
    const float* __restrict__ P, int ms, int n_per,
    const float* __restrict__ U, int ldu,
    float* __restrict__ C, int ldc, int nxh)
{
    __shared__ __align__(16) u16 Ah[64 * TW];
    __shared__ __align__(16) u16 Al[64 * TW];
    __shared__ __align__(16) u16 Bh[128 * TW];
    __shared__ __align__(16) u16 Bl[128 * TW];
    const int b = blockIdx.z;
    const float* Pb = P + (size_t)b * ms * ms;
    const int bxr = blockIdx.x;
    const int transp = (bxr >= nxh) ? 1 : 0;
    const int bn = (bxr - transp * nxh) * 128;
    const int qbase = (2 * b) * n_per, cbase = (2 * b + 1) * n_per;
    const int obase = transp ? cbase : qbase;
    const int ibase = transp ? qbase : cbase;
    const int bm = blockIdx.y * 64;
    const int tid = threadIdx.x, lane = tid & 63, wave = tid >> 6;
    const int wm = wave >> 1, wn = wave & 1;
    const int l15 = lane & 15, lq = lane >> 4;
    const int sar = tid >> 2, sak = (tid & 3) * 8;
    const int sbn = tid >> 1, sbk = (tid & 1) * 16;
    const int Kpad = (n_per + 31) & ~31;

    floatx4 acc[2][4];
    #pragma unroll
    for (int i = 0; i < 2; i++)
        #pragma unroll
        for (int j = 0; j < 4; j++) acc[i][j] = (floatx4){0.f, 0.f, 0.f, 0.f};

    for (int k0 = 0; k0 < Kpad; k0 += 32) {
        {
            u16 ph[8], pl8[8];
            const int m = bm + sar;
            #pragma unroll
            for (int i = 0; i < 8; i++) {
                int kk = k0 + sak + i;
                float v = 0.f;
                if (kk < n_per && m < n_per)
                    v = transp ? Pb[(size_t)kk * ms + m] : Pb[(size_t)m * ms + kk];
                u16 h = f2bf(v);
                ph[i] = h; pl8[i] = f2bf(v - bf2f(h));
            }
            *(uint4*)&Ah[sar * TW + sak] = *(const uint4*)&ph[0];
            *(uint4*)&Al[sar * TW + sak] = *(const uint4*)&pl8[0];
        }
        {
            u16 qh[16], ql[16];
            #pragma unroll
            for (int i = 0; i < 16; i++) {
                int kk = k0 + sbk + i;
                float v = 0.f;
                if (kk < n_per) v = U[(size_t)(ibase + kk) * ldu + bn + sbn];
                u16 h = f2bf(v);
                qh[i] = h; ql[i] = f2bf(v - bf2f(h));
            }
            *(uint4*)&Bh[sbn * TW + sbk]     = *(const uint4*)&qh[0];
            *(uint4*)&Bh[sbn * TW + sbk + 8] = *(const uint4*)&qh[8];
            *(uint4*)&Bl[sbn * TW + sbk]     = *(const uint4*)&ql[0];
            *(uint4*)&Bl[sbn * TW + sbk + 8] = *(const uint4*)&ql[8];
        }
        __syncthreads();
        short8 afh[2], afl[2], bfh[4], bfl[4];
        #pragma unroll
        for (int i = 0; i < 2; i++) {
            const int ro = (wm * 32 + i * 16 + l15) * TW + lq * 8;
            afh[i] = *(const short8*)&Ah[ro];
            afl[i] = *(const short8*)&Al[ro];
        }
        #pragma unroll
        for (int j = 0; j < 4; j++) {
            const int ro = (wn * 64 + j * 16 + l15) * TW + lq * 8;
            bfh[j] = *(const short8*)&Bh[ro];
            bfl[j] = *(const short8*)&Bl[ro];
        }
        #pragma unroll
        for (int i = 0; i < 2; i++)
            #pragma unroll
            for (int j = 0; j < 4; j++) {
                acc[i][j] = __builtin_amdgcn_mfma_f32_16x16x32_bf16(afh[i], bfl[j], acc[i][j], 0, 0, 0);
                acc[i][j] = __builtin_amdgcn_mfma_f32_16x16x32_bf16(afl[i], bfh[j], acc[i][j], 0, 0, 0);
                acc[i][j] = __builtin_amdgcn_mfma_f32_16x16x32_bf16(afh[i], bfh[j], acc[i][j], 0, 0, 0);
            }
        __syncthreads();
    }
    #pragma unroll
    for (int j = 0; j < 4; j++) {
        const int col = bn + wn * 64 + j * 16 + l15;
        #pragma unroll
        for (int i = 0; i < 2; i++) {
            const int row0 = bm + wm * 32 + i * 16 + lq * 4;
            #pragma unroll
            for (int r = 0; r < 4; r++) {
                const int m = row0 + r;
                if (m < n_per)
                    C[(size_t)(obase + m) * ldc + col] = acc[i][j][r];
            }
        }
    }
}

static inline void bgemmDual(hipStream_t s, const float* P, int ms, int n_per,
                             const float* U, int ldu, float* C, int ldc, int N)
{
    int nxh = N / 128;
    dim3 grid(nxh * 2, (n_per + 63) / 64, Bb);
    bgemm_dual_kernel<<<grid, 256, 0, s>>>(P, ms, n_per, U, ldu, C, ldc, nxh);
}

// ---------------------------------------------------------------------------
// Fused node transport: la (64x64) + 10 Sinkhorn iters (potential form) +
// plan=exp write. 4 waves; wave w owns rows 16w..16w+15; lane owns a col.
// ---------------------------------------------------------------------------
__global__ __launch_bounds__(256) void la_sinkhorn64_kernel(
    const float* __restrict__ tt, float* __restrict__ n_la)
{
    const int b = blockIdx.x;
    __shared__ float Aq[64][65];
    __shared__ float Ac[64][65];
    __shared__ float m[64][65];
    __shared__ float v_s[64];
    __shared__ float part[4][64];
    const int tid = threadIdx.x;
    const int lane = tid & 63, w = tid >> 6;
    for (int idx = tid; idx < 4096; idx += 256) {
        int r = idx >> 6, s = idx & 63;
        float vq = 0.f, vc = 0.f;
        if (r < Nn) {
            vq = tt[((size_t)(2 * b) * Nn + r) * Sdim + s];
            vc = tt[((size_t)(2 * b + 1) * Nn + r) * Sdim + s];
        }
        Aq[r][s] = vq;
        Ac[r][s] = vc;
    }
    __syncthreads();
    {
        const int tx = tid & 15, ty = tid >> 4;
        float acc[4][4] = {};
        for (int s = 0; s < 64; s++) {
            float a[4], c[4];
            #pragma unroll
            for (int i = 0; i < 4; i++) a[i] = Aq[ty * 4 + i][s];
            #pragma unroll
            for (int j = 0; j < 4; j++) c[j] = Ac[tx * 4 + j][s];
            #pragma unroll
            for (int i = 0; i < 4; i++)
                #pragma unroll
                for (int j = 0; j < 4; j++)
                    acc[i][j] = fmaf(a[i], c[j], acc[i][j]);
        }
        #pragma unroll
        for (int i = 0; i < 4; i++)
            #pragma unroll
            for (int j = 0; j < 4; j++)
                m[ty * 4 + i][tx * 4 + j] = acc[i][j] * INV_TEMP;
    }
    if (tid < 64) v_s[tid] = 0.f;
    __syncthreads();
    float x[16], u[16];
    #pragma unroll
    for (int j = 0; j < 16; j++) x[j] = m[w * 16 + j][lane];
    #pragma unroll
    for (int j = 0; j < 16; j++) {
        float mx = x[j];
        #pragma unroll
        for (int d = 1; d < 64; d <<= 1) mx = fmaxf(mx, __shfl_xor(mx, d));
        u[j] = mx;
    }
    for (int it = 0; it < 10; it++) {
        float vr = v_s[lane];
        #pragma unroll
        for (int j = 0; j < 16; j++) {
            float s = __expf(x[j] - vr - u[j]);
            #pragma unroll
            for (int d = 1; d < 64; d <<= 1) s += __shfl_xor(s, d);
            u[j] += __logf(s);
        }
        float s = 0.f;
        #pragma unroll
        for (int j = 0; j < 16; j++) s += __expf(x[j] - u[j] - vr);
        part[w][lane] = s;
        __syncthreads();
        if (tid < 64) {
            float ss = part[0][tid] + part[1][tid] + part[2][tid] + part[3][tid];
            v_s[tid] += __logf(ss);
        }
        __syncthreads();
    }
    float vr = v_s[lane];
    float* g = n_la + (size_t)b * 4096;
    #pragma unroll
    for (int j = 0; j < 16; j++)
        g[(size_t)(w * 16 + j) * 64 + lane] = __expf(x[j] - u[j] - vr);
}

// la for edges (256x256): la[b][q][c] = 10 * tq[q]·tc[c], fp32 ttreal guarded.
__global__ __launch_bounds__(256) void la_gemm256_kernel(
    const float* __restrict__ tt, float* __restrict__ la)
{
    const int b = blockIdx.z;
    const int bm = blockIdx.y * 64, bn = blockIdx.x * 64;
    __shared__ float Aq[64][65];
    __shared__ float Ac[64][65];
    const int tid = threadIdx.x;
    for (int idx = tid; idx < 4096; idx += 256) {
        int r = idx >> 6, s = idx & 63;
        float vq = 0.f, vc = 0.f;
        int qr = bm + r, cr = bn + r;
        if (qr < Ee) vq = tt[((size_t)(2 * b) * Ee + qr) * Sdim + s];
        if (cr < Ee) vc = tt[((size_t)(2 * b + 1) * Ee + cr) * Sdim + s];
        Aq[r][s] = vq;
        Ac[r][s] = vc;
    }
    __syncthreads();
    const int tx = tid & 15, ty = tid >> 4;
    float acc[4][4] = {};
    for (int s = 0; s < 64; s++) {
        float a[4], c[4];
        #pragma unroll
        for (int i = 0; i < 4; i++) a[i] = Aq[ty * 4 + i][s];
        #pragma unroll
        for (int j = 0; j < 4; j++) c[j] = Ac[tx * 4 + j][s];
        #pragma unroll
        for (int i = 0; i < 4; i++)
            #pragma unroll
            for (int j = 0; j < 4; j++)
                acc[i][j] = fmaf(a[i], c[j], acc[i][j]);
    }
    #pragma unroll
    for (int i = 0; i < 4; i++)
        #pragma unroll
        for (int j = 0; j < 4; j++)
            la[((size_t)b * 256 + bm + ty * 4 + i) * 256 + bn + tx * 4 + j] = acc[i][j] * INV_TEMP;
}

// ---------------------------------------------------------------------------
// Sinkhorn 256x256, potential form, register-resident rows.
// __launch_bounds__(1024, 4): 128-VGPR budget -> no scratch spills.
// ---------------------------------------------------------------------------
__global__ __launch_bounds__(1024, 4) void sinkhorn256_kernel(float* __restrict__ la)
{
    const int b = blockIdx.x;
    float* g = la + (size_t)b * 65536;
    const int tid = threadIdx.x;
    const int lane = tid & 63, w = tid >> 6;
    __shared__ float v_s[256];
    __shared__ float part[16][64][5];

    float x[4][16];
    #pragma unroll
    for (int cc = 0; cc < 4; cc++)
        #pragma unroll
        for (int j = 0; j < 16; j++)
            x[cc][j] = g[(size_t)(w * 16 + j) * 256 + cc * 64 + lane];

    float u[16];
    #pragma unroll
    for (int j = 0; j < 16; j++) {
        float mx = fmaxf(fmaxf(x[0][j], x[1][j]), fmaxf(x[2][j], x[3][j]));
        #pragma unroll
        for (int d = 1; d < 64; d <<= 1) mx = fmaxf(mx, __shfl_xor(mx, d));
        u[j] = mx;
    }
    if (tid < 256) v_s[tid] = 0.f;
    __syncthreads();

    for (int it = 0; it < 10; it++) {
        float vr[4];
        #pragma unroll
        for (int cc = 0; cc < 4; cc++) vr[cc] = v_s[cc * 64 + lane];
        #pragma unroll
        for (int j = 0; j < 16; j++) {
            float s = __expf(x[0][j] - vr[0] - u[j]) + __expf(x[1][j] - vr[1] - u[j])
                    + __expf(x[2][j] - vr[2] - u[j]) + __expf(x[3][j] - vr[3] - u[j]);
            #pragma unroll
            for (int d = 1; d < 64; d <<= 1) s += __shfl_xor(s, d);
            u[j] += __logf(s);
        }
        #pragma unroll
        for (int cc = 0; cc < 4; cc++) {
            float s = 0.f;
            #pragma unroll
            for (int j = 0; j < 16; j++) s += __expf(x[cc][j] - u[j] - vr[cc]);
            part[w][lane][cc] = s;
        }
        __syncthreads();
        if (tid < 256) {
            const int cl = tid & 63, cc = tid >> 6;
            float ss = 0.f;
            #pragma unroll
            for (int w2 = 0; w2 < 16; w2++) ss += part[w2][cl][cc];
            v_s[tid] += __logf(ss);
        }
        __syncthreads();
    }
    float vr[4];
    #pragma unroll
    for (int cc = 0; cc < 4; cc++) vr[cc] = v_s[cc * 64 + lane];
    #pragma unroll
    for (int cc = 0; cc < 4; cc++)
        #pragma unroll
        for (int j = 0; j < 16; j++)
            g[(size_t)(w * 16 + j) * 256 + cc * 64 + lane] = __expf(x[cc][j] - u[j] - vr[cc]);
}

// ---------------------------------------------------------------------------
// Group-local message aggregation; P0/P1 packed in P01 (ld 512), fp32.
// ---------------------------------------------------------------------------
__global__ __launch_bounds__(256) void agg_kernel(
    const float* __restrict__ P01,
    const float* __restrict__ ec2,
    const int* __restrict__ from_idx, const int* __restrict__ to_idx,
    float* __restrict__ agg)
{
    const int gblk = blockIdx.x;
    const int d = threadIdx.x;
    __shared__ float acc[48][256];
    __shared__ int fr[192], to[192];
    #pragma unroll
    for (int n = 0; n < 48; n++) acc[n][d] = 0.f;
    if (d < 192) {
        fr[d] = from_idx[gblk * 192 + d] - gblk * 48;
        to[d] = to_idx[gblk * 192 + d] - gblk * 48;
    }
    __syncthreads();
    const int nb = gblk * 48;
    const int eb = gblk * 192;
    for (int e = 0; e < 192; e++) {
        int f = fr[e], t = to[e];
        float ee  = ec2[(size_t)(eb + e) * 256 + d];
        float p0f = P01[(size_t)(nb + f) * 512 + d];
        float p1f = P01[(size_t)(nb + f) * 512 + 256 + d];
        float p0t = P01[(size_t)(nb + t) * 512 + d];
        float p1t = P01[(size_t)(nb + t) * 512 + 256 + d];
        acc[t][d] += p0f + p1t + ee;
        acc[f][d] += p0t + p1f + ee;
    }
    __syncthreads();
    for (int n = 0; n < 48; n++) agg[(size_t)(nb + n) * 256 + d] = acc[n][d];
}

// In-place messages: m[e] <- Qs[from]+Qs[to]+2*m[e]
__global__ __launch_bounds__(256) void msgs_inplace_kernel(
    float* __restrict__ m, const float* __restrict__ Qs,
    const int* __restrict__ from_idx, const int* __restrict__ to_idx)
{
    const int e = blockIdx.x;
    const int d = threadIdx.x;
    const int f = from_idx[e], t = to_idx[e];
    size_t o = (size_t)e * 256 + d;
    m[o] = Qs[(size_t)f * 256 + d] + Qs[(size_t)t * 256 + d] + 2.f * m[o];
}

__global__ void diag_kernel(float* __restrict__ out, float v)
{
    out[threadIdx.x] = v;
}

// score[b] = -sum relu( ffq - plan@ffc )
__global__ __launch_bounds__(128) void score_kernel(
    const float* __restrict__ upd_node, const float* __restrict__ plan,
    float* __restrict__ out)
{
    const int b = blockIdx.x;
    const int tid = threadIdx.x;
    __shared__ float ffc[48][128];
    __shared__ float pl[64][48];
    __shared__ float red[128];
    for (int c = 0; c < 48; c++)
        ffc[c][tid] = upd_node[(size_t)((2 * b + 1) * 48 + c) * 640 + 512 + tid];
    for (int idx = tid; idx < 64 * 48; idx += 128) {
        int q = idx / 48, c = idx % 48;
        pl[q][c] = plan[(size_t)b * 4096 + q * 64 + c];
    }
    __syncthreads();
    float accv = 0.f;
    for (int q = 0; q < 64; q++) {
        float rsum = 0.f;
        #pragma unroll 8
        for (int c = 0; c < 48; c++) rsum = fmaf(pl[q][c], ffc[c][tid], rsum);
        float fq = 0.f;
        if (q < 48) fq = upd_node[(size_t)((2 * b) * 48 + q) * 640 + 512 + tid];
        accv += fmaxf(fq - rsum, 0.f);
    }
    red[tid] = accv;
    __syncthreads();
    for (int sft = 64; sft > 0; sft >>= 1) {
        if (tid < sft) red[tid] += red[tid + sft];
        __syncthreads();
    }
    if (tid == 0) out[b] = -red[0];
}

// ---------------------------------------------------------------------------
// Workspace layout (floats). Total 66,265,088 floats = 265.1 MB <= 268.4 MB.
// ---------------------------------------------------------------------------
#define OFF_UPD_NODE   0ULL
#define OFF_NODE_STORE 3932160ULL
#define OFF_EDGE_STORE 7077888ULL
#define OFF_ECOMB      32243712ULL
#define OFF_ENC_N      47972352ULL
#define OFF_ENC_E      48758784ULL
#define OFF_N_LA       51904512ULL
#define OFF_WT         52199424ULL
#define OFF_WTL        52547584ULL
#define OFF_ARENA      52895744ULL
#define TOTAL_FLOATS   66265088ULL

// bf16 weight sub-offsets (u16 from WT/WTL base)
#define WT_NIW1   0
#define WT_NIW2   65536
#define WT_EIW1   98304
#define WT_EIW2   245760
#define WT_MSG    294912
#define WT_P01    393216
#define WT_NUW1   458752
#define WT_NUW2   557056
#define WT_WSUM   589824
#define WT_ENCN   622592
#define WT_ENCE   626688
#define WT_NS1    630784
#define WT_NS2    647168
#define WT_ES1    655360
#define WT_ES2    688128

extern "C" void kernel_launch(void* const* d_in, const int* in_sizes, int n_in,
                              void* d_out, int out_size, void* d_ws, size_t ws_size,
                              hipStream_t stream)
{
    (void)in_sizes; (void)n_in; (void)out_size;
    if (ws_size < TOTAL_FLOATS * sizeof(float)) {
        diag_kernel<<<1, 64, 0, stream>>>((float*)d_out, (float)ws_size);
        return;
    }

    const float* node_features = (const float*)d_in[0];
    const float* edge_features = (const float*)d_in[1];
    const int*   from_idx      = (const int*)d_in[2];
    const int*   to_idx        = (const int*)d_in[3];
    const float* enc_node_W = (const float*)d_in[4];
    const float* enc_node_b = (const float*)d_in[5];
    const float* enc_edge_W = (const float*)d_in[6];
    const float* enc_edge_b = (const float*)d_in[7];
    const float* ni_W1 = (const float*)d_in[8];
    const float* ni_b1 = (const float*)d_in[9];
    const float* ni_W2 = (const float*)d_in[10];
    const float* ni_b2 = (const float*)d_in[11];
    const float* ei_W1 = (const float*)d_in[12];
    const float* ei_b1 = (const float*)d_in[13];
    const float* ei_W2 = (const float*)d_in[14];
    const float* ei_b2 = (const float*)d_in[15];
    const float* msg_W = (const float*)d_in[16];
    const float* msg_b = (const float*)d_in[17];
    const float* nu_W1 = (const float*)d_in[18];
    const float* nu_b1 = (const float*)d_in[19];
    const float* nu_W2 = (const float*)d_in[20];
    const float* nu_b2 = (const float*)d_in[21];
    const float* ns_W1 = (const float*)d_in[22];
    const float* ns_b1 = (const float*)d_in[23];
    const float* ns_W2 = (const float*)d_in[24];
    const float* ns_b2 = (const float*)d_in[25];
    const float* es_W1 = (const float*)d_in[26];
    const float* es_b1 = (const float*)d_in[27];
    const float* es_W2 = (const float*)d_in[28];
    const float* es_b2 = (const float*)d_in[29];

    float* ws = (float*)d_ws;
    float* upd_node   = ws + OFF_UPD_NODE;
    float* node_store = ws + OFF_NODE_STORE;
    float* edge_store = ws + OFF_EDGE_STORE;
    float* ecomb      = ws + OFF_ECOMB;
    float* enc_n      = ws + OFF_ENC_N;
    float* enc_e      = ws + OFF_ENC_E;
    float* n_la       = ws + OFF_N_LA;
    u16* WT  = (u16*)(ws + OFF_WT);
    u16* WTL = (u16*)(ws + OFF_WTL);
    float* arena      = ws + OFF_ARENA;

    // Phase-A arena carve (ehid dead before ec2 is written -> alias;
    // A_ec2 survives the whole k==0 p-loop: nothing else writes 2.36-8.65M)
    float* A_hidden = arena;                  // VN x 256
    float* A_hcomb  = arena + 1572864;        // VN x 128
    float* A_ehid   = arena + 2359296;        // VE x 384
    float* A_ec2    = arena + 2359296;        // VE x 256 (alias)
    float* A_P01    = arena + 8650752;        // VN x 512
    float* A_aggb   = arena + 11796480;       // VN x 256
    // Phase-B arena carve
    float* B_ec2msgs  = arena;                // VE x 256
    float* B_ttreal_e = arena;                // VE x 64 (after msgs consumed)
    float* B_Qs       = arena + 6291456;      // VN x 256 (also thid_e VE x 64)
    float* B_ela      = arena + 7864320;      // 64 x 256 x 256
    float* B_thid_n   = arena + 12058624;     // VN x 64
    float* B_ttreal_n = arena + 12451840;     // VN x 64

    // --- one-shot weight prep (all 16 transposed hi/lo planes + Wsum) ---
    prep_kernel<<<(696320 + 255) / 256, 256, 0, stream>>>(
        ni_W1, ni_W2, ei_W1, ei_W2, msg_W, nu_W1, nu_W2,
        enc_node_W, enc_edge_W, ns_W1, ns_W2, es_W1, es_W2, WT, WTL);

    // --- encoders ---
    gemmM(stream, node_features, 32, 32, nullptr, 0, 0, WT + WT_ENCN, WTL + WT_ENCN, 32,
          enc_node_b, enc_n, 128, VNn, 128, 128, false);
    gemmM(stream, edge_features, 32, 32, nullptr, 0, 0, WT + WT_ENCE, WTL + WT_ENCE, 32,
          enc_edge_b, enc_e, 128, VEe, 128, 128, false);

    for (int k = 0; k < 3; k++) {
        if (k == 0) {
            // edge_store == 0 for ALL p at k=0 -> e_comb/ec2 identical across
            // the 5 steps: compute once. ECOMB slot 0 holds the shared e_comb
            // (also reused as the p==1 e_comb for k>0, since store slot0==0).
            gemmM(stream, enc_e, 128, 128, nullptr, 0, 0,
                  WT + WT_EIW1, WTL + WT_EIW1, 384, ei_b1,
                  A_ehid, 384, VEe, 384, 384, true);
            gemmM(stream, A_ehid, 384, 384, nullptr, 0, 0, WT + WT_EIW2, WTL + WT_EIW2, 384,
                  ei_b2, ecomb, 128, VEe, 128, 128, false);
            gemmM(stream, ecomb, 128, 128, nullptr, 0, 0,
                  WT + WT_MSG + 256, WTL + WT_MSG + 256, 384,
                  msg_b, A_ec2, 256, VEe, 256, 256, false);
        }
        for (int p = 1; p <= 5; p++) {
            const bool hs = (k > 0) && (p > 1);
            // h_comb = mlp2([h, node_store slot p-1], ni)
            if (p == 1)
                gemmM(stream, enc_n, 128, 128,
                      hs ? node_store + (size_t)(p - 2) * 128 : nullptr, 512, hs ? 128 : 0,
                      WT + WT_NIW1, WTL + WT_NIW1, 256, ni_b1,
                      A_hidden, 256, VNn, 256, 256, true);
            else
                gemmM(stream, upd_node + (size_t)(p - 2) * 128, 640, 128,
                      hs ? node_store + (size_t)(p - 2) * 128 : nullptr, 512, hs ? 128 : 0,
                      WT + WT_NIW1, WTL + WT_NIW1, 256, ni_b1,
                      A_hidden, 256, VNn, 256, 256, true);
            gemmM(stream, A_hidden, 256, 256, nullptr, 0, 0, WT + WT_NIW2, WTL + WT_NIW2, 256,
                  ni_b2, A_hcomb, 128, VNn, 128, 128, false);
            if (k > 0) {
                if (p == 1) {
                    // store slot 0 == 0 -> e_comb == shared value in ECOMB
                    // slot 0 (still valid); only refresh ec2 into A_ec2.
                    gemmM(stream, ecomb, 128, 128, nullptr, 0, 0,
                          WT + WT_MSG + 256, WTL + WT_MSG + 256, 384,
                          msg_b, A_ec2, 256, VEe, 256, 256, false);
                } else {
                    // e_comb = mlp2([enc_e, edge_store slot p-1], ei)
                    float* ec_slot = ecomb + (size_t)(p - 1) * VEe * 128;
                    gemmM(stream, enc_e, 128, 128,
                          edge_store + (size_t)(p - 2) * 256, 1024, 256,
                          WT + WT_EIW1, WTL + WT_EIW1, 384, ei_b1,
                          A_ehid, 384, VEe, 384, 384, true);
                    gemmM(stream, A_ehid, 384, 384, nullptr, 0, 0,
                          WT + WT_EIW2, WTL + WT_EIW2, 384,
                          ei_b2, ec_slot, 128, VEe, 128, 128, false);
                    gemmM(stream, ec_slot, 128, 128, nullptr, 0, 0,
                          WT + WT_MSG + 256, WTL + WT_MSG + 256, 384,
                          msg_b, A_ec2, 256, VEe, 256, 256, false);
                }
            }
            // P01 = h_comb @ [W0|W1]
            gemmM(stream, A_hcomb, 128, 128, nullptr, 0, 0, WT + WT_P01, WTL + WT_P01, 128,
                  nullptr, A_P01, 512, VNn, 512, 512, false);
            agg_kernel<<<NGg, 256, 0, stream>>>(A_P01, A_ec2, from_idx, to_idx, A_aggb);
            // h = mlp2([h_comb, agg], nu) -> upd_node slot p
            gemmM(stream, A_hcomb, 128, 128, A_aggb, 256, 256, WT + WT_NUW1, WTL + WT_NUW1, 384,
                  nu_b1, A_hidden, 256, VNn, 256, 256, true);
            gemmM(stream, A_hidden, 256, 256, nullptr, 0, 0, WT + WT_NUW2, WTL + WT_NUW2, 256,
                  nu_b2, upd_node + (size_t)(p - 1) * 128, 640, VNn, 128, 128, false);
        }
        // ---- node transport (fused la + sinkhorn) ----
        gemmM(stream, upd_node + 512, 640, 128, nullptr, 0, 0, WT + WT_NS1, WTL + WT_NS1, 128,
              ns_b1, B_thid_n, 64, VNn, 128, 64, true);
        gemmM(stream, B_thid_n, 64, 64, nullptr, 0, 0, WT + WT_NS2, WTL + WT_NS2, 64,
              ns_b2, B_ttreal_n, 64, VNn, 128, 64, false);
        la_sinkhorn64_kernel<<<Bb, 256, 0, stream>>>(B_ttreal_n, n_la);
        if (k < 2) {
            bgemmDual(stream, n_la, 64, 48, upd_node, 640, node_store, 512, 512);
            // ---- edge transport: msgs slot 5 for es features ----
            const size_t s5 = (k == 0) ? 0 : 4;
            gemmM(stream, ecomb + s5 * VEe * 128, 128, 128, nullptr, 0, 0,
                  WT + WT_MSG + 256, WTL + WT_MSG + 256, 384,
                  msg_b, B_ec2msgs, 256, VEe, 256, 256, false);
            gemmM(stream, upd_node + 512, 640, 128, nullptr, 0, 0,
                  WT + WT_WSUM, WTL + WT_WSUM, 128,
                  nullptr, B_Qs, 256, VNn, 256, 256, false);
            msgs_inplace_kernel<<<VEe, 256, 0, stream>>>(B_ec2msgs, B_Qs, from_idx, to_idx);
            gemmM(stream, B_ec2msgs, 256, 256, nullptr, 0, 0, WT + WT_ES1, WTL + WT_ES1, 256,
                  es_b1, B_Qs /*thid_e*/, 64, VEe, 128, 64, true);
            gemmM(stream, B_Qs, 64, 64, nullptr, 0, 0, WT + WT_ES2, WTL + WT_ES2, 64,
                  es_b2, B_ttreal_e, 64, VEe, 128, 64, false);
            la_gemm256_kernel<<<dim3(4, 4, Bb), 256, 0, stream>>>(B_ttreal_e, B_ela);
            sinkhorn256_kernel<<<Bb, 1024, 0, stream>>>(B_ela);
            for (int sl = 1; sl <= 4; sl++) {
                const size_t ss = (k == 0) ? 0 : (size_t)(sl - 1);
                gemmM(stream, ecomb + ss * VEe * 128, 128, 128, nullptr, 0, 0,
                      WT + WT_MSG + 256, WTL + WT_MSG + 256, 384,
                      msg_b, B_ec2msgs, 256, VEe, 256, 256, false);
                gemmM(stream, upd_node + (size_t)(sl - 1) * 128, 640, 128, nullptr, 0, 0,
                      WT + WT_WSUM, WTL + WT_WSUM, 128,
                      nullptr, B_Qs, 256, VNn, 256, 256, false);
                msgs_inplace_kernel<<<VEe, 256, 0, stream>>>(B_ec2msgs, B_Qs, from_idx, to_idx);
                bgemmDual(stream, B_ela, 256, 192, B_ec2msgs, 256,
                          edge_store + (size_t)(sl - 1) * 256, 1024, 256);
            }
        }
    }
    score_kernel<<<Bb, 128, 0, stream>>>(upd_node, n_la, (float*)d_out);
}

// Round 12
// 3855.473 us; speedup vs baseline: 1.4995x; 1.0408x over previous
//
#include <hip/hip_runtime.h>
#include <cstdint>
#include <cstddef>

// Problem constants (from reference)
#define NGg   128     // 2*B
#define Bb    64
#define Nn    48
#define Ee    192
#define Sdim  64
#define VNn   6144    // NGg*Nn
#define VEe   24576   // NGg*Ee
#define INV_TEMP 10.0f

typedef unsigned short u16;
typedef __attribute__((ext_vector_type(8))) short short8;
typedef __attribute__((ext_vector_type(4))) float floatx4;

// round-to-nearest-even fp32 -> bf16
__device__ __forceinline__ u16 f2bf(float f)
{
    unsigned int u = __float_as_uint(f);
    u += 0x7FFFu + ((u >> 16) & 1u);
    return (u16)(u >> 16);
}
__device__ __forceinline__ float bf2f(u16 h)
{
    return __uint_as_float(((unsigned int)h) << 16);
}

// ---------------------------------------------------------------------------
// Split-precision bf16x3 MFMA GEMM ("emulated fp32"):
//   C = maybeReLU( (A_hi+A_lo) @ (W_hi+W_lo) + bias ),  dropping lo*lo.
// 128x128 tile, BK=32, 4 waves 2x2, wave = 4x4 mfma 16x16x32 x3.
// ---------------------------------------------------------------------------
#define TW 40
__global__ __launch_bounds__(256) void gemm_mfma_kernel(
    const float* __restrict__ A1, int lda1, int K1,
    const float* __restrict__ A2, int lda2, int K2,
    const u16* __restrict__ Wh, const u16* __restrict__ Wl, int ldwt,
    const float* __restrict__ bias,
    float* __restrict__ C, int ldc,
    int Ncap, int relu)
{
    __shared__ __align__(16) u16 Ah[128 * TW];
    __shared__ __align__(16) u16 Al[128 * TW];
    __shared__ __align__(16) u16 Bh[128 * TW];
    __shared__ __align__(16) u16 Bl[128 * TW];
    const int tid = threadIdx.x;
    const int lane = tid & 63, wave = tid >> 6;
    const int wm = wave >> 1, wn = wave & 1;
    const int bm = blockIdx.y * 128, bn = blockIdx.x * 128;
    const int K = K1 + K2;
    const int srow = tid >> 1;
    const int skoff = (tid & 1) * 16;

    floatx4 acc[4][4];
    #pragma unroll
    for (int i = 0; i < 4; i++)
        #pragma unroll
        for (int j = 0; j < 4; j++) acc[i][j] = (floatx4){0.f, 0.f, 0.f, 0.f};

    const int arow = bm + srow;
    const int brow = bn + srow;
    const int l15 = lane & 15, lq = lane >> 4;

    for (int k0 = 0; k0 < K; k0 += 32) {
        const int kk = k0 + skoff;
        const float* asrc = (kk < K1) ? (A1 + (size_t)arow * lda1 + kk)
                                      : (A2 + (size_t)arow * lda2 + (kk - K1));
        float f[16];
        ((float4*)f)[0] = ((const float4*)asrc)[0];
        ((float4*)f)[1] = ((const float4*)asrc)[1];
        ((float4*)f)[2] = ((const float4*)asrc)[2];
        ((float4*)f)[3] = ((const float4*)asrc)[3];
        u16 ph[16], pl8[16];
        #pragma unroll
        for (int q = 0; q < 16; q++) {
            u16 h = f2bf(f[q]);
            ph[q] = h;
            pl8[q] = f2bf(f[q] - bf2f(h));
        }
        *(uint4*)&Ah[srow * TW + skoff]     = *(const uint4*)&ph[0];
        *(uint4*)&Ah[srow * TW + skoff + 8] = *(const uint4*)&ph[8];
        *(uint4*)&Al[srow * TW + skoff]     = *(const uint4*)&pl8[0];
        *(uint4*)&Al[srow * TW + skoff + 8] = *(const uint4*)&pl8[8];
        const u16* bh = Wh + (size_t)brow * ldwt + kk;
        const u16* bl = Wl + (size_t)brow * ldwt + kk;
        *(uint4*)&Bh[srow * TW + skoff]     = ((const uint4*)bh)[0];
        *(uint4*)&Bh[srow * TW + skoff + 8] = ((const uint4*)bh)[1];
        *(uint4*)&Bl[srow * TW + skoff]     = ((const uint4*)bl)[0];
        *(uint4*)&Bl[srow * TW + skoff + 8] = ((const uint4*)bl)[1];
        __syncthreads();
        short8 afh[4], afl[4], bfh[4], bfl[4];
        #pragma unroll
        for (int i = 0; i < 4; i++) {
            const int ro = (wm * 64 + i * 16 + l15) * TW + lq * 8;
            afh[i] = *(const short8*)&Ah[ro];
            afl[i] = *(const short8*)&Al[ro];
        }
        #pragma unroll
        for (int j = 0; j < 4; j++) {
            const int ro = (wn * 64 + j * 16 + l15) * TW + lq * 8;
            bfh[j] = *(const short8*)&Bh[ro];
            bfl[j] = *(const short8*)&Bl[ro];
        }
        #pragma unroll
        for (int i = 0; i < 4; i++)
            #pragma unroll
            for (int j = 0; j < 4; j++) {
                acc[i][j] = __builtin_amdgcn_mfma_f32_16x16x32_bf16(afh[i], bfl[j], acc[i][j], 0, 0, 0);
                acc[i][j] = __builtin_amdgcn_mfma_f32_16x16x32_bf16(afl[i], bfh[j], acc[i][j], 0, 0, 0);
                acc[i][j] = __builtin_amdgcn_mfma_f32_16x16x32_bf16(afh[i], bfh[j], acc[i][j], 0, 0, 0);
            }
        __syncthreads();
    }
    #pragma unroll
    for (int j = 0; j < 4; j++) {
        const int col = bn + wn * 64 + j * 16 + l15;
        const bool cok = (col < Ncap);
        const float bv = (bias && cok) ? bias[col] : 0.f;
        #pragma unroll
        for (int i = 0; i < 4; i++) {
            const int row0 = bm + wm * 64 + i * 16 + lq * 4;
            #pragma unroll
            for (int r = 0; r < 4; r++) {
                float v = acc[i][j][r] + bv;
                if (relu) v = fmaxf(v, 0.f);
                if (cok) C[(size_t)(row0 + r) * ldc + col] = v;
            }
        }
    }
}

static inline void gemmM(hipStream_t s,
                         const float* A1, int lda1, int K1,
                         const float* A2, int lda2, int K2,
                         const u16* Wh, const u16* Wl, int ldwt,
                         const float* bias,
                         float* C, int ldc, int M, int Ngrid, int Ncap, bool relu)
{
    dim3 grid(Ngrid / 128, M / 128);
    gemm_mfma_kernel<<<grid, 256, 0, s>>>(A1, lda1, K1, A2, lda2, K2, Wh, Wl, ldwt,
                                          bias, C, ldc, Ncap, relu ? 1 : 0);
}

// ---------------------------------------------------------------------------
// Fused ec2+msgs GEMM (edge transport): for edge row e,
//   out[e][col] = 2*( (ecomb[e]@Wmsg2)[col] + msg_b[col] )
//                 + Qs[from[e]][col] + Qs[to[e]][col]
// A = ecomb slot (VE x 128), K=128, N=256 fixed.
// ---------------------------------------------------------------------------
__global__ __launch_bounds__(256) void gemm_ec2msgs_kernel(
    const float* __restrict__ A,
    const u16* __restrict__ Wh, const u16* __restrict__ Wl, int ldwt,
    const float* __restrict__ bias,
    const float* __restrict__ Qs,
    const int* __restrict__ from_idx, const int* __restrict__ to_idx,
    float* __restrict__ M)
{
    __shared__ __align__(16) u16 Ah[128 * TW];
    __shared__ __align__(16) u16 Al[128 * TW];
    __shared__ __align__(16) u16 Bh[128 * TW];
    __shared__ __align__(16) u16 Bl[128 * TW];
    const int tid = threadIdx.x;
    const int lane = tid & 63, wave = tid >> 6;
    const int wm = wave >> 1, wn = wave & 1;
    const int bm = blockIdx.y * 128, bn = blockIdx.x * 128;
    const int srow = tid >> 1;
    const int skoff = (tid & 1) * 16;

    floatx4 acc[4][4];
    #pragma unroll
    for (int i = 0; i < 4; i++)
        #pragma unroll
        for (int j = 0; j < 4; j++) acc[i][j] = (floatx4){0.f, 0.f, 0.f, 0.f};

    const int arow = bm + srow;
    const int brow = bn + srow;
    const int l15 = lane & 15, lq = lane >> 4;

    for (int k0 = 0; k0 < 128; k0 += 32) {
        const int kk = k0 + skoff;
        const float* asrc = A + (size_t)arow * 128 + kk;
        float f[16];
        ((float4*)f)[0] = ((const float4*)asrc)[0];
        ((float4*)f)[1] = ((const float4*)asrc)[1];
        ((float4*)f)[2] = ((const float4*)asrc)[2];
        ((float4*)f)[3] = ((const float4*)asrc)[3];
        u16 ph[16], pl8[16];
        #pragma unroll
        for (int q = 0; q < 16; q++) {
            u16 h = f2bf(f[q]);
            ph[q] = h;
            pl8[q] = f2bf(f[q] - bf2f(h));
        }
        *(uint4*)&Ah[srow * TW + skoff]     = *(const uint4*)&ph[0];
        *(uint4*)&Ah[srow * TW + skoff + 8] = *(const uint4*)&ph[8];
        *(uint4*)&Al[srow * TW + skoff]     = *(const uint4*)&pl8[0];
        *(uint4*)&Al[srow * TW + skoff + 8] = *(const uint4*)&pl8[8];
        const u16* bh = Wh + (size_t)brow * ldwt + kk;
        const u16* bl = Wl + (size_t)brow * ldwt + kk;
        *(uint4*)&Bh[srow * TW + skoff]     = ((const uint4*)bh)[0];
        *(uint4*)&Bh[srow * TW + skoff + 8] = ((const uint4*)bh)[1];
        *(uint4*)&Bl[srow * TW + skoff]     = ((const uint4*)bl)[0];
        *(uint4*)&Bl[srow * TW + skoff + 8] = ((const uint4*)bl)[1];
        __syncthreads();
        short8 afh[4], afl[4], bfh[4], bfl[4];
        #pragma unroll
        for (int i = 0; i < 4; i++) {
            const int ro = (wm * 64 + i * 16 + l15) * TW + lq * 8;
            afh[i] = *(const short8*)&Ah[ro];
            afl[i] = *(const short8*)&Al[ro];
        }
        #pragma unroll
        for (int j = 0; j < 4; j++) {
            const int ro = (wn * 64 + j * 16 + l15) * TW + lq * 8;
            bfh[j] = *(const short8*)&Bh[ro];
            bfl[j] = *(const short8*)&Bl[ro];
        }
        #pragma unroll
        for (int i = 0; i < 4; i++)
            #pragma unroll
            for (int j = 0; j < 4; j++) {
                acc[i][j] = __builtin_amdgcn_mfma_f32_16x16x32_bf16(afh[i], bfl[j], acc[i][j], 0, 0, 0);
                acc[i][j] = __builtin_amdgcn_mfma_f32_16x16x32_bf16(afl[i], bfh[j], acc[i][j], 0, 0, 0);
                acc[i][j] = __builtin_amdgcn_mfma_f32_16x16x32_bf16(afh[i], bfh[j], acc[i][j], 0, 0, 0);
            }
        __syncthreads();
    }
    #pragma unroll
    for (int i = 0; i < 4; i++) {
        #pragma unroll
        for (int r = 0; r < 4; r++) {
            const int row = bm + wm * 64 + i * 16 + lq * 4 + r;
            const int fi = from_idx[row], ti = to_idx[row];
            #pragma unroll
            for (int j = 0; j < 4; j++) {
                const int col = bn + wn * 64 + j * 16 + l15;
                float v = 2.f * (acc[i][j][r] + bias[col])
                        + Qs[(size_t)fi * 256 + col] + Qs[(size_t)ti * 256 + col];
                M[(size_t)row * 256 + col] = v;
            }
        }
    }
}

// ---------------------------------------------------------------------------
// One-shot weight prep: all transposed hi/lo bf16 weight planes in a single
// kernel (segment table compile-time; Wsum computed inline from msg_W).
// ---------------------------------------------------------------------------
__global__ __launch_bounds__(256) void prep_kernel(
    const float* __restrict__ niW1, const float* __restrict__ niW2,
    const float* __restrict__ eiW1, const float* __restrict__ eiW2,
    const float* __restrict__ msgW, const float* __restrict__ nuW1,
    const float* __restrict__ nuW2, const float* __restrict__ encnW,
    const float* __restrict__ enceW, const float* __restrict__ nsW1,
    const float* __restrict__ nsW2, const float* __restrict__ esW1,
    const float* __restrict__ esW2,
    u16* __restrict__ WT, u16* __restrict__ WTL)
{
    int idx = blockIdx.x * 256 + threadIdx.x;
    if (idx >= 696320) return;
    const float* src; int base, N, Npad, ldk, noff = 0, wtoff;
    int wsum = 0;
    if      (idx < 65536)  { src = niW1;  base = 0;      N = 256; Npad = 256; ldk = 256; wtoff = 0; }
    else if (idx < 98304)  { src = niW2;  base = 65536;  N = 128; Npad = 128; ldk = 256; wtoff = 65536; }
    else if (idx < 245760) { src = eiW1;  base = 98304;  N = 384; Npad = 384; ldk = 384; wtoff = 98304; }
    else if (idx < 294912) { src = eiW2;  base = 245760; N = 128; Npad = 128; ldk = 384; wtoff = 245760; }
    else if (idx < 393216) { src = msgW;  base = 294912; N = 256; Npad = 256; ldk = 384; wtoff = 294912; }
    else if (idx < 425984) { src = msgW;  base = 393216; N = 256; Npad = 256; ldk = 128; wtoff = 393216; }
    else if (idx < 458752) { src = msgW + 32768; base = 425984; N = 256; Npad = 256; ldk = 128; noff = 256; wtoff = 393216; }
    else if (idx < 557056) { src = nuW1;  base = 458752; N = 256; Npad = 256; ldk = 384; wtoff = 458752; }
    else if (idx < 589824) { src = nuW2;  base = 557056; N = 128; Npad = 128; ldk = 256; wtoff = 557056; }
    else if (idx < 622592) { src = msgW;  base = 589824; N = 256; Npad = 256; ldk = 128; wtoff = 589824; wsum = 1; }
    else if (idx < 626688) { src = encnW; base = 622592; N = 128; Npad = 128; ldk = 32;  wtoff = 622592; }
    else if (idx < 630784) { src = enceW; base = 626688; N = 128; Npad = 128; ldk = 32;  wtoff = 626688; }
    else if (idx < 647168) { src = nsW1;  base = 630784; N = 64;  Npad = 128; ldk = 128; wtoff = 630784; }
    else if (idx < 655360) { src = nsW2;  base = 647168; N = 64;  Npad = 128; ldk = 64;  wtoff = 647168; }
    else if (idx < 688128) { src = esW1;  base = 655360; N = 64;  Npad = 128; ldk = 256; wtoff = 655360; }
    else                   { src = esW2;  base = 688128; N = 64;  Npad = 128; ldk = 64;  wtoff = 688128; }
    int rel = idx - base;
    int k = rel / Npad, n = rel % Npad;
    float v = 0.f;
    if (n < N) {
        v = src[(size_t)k * N + n];
        if (wsum) v += src[32768 + (size_t)k * N + n];
    }
    u16 h = f2bf(v);
    size_t o = (size_t)wtoff + (size_t)(noff + n) * ldk + k;
    WT[o] = h;
    WTL[o] = f2bf(v - bf2f(h));
}

// ---------------------------------------------------------------------------
// Dual batched MFMA plan-GEMM: qi (transp=0) + ci (transp=1) in one launch.
// ---------------------------------------------------------------------------
__global__ __launch_bounds__(256) void bgemm_dual_kernel(
    const float* __restrict__ P, int ms, int n_per,
    const float* __restrict__ U, int ldu,
    float* __restrict__ C, int ldc, int nxh)
{
    __shared__ __align__(16) u16 Ah[64 * TW];
    __shared__ __align__(16) u16 Al[64 * TW];
    __shared__ __align__(16) u16 Bh[128 * TW];
    __shared__ __align__(16) u16 Bl[128 * TW];
    const int b = blockIdx.z;
    const float* Pb = P + (size_t)b * ms * ms;
    const int bxr = blockIdx.x;
    const int transp = (bxr >= nxh) ? 1 : 0;
    const int bn = (bxr - transp * nxh) * 128;
    const int qbase = (2 * b) * n_per, cbase = (2 * b + 1) * n_per;
    const int obase = transp ? cbase : qbase;
    const int ibase = transp ? qbase : cbase;
    const int bm = blockIdx.y * 64;
    const int tid = threadIdx.x, lane = tid & 63, wave = tid >> 6;
    const int wm = wave >> 1, wn = wave & 1;
    const int l15 = lane & 15, lq = lane >> 4;
    const int sar = tid >> 2, sak = (tid & 3) * 8;
    const int sbn = tid >> 1, sbk = (tid & 1) * 16;
    const int Kpad = (n_per + 31) & ~31;

    floatx4 acc[2][4];
    #pragma unroll
    for (int i = 0; i < 2; i++)
        #pragma unroll
        for (int j = 0; j < 4; j++) acc[i][j] = (floatx4){0.f, 0.f, 0.f, 0.f};

    for (int k0 = 0; k0 < Kpad; k0 += 32) {
        {
            u16 ph[8], pl8[8];
            const int m = bm + sar;
            #pragma unroll
            for (int i = 0; i < 8; i++) {
                int kk = k0 + sak + i;
                float v = 0.f;
                if (kk < n_per && m < n_per)
                    v = transp ? Pb[(size_t)kk * ms + m] : Pb[(size_t)m * ms + kk];
                u16 h = f2bf(v);
                ph[i] = h; pl8[i] = f2bf(v - bf2f(h));
            }
            *(uint4*)&Ah[sar * TW + sak] = *(const uint4*)&ph[0];
            *(uint4*)&Al[sar * TW + sak] = *(const uint4*)&pl8[0];
        }
        {
            u16 qh[16], ql[16];
            #pragma unroll
            for (int i = 0; i < 16; i++) {
                int kk = k0 + sbk + i;
                float v = 0.f;
                if (kk < n_per) v = U[(size_t)(ibase + kk) * ldu + bn + sbn];
                u16 h = f2bf(v);
                qh[i] = h; ql[i] = f2bf(v - bf2f(h));
            }
            *(uint4*)&Bh[sbn * TW + sbk]     = *(const uint4*)&qh[0];
            *(uint4*)&Bh[sbn * TW + sbk + 8] = *(const uint4*)&qh[8];
            *(uint4*)&Bl[sbn * TW + sbk]     = *(const uint4*)&ql[0];
            *(uint4*)&Bl[sbn * TW + sbk + 8] = *(const uint4*)&ql[8];
        }
        __syncthreads();
        short8 afh[2], afl[2], bfh[4], bfl[4];
        #pragma unroll
        for (int i = 0; i < 2; i++) {
            const int ro = (wm * 32 + i * 16 + l15) * TW + lq * 8;
            afh[i] = *(const short8*)&Ah[ro];
            afl[i] = *(const short8*)&Al[ro];
        }
        #pragma unroll
        for (int j = 0; j < 4; j++) {
            const int ro = (wn * 64 + j * 16 + l15) * TW + lq * 8;
            bfh[j] = *(const short8*)&Bh[ro];
            bfl[j] = *(const short8*)&Bl[ro];
        }
        #pragma unroll
        for (int i = 0; i < 2; i++)
            #pragma unroll
            for (int j = 0; j < 4; j++) {
                acc[i][j] = __builtin_amdgcn_mfma_f32_16x16x32_bf16(afh[i], bfl[j], acc[i][j], 0, 0, 0);
                acc[i][j] = __builtin_amdgcn_mfma_f32_16x16x32_bf16(afl[i], bfh[j], acc[i][j], 0, 0, 0);
                acc[i][j] = __builtin_amdgcn_mfma_f32_16x16x32_bf16(afh[i], bfh[j], acc[i][j], 0, 0, 0);
            }
        __syncthreads();
    }
    #pragma unroll
    for (int j = 0; j < 4; j++) {
        const int col = bn + wn * 64 + j * 16 + l15;
        #pragma unroll
        for (int i = 0; i < 2; i++) {
            const int row0 = bm + wm * 32 + i * 16 + lq * 4;
            #pragma unroll
            for (int r = 0; r < 4; r++) {
                const int m = row0 + r;
                if (m < n_per)
                    C[(size_t)(obase + m) * ldc + col] = acc[i][j][r];
            }
        }
    }
}

static inline void bgemmDual(hipStream_t s, const float* P, int ms, int n_per,
                             const float* U, int ldu, float* C, int ldc, int N)
{
    int nxh = N / 128;
    dim3 grid(nxh * 2, (n_per + 63) / 64, Bb);
    bgemm_dual_kernel<<<grid, 256, 0, s>>>(P, ms, n_per, U, ldu, C, ldc, nxh);
}

// ---------------------------------------------------------------------------
// Fused node transport: la (64x64) + 10 Sinkhorn iters (potential form) +
// plan=exp write. 4 waves; wave w owns rows 16w..16w+15; lane owns a col.
// ---------------------------------------------------------------------------
__global__ __launch_bounds__(256) void la_sinkhorn64_kernel(
    const float* __restrict__ tt, float* __restrict__ n_la)
{
    const int b = blockIdx.x;
    __shared__ float Aq[64][65];
    __shared__ float Ac[64][65];
    __shared__ float m[64][65];
    __shared__ float v_s[64];
    __shared__ float part[4][64];
    const int tid = threadIdx.x;
    const int lane = tid & 63, w = tid >> 6;
    for (int idx = tid; idx < 4096; idx += 256) {
        int r = idx >> 6, s = idx & 63;
        float vq = 0.f, vc = 0.f;
        if (r < Nn) {
            vq = tt[((size_t)(2 * b) * Nn + r) * Sdim + s];
            vc = tt[((size_t)(2 * b + 1) * Nn + r) * Sdim + s];
        }
        Aq[r][s] = vq;
        Ac[r][s] = vc;
    }
    __syncthreads();
    {
        const int tx = tid & 15, ty = tid >> 4;
        float acc[4][4] = {};
        for (int s = 0; s < 64; s++) {
            float a[4], c[4];
            #pragma unroll
            for (int i = 0; i < 4; i++) a[i] = Aq[ty * 4 + i][s];
            #pragma unroll
            for (int j = 0; j < 4; j++) c[j] = Ac[tx * 4 + j][s];
            #pragma unroll
            for (int i = 0; i < 4; i++)
                #pragma unroll
                for (int j = 0; j < 4; j++)
                    acc[i][j] = fmaf(a[i], c[j], acc[i][j]);
        }
        #pragma unroll
        for (int i = 0; i < 4; i++)
            #pragma unroll
            for (int j = 0; j < 4; j++)
                m[ty * 4 + i][tx * 4 + j] = acc[i][j] * INV_TEMP;
    }
    if (tid < 64) v_s[tid] = 0.f;
    __syncthreads();
    float x[16], u[16];
    #pragma unroll
    for (int j = 0; j < 16; j++) x[j] = m[w * 16 + j][lane];
    #pragma unroll
    for (int j = 0; j < 16; j++) {
        float mx = x[j];
        #pragma unroll
        for (int d = 1; d < 64; d <<= 1) mx = fmaxf(mx, __shfl_xor(mx, d));
        u[j] = mx;
    }
    for (int it = 0; it < 10; it++) {
        float vr = v_s[lane];
        #pragma unroll
        for (int j = 0; j < 16; j++) {
            float s = __expf(x[j] - vr - u[j]);
            #pragma unroll
            for (int d = 1; d < 64; d <<= 1) s += __shfl_xor(s, d);
            u[j] += __logf(s);
        }
        float s = 0.f;
        #pragma unroll
        for (int j = 0; j < 16; j++) s += __expf(x[j] - u[j] - vr);
        part[w][lane] = s;
        __syncthreads();
        if (tid < 64) {
            float ss = part[0][tid] + part[1][tid] + part[2][tid] + part[3][tid];
            v_s[tid] += __logf(ss);
        }
        __syncthreads();
    }
    float vr = v_s[lane];
    float* g = n_la + (size_t)b * 4096;
    #pragma unroll
    for (int j = 0; j < 16; j++)
        g[(size_t)(w * 16 + j) * 64 + lane] = __expf(x[j] - u[j] - vr);
}

// la for edges (256x256): la[b][q][c] = 10 * tq[q]·tc[c], fp32 ttreal guarded.
__global__ __launch_bounds__(256) void la_gemm256_kernel(
    const float* __restrict__ tt, float* __restrict__ la)
{
    const int b = blockIdx.z;
    const int bm = blockIdx.y * 64, bn = blockIdx.x * 64;
    __shared__ float Aq[64][65];
    __shared__ float Ac[64][65];
    const int tid = threadIdx.x;
    for (int idx = tid; idx < 4096; idx += 256) {
        int r = idx >> 6, s = idx & 63;
        float vq = 0.f, vc = 0.f;
        int qr = bm + r, cr = bn + r;
        if (qr < Ee) vq = tt[((size_t)(2 * b) * Ee + qr) * Sdim + s];
        if (cr < Ee) vc = tt[((size_t)(2 * b + 1) * Ee + cr) * Sdim + s];
        Aq[r][s] = vq;
        Ac[r][s] = vc;
    }
    __syncthreads();
    const int tx = tid & 15, ty = tid >> 4;
    float acc[4][4] = {};
    for (int s = 0; s < 64; s++) {
        float a[4], c[4];
        #pragma unroll
        for (int i = 0; i < 4; i++) a[i] = Aq[ty * 4 + i][s];
        #pragma unroll
        for (int j = 0; j < 4; j++) c[j] = Ac[tx * 4 + j][s];
        #pragma unroll
        for (int i = 0; i < 4; i++)
            #pragma unroll
            for (int j = 0; j < 4; j++)
                acc[i][j] = fmaf(a[i], c[j], acc[i][j]);
    }
    #pragma unroll
    for (int i = 0; i < 4; i++)
        #pragma unroll
        for (int j = 0; j < 4; j++)
            la[((size_t)b * 256 + bm + ty * 4 + i) * 256 + bn + tx * 4 + j] = acc[i][j] * INV_TEMP;
}

// ---------------------------------------------------------------------------
// Sinkhorn 256x256, potential form, register-resident rows.
// amdgpu_waves_per_eu(4,4): pin exactly 4 waves/EU -> 128-VGPR budget, no
// scratch spills (round-11 counters showed VGPR=64 + 41MB scratch traffic).
// ---------------------------------------------------------------------------
__global__ void __attribute__((amdgpu_waves_per_eu(4, 4)))
__launch_bounds__(1024) sinkhorn256_kernel(float* __restrict__ la)
{
    const int b = blockIdx.x;
    float* g = la + (size_t)b * 65536;
    const int tid = threadIdx.x;
    const int lane = tid & 63, w = tid >> 6;
    __shared__ float v_s[256];
    __shared__ float part[16][64][5];

    float x[4][16];
    #pragma unroll
    for (int cc = 0; cc < 4; cc++)
        #pragma unroll
        for (int j = 0; j < 16; j++)
            x[cc][j] = g[(size_t)(w * 16 + j) * 256 + cc * 64 + lane];

    float u[16];
    #pragma unroll
    for (int j = 0; j < 16; j++) {
        float mx = fmaxf(fmaxf(x[0][j], x[1][j]), fmaxf(x[2][j], x[3][j]));
        #pragma unroll
        for (int d = 1; d < 64; d <<= 1) mx = fmaxf(mx, __shfl_xor(mx, d));
        u[j] = mx;
    }
    if (tid < 256) v_s[tid] = 0.f;
    __syncthreads();

    for (int it = 0; it < 10; it++) {
        float vr[4];
        #pragma unroll
        for (int cc = 0; cc < 4; cc++) vr[cc] = v_s[cc * 64 + lane];
        #pragma unroll
        for (int j = 0; j < 16; j++) {
            float s = __expf(x[0][j] - vr[0] - u[j]) + __expf(x[1][j] - vr[1] - u[j])
                    + __expf(x[2][j] - vr[2] - u[j]) + __expf(x[3][j] - vr[3] - u[j]);
            #pragma unroll
            for (int d = 1; d < 64; d <<= 1) s += __shfl_xor(s, d);
            u[j] += __logf(s);
        }
        #pragma unroll
        for (int cc = 0; cc < 4; cc++) {
            float s = 0.f;
            #pragma unroll
            for (int j = 0; j < 16; j++) s += __expf(x[cc][j] - u[j] - vr[cc]);
            part[w][lane][cc] = s;
        }
        __syncthreads();
        if (tid < 256) {
            const int cl = tid & 63, cc = tid >> 6;
            float ss = 0.f;
            #pragma unroll
            for (int w2 = 0; w2 < 16; w2++) ss += part[w2][cl][cc];
            v_s[tid] += __logf(ss);
        }
        __syncthreads();
    }
    float vr[4];
    #pragma unroll
    for (int cc = 0; cc < 4; cc++) vr[cc] = v_s[cc * 64 + lane];
    #pragma unroll
    for (int cc = 0; cc < 4; cc++)
        #pragma unroll
        for (int j = 0; j < 16; j++)
            g[(size_t)(w * 16 + j) * 256 + cc * 64 + lane] = __expf(x[cc][j] - u[j] - vr[cc]);
}

// ---------------------------------------------------------------------------
// Group-local message aggregation; P0/P1 packed in P01 (ld 512), fp32.
// ---------------------------------------------------------------------------
__global__ __launch_bounds__(256) void agg_kernel(
    const float* __restrict__ P01,
    const float* __restrict__ ec2,
    const int* __restrict__ from_idx, const int* __restrict__ to_idx,
    float* __restrict__ agg)
{
    const int gblk = blockIdx.x;
    const int d = threadIdx.x;
    __shared__ float acc[48][256];
    __shared__ int fr[192], to[192];
    #pragma unroll
    for (int n = 0; n < 48; n++) acc[n][d] = 0.f;
    if (d < 192) {
        fr[d] = from_idx[gblk * 192 + d] - gblk * 48;
        to[d] = to_idx[gblk * 192 + d] - gblk * 48;
    }
    __syncthreads();
    const int nb = gblk * 48;
    const int eb = gblk * 192;
    for (int e = 0; e < 192; e++) {
        int f = fr[e], t = to[e];
        float ee  = ec2[(size_t)(eb + e) * 256 + d];
        float p0f = P01[(size_t)(nb + f) * 512 + d];
        float p1f = P01[(size_t)(nb + f) * 512 + 256 + d];
        float p0t = P01[(size_t)(nb + t) * 512 + d];
        float p1t = P01[(size_t)(nb + t) * 512 + 256 + d];
        acc[t][d] += p0f + p1t + ee;
        acc[f][d] += p0t + p1f + ee;
    }
    __syncthreads();
    for (int n = 0; n < 48; n++) agg[(size_t)(nb + n) * 256 + d] = acc[n][d];
}

// In-place messages: m[e] <- Qs[from]+Qs[to]+2*m[e]  (used only for slot 5)
__global__ __launch_bounds__(256) void msgs_inplace_kernel(
    float* __restrict__ m, const float* __restrict__ Qs,
    const int* __restrict__ from_idx, const int* __restrict__ to_idx)
{
    const int e = blockIdx.x;
    const int d = threadIdx.x;
    const int f = from_idx[e], t = to_idx[e];
    size_t o = (size_t)e * 256 + d;
    m[o] = Qs[(size_t)f * 256 + d] + Qs[(size_t)t * 256 + d] + 2.f * m[o];
}

__global__ void diag_kernel(float* __restrict__ out, float v)
{
    out[threadIdx.x] = v;
}

// score[b] = -sum relu( ffq - plan@ffc )
__global__ __launch_bounds__(128) void score_kernel(
    const float* __restrict__ upd_node, const float* __restrict__ plan,
    float* __restrict__ out)
{
    const int b = blockIdx.x;
    const int tid = threadIdx.x;
    __shared__ float ffc[48][128];
    __shared__ float pl[64][48];
    __shared__ float red[128];
    for (int c = 0; c < 48; c++)
        ffc[c][tid] = upd_node[(size_t)((2 * b + 1) * 48 + c) * 640 + 512 + tid];
    for (int idx = tid; idx < 64 * 48; idx += 128) {
        int q = idx / 48, c = idx % 48;
        pl[q][c] = plan[(size_t)b * 4096 + q * 64 + c];
    }
    __syncthreads();
    float accv = 0.f;
    for (int q = 0; q < 64; q++) {
        float rsum = 0.f;
        #pragma unroll 8
        for (int c = 0; c < 48; c++) rsum = fmaf(pl[q][c], ffc[c][tid], rsum);
        float fq = 0.f;
        if (q < 48) fq = upd_node[(size_t)((2 * b) * 48 + q) * 640 + 512 + tid];
        accv += fmaxf(fq - rsum, 0.f);
    }
    red[tid] = accv;
    __syncthreads();
    for (int sft = 64; sft > 0; sft >>= 1) {
        if (tid < sft) red[tid] += red[tid + sft];
        __syncthreads();
    }
    if (tid == 0) out[b] = -red[0];
}

// ---------------------------------------------------------------------------
// Workspace layout (floats). Total 66,265,088 floats = 265.1 MB <= 268.4 MB.
// ---------------------------------------------------------------------------
#define OFF_UPD_NODE   0ULL
#define OFF_NODE_STORE 3932160ULL
#define OFF_EDGE_STORE 7077888ULL
#define OFF_ECOMB      32243712ULL
#define OFF_ENC_N      47972352ULL
#define OFF_ENC_E      48758784ULL
#define OFF_N_LA       51904512ULL
#define OFF_WT         52199424ULL
#define OFF_WTL        52547584ULL
#define OFF_ARENA      52895744ULL
#define TOTAL_FLOATS   66265088ULL

// bf16 weight sub-offsets (u16 from WT/WTL base)
#define WT_NIW1   0
#define WT_NIW2   65536
#define WT_EIW1   98304
#define WT_EIW2   245760
#define WT_MSG    294912
#define WT_P01    393216
#define WT_NUW1   458752
#define WT_NUW2   557056
#define WT_WSUM   589824
#define WT_ENCN   622592
#define WT_ENCE   626688
#define WT_NS1    630784
#define WT_NS2    647168
#define WT_ES1    655360
#define WT_ES2    688128

extern "C" void kernel_launch(void* const* d_in, const int* in_sizes, int n_in,
                              void* d_out, int out_size, void* d_ws, size_t ws_size,
                              hipStream_t stream)
{
    (void)in_sizes; (void)n_in; (void)out_size;
    if (ws_size < TOTAL_FLOATS * sizeof(float)) {
        diag_kernel<<<1, 64, 0, stream>>>((float*)d_out, (float)ws_size);
        return;
    }

    const float* node_features = (const float*)d_in[0];
    const float* edge_features = (const float*)d_in[1];
    const int*   from_idx      = (const int*)d_in[2];
    const int*   to_idx        = (const int*)d_in[3];
    const float* enc_node_W = (const float*)d_in[4];
    const float* enc_node_b = (const float*)d_in[5];
    const float* enc_edge_W = (const float*)d_in[6];
    const float* enc_edge_b = (const float*)d_in[7];
    const float* ni_W1 = (const float*)d_in[8];
    const float* ni_b1 = (const float*)d_in[9];
    const float* ni_W2 = (const float*)d_in[10];
    const float* ni_b2 = (const float*)d_in[11];
    const float* ei_W1 = (const float*)d_in[12];
    const float* ei_b1 = (const float*)d_in[13];
    const float* ei_W2 = (const float*)d_in[14];
    const float* ei_b2 = (const float*)d_in[15];
    const float* msg_W = (const float*)d_in[16];
    const float* msg_b = (const float*)d_in[17];
    const float* nu_W1 = (const float*)d_in[18];
    const float* nu_b1 = (const float*)d_in[19];
    const float* nu_W2 = (const float*)d_in[20];
    const float* nu_b2 = (const float*)d_in[21];
    const float* ns_W1 = (const float*)d_in[22];
    const float* ns_b1 = (const float*)d_in[23];
    const float* ns_W2 = (const float*)d_in[24];
    const float* ns_b2 = (const float*)d_in[25];
    const float* es_W1 = (const float*)d_in[26];
    const float* es_b1 = (const float*)d_in[27];
    const float* es_W2 = (const float*)d_in[28];
    const float* es_b2 = (const float*)d_in[29];

    float* ws = (float*)d_ws;
    float* upd_node   = ws + OFF_UPD_NODE;
    float* node_store = ws + OFF_NODE_STORE;
    float* edge_store = ws + OFF_EDGE_STORE;
    float* ecomb      = ws + OFF_ECOMB;
    float* enc_n      = ws + OFF_ENC_N;
    float* enc_e      = ws + OFF_ENC_E;
    float* n_la       = ws + OFF_N_LA;
    u16* WT  = (u16*)(ws + OFF_WT);
    u16* WTL = (u16*)(ws + OFF_WTL);
    float* arena      = ws + OFF_ARENA;

    // Phase-A arena carve (ehid dead before ec2 is written -> alias;
    // A_ec2 survives past phase A: at transport time it holds slot-5's ec2)
    float* A_hidden = arena;                  // [0, 1.57M)   VN x 256
    float* A_hcomb  = arena + 1572864;        // [1.57, 2.36M) VN x 128
    float* A_ehid   = arena + 2359296;        // [2.36, 11.80M) VE x 384
    float* A_ec2    = arena + 2359296;        // [2.36, 8.65M) VE x 256 (alias)
    float* A_P01    = arena + 8650752;        // [8.65, 11.80M) VN x 512
    float* A_aggb   = arena + 11796480;       // [11.80, 13.37M) VN x 256
    // Phase-B carve (ordering-checked against A_ec2 liveness):
    //  node: thid_n/ttreal_n at 12.06/12.45M (A_aggb dead)
    //  edge: Qs@0 (hidden dead); msgs_inplace on A_ec2 in place;
    //        thid_e@8.65 (P01 dead); ttreal_e@10.22; ela@2.36 (A_ec2 dead
    //        after es1); msgs@6.55 (ela intact, thid/ttreal_e dead).
    float* B_Qs       = arena;                // VN x 256
    float* B_thid_e   = arena + 8650752;      // VE x 64
    float* B_ttreal_e = arena + 10223616;     // VE x 64
    float* B_ela      = arena + 2359296;      // 64 x 256 x 256
    float* B_msgs     = arena + 6553600;      // VE x 256
    float* B_thid_n   = arena + 12058624;     // VN x 64
    float* B_ttreal_n = arena + 12451840;     // VN x 64

    // --- one-shot weight prep ---
    prep_kernel<<<(696320 + 255) / 256, 256, 0, stream>>>(
        ni_W1, ni_W2, ei_W1, ei_W2, msg_W, nu_W1, nu_W2,
        enc_node_W, enc_edge_W, ns_W1, ns_W2, es_W1, es_W2, WT, WTL);

    // --- encoders ---
    gemmM(stream, node_features, 32, 32, nullptr, 0, 0, WT + WT_ENCN, WTL + WT_ENCN, 32,
          enc_node_b, enc_n, 128, VNn, 128, 128, false);
    gemmM(stream, edge_features, 32, 32, nullptr, 0, 0, WT + WT_ENCE, WTL + WT_ENCE, 32,
          enc_edge_b, enc_e, 128, VEe, 128, 128, false);

    for (int k = 0; k < 3; k++) {
        if (k == 0) {
            // edge_store == 0 for ALL p at k=0 -> shared e_comb/ec2, once.
            gemmM(stream, enc_e, 128, 128, nullptr, 0, 0,
                  WT + WT_EIW1, WTL + WT_EIW1, 384, ei_b1,
                  A_ehid, 384, VEe, 384, 384, true);
            gemmM(stream, A_ehid, 384, 384, nullptr, 0, 0, WT + WT_EIW2, WTL + WT_EIW2, 384,
                  ei_b2, ecomb, 128, VEe, 128, 128, false);
            gemmM(stream, ecomb, 128, 128, nullptr, 0, 0,
                  WT + WT_MSG + 256, WTL + WT_MSG + 256, 384,
                  msg_b, A_ec2, 256, VEe, 256, 256, false);
        }
        for (int p = 1; p <= 5; p++) {
            const bool hs = (k > 0) && (p > 1);
            // h_comb = mlp2([h, node_store slot p-1], ni)
            if (p == 1)
                gemmM(stream, enc_n, 128, 128,
                      hs ? node_store + (size_t)(p - 2) * 128 : nullptr, 512, hs ? 128 : 0,
                      WT + WT_NIW1, WTL + WT_NIW1, 256, ni_b1,
                      A_hidden, 256, VNn, 256, 256, true);
            else
                gemmM(stream, upd_node + (size_t)(p - 2) * 128, 640, 128,
                      hs ? node_store + (size_t)(p - 2) * 128 : nullptr, 512, hs ? 128 : 0,
                      WT + WT_NIW1, WTL + WT_NIW1, 256, ni_b1,
                      A_hidden, 256, VNn, 256, 256, true);
            gemmM(stream, A_hidden, 256, 256, nullptr, 0, 0, WT + WT_NIW2, WTL + WT_NIW2, 256,
                  ni_b2, A_hcomb, 128, VNn, 128, 128, false);
            if (k > 0) {
                if (p == 1) {
                    // store slot 0 == 0 -> e_comb == ECOMB slot 0 (valid);
                    // only refresh ec2 into A_ec2.
                    gemmM(stream, ecomb, 128, 128, nullptr, 0, 0,
                          WT + WT_MSG + 256, WTL + WT_MSG + 256, 384,
                          msg_b, A_ec2, 256, VEe, 256, 256, false);
                } else {
                    float* ec_slot = ecomb + (size_t)(p - 1) * VEe * 128;
                    gemmM(stream, enc_e, 128, 128,
                          edge_store + (size_t)(p - 2) * 256, 1024, 256,
                          WT + WT_EIW1, WTL + WT_EIW1, 384, ei_b1,
                          A_ehid, 384, VEe, 384, 384, true);
                    gemmM(stream, A_ehid, 384, 384, nullptr, 0, 0,
                          WT + WT_EIW2, WTL + WT_EIW2, 384,
                          ei_b2, ec_slot, 128, VEe, 128, 128, false);
                    gemmM(stream, ec_slot, 128, 128, nullptr, 0, 0,
                          WT + WT_MSG + 256, WTL + WT_MSG + 256, 384,
                          msg_b, A_ec2, 256, VEe, 256, 256, false);
                }
            }
            // P01 = h_comb @ [W0|W1]
            gemmM(stream, A_hcomb, 128, 128, nullptr, 0, 0, WT + WT_P01, WTL + WT_P01, 128,
                  nullptr, A_P01, 512, VNn, 512, 512, false);
            agg_kernel<<<NGg, 256, 0, stream>>>(A_P01, A_ec2, from_idx, to_idx, A_aggb);
            // h = mlp2([h_comb, agg], nu) -> upd_node slot p
            gemmM(stream, A_hcomb, 128, 128, A_aggb, 256, 256, WT + WT_NUW1, WTL + WT_NUW1, 384,
                  nu_b1, A_hidden, 256, VNn, 256, 256, true);
            gemmM(stream, A_hidden, 256, 256, nullptr, 0, 0, WT + WT_NUW2, WTL + WT_NUW2, 256,
                  nu_b2, upd_node + (size_t)(p - 1) * 128, 640, VNn, 128, 128, false);
        }
        // ---- node transport (fused la + sinkhorn) ----
        gemmM(stream, upd_node + 512, 640, 128, nullptr, 0, 0, WT + WT_NS1, WTL + WT_NS1, 128,
              ns_b1, B_thid_n, 64, VNn, 128, 64, true);
        gemmM(stream, B_thid_n, 64, 64, nullptr, 0, 0, WT + WT_NS2, WTL + WT_NS2, 64,
              ns_b2, B_ttreal_n, 64, VNn, 128, 64, false);
        la_sinkhorn64_kernel<<<Bb, 256, 0, stream>>>(B_ttreal_n, n_la);
        if (k < 2) {
            bgemmDual(stream, n_la, 64, 48, upd_node, 640, node_store, 512, 512);
            // ---- edge transport ----
            // slot 5: A_ec2 already holds slot-5's ec2 (k=0: shared slot-0;
            // k>=1: phase-A p=5 left ecomb-slot-4's ec2). msgs in place.
            gemmM(stream, upd_node + 512, 640, 128, nullptr, 0, 0,
                  WT + WT_WSUM, WTL + WT_WSUM, 128,
                  nullptr, B_Qs, 256, VNn, 256, 256, false);
            msgs_inplace_kernel<<<VEe, 256, 0, stream>>>(A_ec2, B_Qs, from_idx, to_idx);
            gemmM(stream, A_ec2, 256, 256, nullptr, 0, 0, WT + WT_ES1, WTL + WT_ES1, 256,
                  es_b1, B_thid_e, 64, VEe, 128, 64, true);
            gemmM(stream, B_thid_e, 64, 64, nullptr, 0, 0, WT + WT_ES2, WTL + WT_ES2, 64,
                  es_b2, B_ttreal_e, 64, VEe, 128, 64, false);
            la_gemm256_kernel<<<dim3(4, 4, Bb), 256, 0, stream>>>(B_ttreal_e, B_ela);
            sinkhorn256_kernel<<<Bb, 1024, 0, stream>>>(B_ela);
            for (int sl = 1; sl <= 4; sl++) {
                const size_t ss = (k == 0) ? 0 : (size_t)(sl - 1);
                gemmM(stream, upd_node + (size_t)(sl - 1) * 128, 640, 128, nullptr, 0, 0,
                      WT + WT_WSUM, WTL + WT_WSUM, 128,
                      nullptr, B_Qs, 256, VNn, 256, 256, false);
                // fused: msgs = 2*(ecomb_ss @ Wmsg2 + msg_b) + Qs[f] + Qs[t]
                gemm_ec2msgs_kernel<<<dim3(2, VEe / 128), 256, 0, stream>>>(
                    ecomb + ss * VEe * 128,
                    WT + WT_MSG + 256, WTL + WT_MSG + 256, 384,
                    msg_b, B_Qs, from_idx, to_idx, B_msgs);
                bgemmDual(stream, B_ela, 256, 192, B_msgs, 256,
                          edge_store + (size_t)(sl - 1) * 256, 1024, 256);
            }
        }
    }
    score_kernel<<<Bb, 128, 0, stream>>>(upd_node, n_la, (float*)d_out);
}

// Round 13
// 3848.953 us; speedup vs baseline: 1.5020x; 1.0017x over previous
//
#include <hip/hip_runtime.h>
#include <cstdint>
#include <cstddef>

// Problem constants (from reference)
#define NGg   128     // 2*B
#define Bb    64
#define Nn    48
#define Ee    192
#define Sdim  64
#define VNn   6144    // NGg*Nn
#define VEe   24576   // NGg*Ee
#define INV_TEMP 10.0f

typedef unsigned short u16;
typedef __attribute__((ext_vector_type(8))) short short8;
typedef __attribute__((ext_vector_type(4))) float floatx4;

// round-to-nearest-even fp32 -> bf16
__device__ __forceinline__ u16 f2bf(float f)
{
    unsigned int u = __float_as_uint(f);
    u += 0x7FFFu + ((u >> 16) & 1u);
    return (u16)(u >> 16);
}
__device__ __forceinline__ float bf2f(u16 h)
{
    return __uint_as_float(((unsigned int)h) << 16);
}

// ---------------------------------------------------------------------------
// Split-precision bf16x3 MFMA GEMM ("emulated fp32"):
//   C = maybeReLU( (A_hi+A_lo) @ (W_hi+W_lo) + bias ),  dropping lo*lo.
// 128x128 tile, BK=32, 4 waves 2x2, wave = 4x4 mfma 16x16x32 x3.
// ---------------------------------------------------------------------------
#define TW 40
__global__ __launch_bounds__(256) void gemm_mfma_kernel(
    const float* __restrict__ A1, int lda1, int K1,
    const float* __restrict__ A2, int lda2, int K2,
    const u16* __restrict__ Wh, const u16* __restrict__ Wl, int ldwt,
    const float* __restrict__ bias,
    float* __restrict__ C, int ldc,
    int Ncap, int relu)
{
    __shared__ __align__(16) u16 Ah[128 * TW];
    __shared__ __align__(16) u16 Al[128 * TW];
    __shared__ __align__(16) u16 Bh[128 * TW];
    __shared__ __align__(16) u16 Bl[128 * TW];
    const int tid = threadIdx.x;
    const int lane = tid & 63, wave = tid >> 6;
    const int wm = wave >> 1, wn = wave & 1;
    const int bm = blockIdx.y * 128, bn = blockIdx.x * 128;
    const int K = K1 + K2;
    const int srow = tid >> 1;
    const int skoff = (tid & 1) * 16;

    floatx4 acc[4][4];
    #pragma unroll
    for (int i = 0; i < 4; i++)
        #pragma unroll
        for (int j = 0; j < 4; j++) acc[i][j] = (floatx4){0.f, 0.f, 0.f, 0.f};

    const int arow = bm + srow;
    const int brow = bn + srow;
    const int l15 = lane & 15, lq = lane >> 4;

    for (int k0 = 0; k0 < K; k0 += 32) {
        const int kk = k0 + skoff;
        const float* asrc = (kk < K1) ? (A1 + (size_t)arow * lda1 + kk)
                                      : (A2 + (size_t)arow * lda2 + (kk - K1));
        float f[16];
        ((float4*)f)[0] = ((const float4*)asrc)[0];
        ((float4*)f)[1] = ((const float4*)asrc)[1];
        ((float4*)f)[2] = ((const float4*)asrc)[2];
        ((float4*)f)[3] = ((const float4*)asrc)[3];
        u16 ph[16], pl8[16];
        #pragma unroll
        for (int q = 0; q < 16; q++) {
            u16 h = f2bf(f[q]);
            ph[q] = h;
            pl8[q] = f2bf(f[q] - bf2f(h));
        }
        *(uint4*)&Ah[srow * TW + skoff]     = *(const uint4*)&ph[0];
        *(uint4*)&Ah[srow * TW + skoff + 8] = *(const uint4*)&ph[8];
        *(uint4*)&Al[srow * TW + skoff]     = *(const uint4*)&pl8[0];
        *(uint4*)&Al[srow * TW + skoff + 8] = *(const uint4*)&pl8[8];
        const u16* bh = Wh + (size_t)brow * ldwt + kk;
        const u16* bl = Wl + (size_t)brow * ldwt + kk;
        *(uint4*)&Bh[srow * TW + skoff]     = ((const uint4*)bh)[0];
        *(uint4*)&Bh[srow * TW + skoff + 8] = ((const uint4*)bh)[1];
        *(uint4*)&Bl[srow * TW + skoff]     = ((const uint4*)bl)[0];
        *(uint4*)&Bl[srow * TW + skoff + 8] = ((const uint4*)bl)[1];
        __syncthreads();
        short8 afh[4], afl[4], bfh[4], bfl[4];
        #pragma unroll
        for (int i = 0; i < 4; i++) {
            const int ro = (wm * 64 + i * 16 + l15) * TW + lq * 8;
            afh[i] = *(const short8*)&Ah[ro];
            afl[i] = *(const short8*)&Al[ro];
        }
        #pragma unroll
        for (int j = 0; j < 4; j++) {
            const int ro = (wn * 64 + j * 16 + l15) * TW + lq * 8;
            bfh[j] = *(const short8*)&Bh[ro];
            bfl[j] = *(const short8*)&Bl[ro];
        }
        #pragma unroll
        for (int i = 0; i < 4; i++)
            #pragma unroll
            for (int j = 0; j < 4; j++) {
                acc[i][j] = __builtin_amdgcn_mfma_f32_16x16x32_bf16(afh[i], bfl[j], acc[i][j], 0, 0, 0);
                acc[i][j] = __builtin_amdgcn_mfma_f32_16x16x32_bf16(afl[i], bfh[j], acc[i][j], 0, 0, 0);
                acc[i][j] = __builtin_amdgcn_mfma_f32_16x16x32_bf16(afh[i], bfh[j], acc[i][j], 0, 0, 0);
            }
        __syncthreads();
    }
    #pragma unroll
    for (int j = 0; j < 4; j++) {
        const int col = bn + wn * 64 + j * 16 + l15;
        const bool cok = (col < Ncap);
        const float bv = (bias && cok) ? bias[col] : 0.f;
        #pragma unroll
        for (int i = 0; i < 4; i++) {
            const int row0 = bm + wm * 64 + i * 16 + lq * 4;
            #pragma unroll
            for (int r = 0; r < 4; r++) {
                float v = acc[i][j][r] + bv;
                if (relu) v = fmaxf(v, 0.f);
                if (cok) C[(size_t)(row0 + r) * ldc + col] = v;
            }
        }
    }
}

static inline void gemmM(hipStream_t s,
                         const float* A1, int lda1, int K1,
                         const float* A2, int lda2, int K2,
                         const u16* Wh, const u16* Wl, int ldwt,
                         const float* bias,
                         float* C, int ldc, int M, int Ngrid, int Ncap, bool relu)
{
    dim3 grid(Ngrid / 128, M / 128);
    gemm_mfma_kernel<<<grid, 256, 0, s>>>(A1, lda1, K1, A2, lda2, K2, Wh, Wl, ldwt,
                                          bias, C, ldc, Ncap, relu ? 1 : 0);
}

// ---------------------------------------------------------------------------
// Fused ec2+msgs GEMM (edge transport): for edge row e,
//   out[e][col] = 2*( (ecomb[e]@Wmsg2)[col] + msg_b[col] )
//                 + Qs[from[e]][col] + Qs[to[e]][col]
// A = ecomb slot (VE x 128), K=128, N=256 fixed.
// ---------------------------------------------------------------------------
__global__ __launch_bounds__(256) void gemm_ec2msgs_kernel(
    const float* __restrict__ A,
    const u16* __restrict__ Wh, const u16* __restrict__ Wl, int ldwt,
    const float* __restrict__ bias,
    const float* __restrict__ Qs,
    const int* __restrict__ from_idx, const int* __restrict__ to_idx,
    float* __restrict__ M)
{
    __shared__ __align__(16) u16 Ah[128 * TW];
    __shared__ __align__(16) u16 Al[128 * TW];
    __shared__ __align__(16) u16 Bh[128 * TW];
    __shared__ __align__(16) u16 Bl[128 * TW];
    const int tid = threadIdx.x;
    const int lane = tid & 63, wave = tid >> 6;
    const int wm = wave >> 1, wn = wave & 1;
    const int bm = blockIdx.y * 128, bn = blockIdx.x * 128;
    const int srow = tid >> 1;
    const int skoff = (tid & 1) * 16;

    floatx4 acc[4][4];
    #pragma unroll
    for (int i = 0; i < 4; i++)
        #pragma unroll
        for (int j = 0; j < 4; j++) acc[i][j] = (floatx4){0.f, 0.f, 0.f, 0.f};

    const int arow = bm + srow;
    const int brow = bn + srow;
    const int l15 = lane & 15, lq = lane >> 4;

    for (int k0 = 0; k0 < 128; k0 += 32) {
        const int kk = k0 + skoff;
        const float* asrc = A + (size_t)arow * 128 + kk;
        float f[16];
        ((float4*)f)[0] = ((const float4*)asrc)[0];
        ((float4*)f)[1] = ((const float4*)asrc)[1];
        ((float4*)f)[2] = ((const float4*)asrc)[2];
        ((float4*)f)[3] = ((const float4*)asrc)[3];
        u16 ph[16], pl8[16];
        #pragma unroll
        for (int q = 0; q < 16; q++) {
            u16 h = f2bf(f[q]);
            ph[q] = h;
            pl8[q] = f2bf(f[q] - bf2f(h));
        }
        *(uint4*)&Ah[srow * TW + skoff]     = *(const uint4*)&ph[0];
        *(uint4*)&Ah[srow * TW + skoff + 8] = *(const uint4*)&ph[8];
        *(uint4*)&Al[srow * TW + skoff]     = *(const uint4*)&pl8[0];
        *(uint4*)&Al[srow * TW + skoff + 8] = *(const uint4*)&pl8[8];
        const u16* bh = Wh + (size_t)brow * ldwt + kk;
        const u16* bl = Wl + (size_t)brow * ldwt + kk;
        *(uint4*)&Bh[srow * TW + skoff]     = ((const uint4*)bh)[0];
        *(uint4*)&Bh[srow * TW + skoff + 8] = ((const uint4*)bh)[1];
        *(uint4*)&Bl[srow * TW + skoff]     = ((const uint4*)bl)[0];
        *(uint4*)&Bl[srow * TW + skoff + 8] = ((const uint4*)bl)[1];
        __syncthreads();
        short8 afh[4], afl[4], bfh[4], bfl[4];
        #pragma unroll
        for (int i = 0; i < 4; i++) {
            const int ro = (wm * 64 + i * 16 + l15) * TW + lq * 8;
            afh[i] = *(const short8*)&Ah[ro];
            afl[i] = *(const short8*)&Al[ro];
        }
        #pragma unroll
        for (int j = 0; j < 4; j++) {
            const int ro = (wn * 64 + j * 16 + l15) * TW + lq * 8;
            bfh[j] = *(const short8*)&Bh[ro];
            bfl[j] = *(const short8*)&Bl[ro];
        }
        #pragma unroll
        for (int i = 0; i < 4; i++)
            #pragma unroll
            for (int j = 0; j < 4; j++) {
                acc[i][j] = __builtin_amdgcn_mfma_f32_16x16x32_bf16(afh[i], bfl[j], acc[i][j], 0, 0, 0);
                acc[i][j] = __builtin_amdgcn_mfma_f32_16x16x32_bf16(afl[i], bfh[j], acc[i][j], 0, 0, 0);
                acc[i][j] = __builtin_amdgcn_mfma_f32_16x16x32_bf16(afh[i], bfh[j], acc[i][j], 0, 0, 0);
            }
        __syncthreads();
    }
    #pragma unroll
    for (int i = 0; i < 4; i++) {
        #pragma unroll
        for (int r = 0; r < 4; r++) {
            const int row = bm + wm * 64 + i * 16 + lq * 4 + r;
            const int fi = from_idx[row], ti = to_idx[row];
            #pragma unroll
            for (int j = 0; j < 4; j++) {
                const int col = bn + wn * 64 + j * 16 + l15;
                float v = 2.f * (acc[i][j][r] + bias[col])
                        + Qs[(size_t)fi * 256 + col] + Qs[(size_t)ti * 256 + col];
                M[(size_t)row * 256 + col] = v;
            }
        }
    }
}

// ---------------------------------------------------------------------------
// One-shot weight prep: all transposed hi/lo bf16 weight planes in a single
// kernel (segment table compile-time; Wsum computed inline from msg_W).
// ---------------------------------------------------------------------------
__global__ __launch_bounds__(256) void prep_kernel(
    const float* __restrict__ niW1, const float* __restrict__ niW2,
    const float* __restrict__ eiW1, const float* __restrict__ eiW2,
    const float* __restrict__ msgW, const float* __restrict__ nuW1,
    const float* __restrict__ nuW2, const float* __restrict__ encnW,
    const float* __restrict__ enceW, const float* __restrict__ nsW1,
    const float* __restrict__ nsW2, const float* __restrict__ esW1,
    const float* __restrict__ esW2,
    u16* __restrict__ WT, u16* __restrict__ WTL)
{
    int idx = blockIdx.x * 256 + threadIdx.x;
    if (idx >= 696320) return;
    const float* src; int base, N, Npad, ldk, noff = 0, wtoff;
    int wsum = 0;
    if      (idx < 65536)  { src = niW1;  base = 0;      N = 256; Npad = 256; ldk = 256; wtoff = 0; }
    else if (idx < 98304)  { src = niW2;  base = 65536;  N = 128; Npad = 128; ldk = 256; wtoff = 65536; }
    else if (idx < 245760) { src = eiW1;  base = 98304;  N = 384; Npad = 384; ldk = 384; wtoff = 98304; }
    else if (idx < 294912) { src = eiW2;  base = 245760; N = 128; Npad = 128; ldk = 384; wtoff = 245760; }
    else if (idx < 393216) { src = msgW;  base = 294912; N = 256; Npad = 256; ldk = 384; wtoff = 294912; }
    else if (idx < 425984) { src = msgW;  base = 393216; N = 256; Npad = 256; ldk = 128; wtoff = 393216; }
    else if (idx < 458752) { src = msgW + 32768; base = 425984; N = 256; Npad = 256; ldk = 128; noff = 256; wtoff = 393216; }
    else if (idx < 557056) { src = nuW1;  base = 458752; N = 256; Npad = 256; ldk = 384; wtoff = 458752; }
    else if (idx < 589824) { src = nuW2;  base = 557056; N = 128; Npad = 128; ldk = 256; wtoff = 557056; }
    else if (idx < 622592) { src = msgW;  base = 589824; N = 256; Npad = 256; ldk = 128; wtoff = 589824; wsum = 1; }
    else if (idx < 626688) { src = encnW; base = 622592; N = 128; Npad = 128; ldk = 32;  wtoff = 622592; }
    else if (idx < 630784) { src = enceW; base = 626688; N = 128; Npad = 128; ldk = 32;  wtoff = 626688; }
    else if (idx < 647168) { src = nsW1;  base = 630784; N = 64;  Npad = 128; ldk = 128; wtoff = 630784; }
    else if (idx < 655360) { src = nsW2;  base = 647168; N = 64;  Npad = 128; ldk = 64;  wtoff = 647168; }
    else if (idx < 688128) { src = esW1;  base = 655360; N = 64;  Npad = 128; ldk = 256; wtoff = 655360; }
    else                   { src = esW2;  base = 688128; N = 64;  Npad = 128; ldk = 64;  wtoff = 688128; }
    int rel = idx - base;
    int k = rel / Npad, n = rel % Npad;
    float v = 0.f;
    if (n < N) {
        v = src[(size_t)k * N + n];
        if (wsum) v += src[32768 + (size_t)k * N + n];
    }
    u16 h = f2bf(v);
    size_t o = (size_t)wtoff + (size_t)(noff + n) * ldk + k;
    WT[o] = h;
    WTL[o] = f2bf(v - bf2f(h));
}

// ---------------------------------------------------------------------------
// Dual batched MFMA plan-GEMM: qi (transp=0) + ci (transp=1) in one launch.
// ---------------------------------------------------------------------------
__global__ __launch_bounds__(256) void bgemm_dual_kernel(
    const float* __restrict__ P, int ms, int n_per,
    const float* __restrict__ U, int ldu,
    float* __restrict__ C, int ldc, int nxh)
{
    __shared__ __align__(16) u16 Ah[64 * TW];
    __shared__ __align__(16) u16 Al[64 * TW];
    __shared__ __align__(16) u16 Bh[128 * TW];
    __shared__ __align__(16) u16 Bl[128 * TW];
    const int b = blockIdx.z;
    const float* Pb = P + (size_t)b * ms * ms;
    const int bxr = blockIdx.x;
    const int transp = (bxr >= nxh) ? 1 : 0;
    const int bn = (bxr - transp * nxh) * 128;
    const int qbase = (2 * b) * n_per, cbase = (2 * b + 1) * n_per;
    const int obase = transp ? cbase : qbase;
    const int ibase = transp ? qbase : cbase;
    const int bm = blockIdx.y * 64;
    const int tid = threadIdx.x, lane = tid & 63, wave = tid >> 6;
    const int wm = wave >> 1, wn = wave & 1;
    const int l15 = lane & 15, lq = lane >> 4;
    const int sar = tid >> 2, sak = (tid & 3) * 8;
    const int sbn = tid >> 1, sbk = (tid & 1) * 16;
    const int Kpad = (n_per + 31) & ~31;

    floatx4 acc[2][4];
    #pragma unroll
    for (int i = 0; i < 2; i++)
        #pragma unroll
        for (int j = 0; j < 4; j++) acc[i][j] = (floatx4){0.f, 0.f, 0.f, 0.f};

    for (int k0 = 0; k0 < Kpad; k0 += 32) {
        {
            u16 ph[8], pl8[8];
            const int m = bm + sar;
            #pragma unroll
            for (int i = 0; i < 8; i++) {
                int kk = k0 + sak + i;
                float v = 0.f;
                if (kk < n_per && m < n_per)
                    v = transp ? Pb[(size_t)kk * ms + m] : Pb[(size_t)m * ms + kk];
                u16 h = f2bf(v);
                ph[i] = h; pl8[i] = f2bf(v - bf2f(h));
            }
            *(uint4*)&Ah[sar * TW + sak] = *(const uint4*)&ph[0];
            *(uint4*)&Al[sar * TW + sak] = *(const uint4*)&pl8[0];
        }
        {
            u16 qh[16], ql[16];
            #pragma unroll
            for (int i = 0; i < 16; i++) {
                int kk = k0 + sbk + i;
                float v = 0.f;
                if (kk < n_per) v = U[(size_t)(ibase + kk) * ldu + bn + sbn];
                u16 h = f2bf(v);
                qh[i] = h; ql[i] = f2bf(v - bf2f(h));
            }
            *(uint4*)&Bh[sbn * TW + sbk]     = *(const uint4*)&qh[0];
            *(uint4*)&Bh[sbn * TW + sbk + 8] = *(const uint4*)&qh[8];
            *(uint4*)&Bl[sbn * TW + sbk]     = *(const uint4*)&ql[0];
            *(uint4*)&Bl[sbn * TW + sbk + 8] = *(const uint4*)&ql[8];
        }
        __syncthreads();
        short8 afh[2], afl[2], bfh[4], bfl[4];
        #pragma unroll
        for (int i = 0; i < 2; i++) {
            const int ro = (wm * 32 + i * 16 + l15) * TW + lq * 8;
            afh[i] = *(const short8*)&Ah[ro];
            afl[i] = *(const short8*)&Al[ro];
        }
        #pragma unroll
        for (int j = 0; j < 4; j++) {
            const int ro = (wn * 64 + j * 16 + l15) * TW + lq * 8;
            bfh[j] = *(const short8*)&Bh[ro];
            bfl[j] = *(const short8*)&Bl[ro];
        }
        #pragma unroll
        for (int i = 0; i < 2; i++)
            #pragma unroll
            for (int j = 0; j < 4; j++) {
                acc[i][j] = __builtin_amdgcn_mfma_f32_16x16x32_bf16(afh[i], bfl[j], acc[i][j], 0, 0, 0);
                acc[i][j] = __builtin_amdgcn_mfma_f32_16x16x32_bf16(afl[i], bfh[j], acc[i][j], 0, 0, 0);
                acc[i][j] = __builtin_amdgcn_mfma_f32_16x16x32_bf16(afh[i], bfh[j], acc[i][j], 0, 0, 0);
            }
        __syncthreads();
    }
    #pragma unroll
    for (int j = 0; j < 4; j++) {
        const int col = bn + wn * 64 + j * 16 + l15;
        #pragma unroll
        for (int i = 0; i < 2; i++) {
            const int row0 = bm + wm * 32 + i * 16 + lq * 4;
            #pragma unroll
            for (int r = 0; r < 4; r++) {
                const int m = row0 + r;
                if (m < n_per)
                    C[(size_t)(obase + m) * ldc + col] = acc[i][j][r];
            }
        }
    }
}

static inline void bgemmDual(hipStream_t s, const float* P, int ms, int n_per,
                             const float* U, int ldu, float* C, int ldc, int N)
{
    int nxh = N / 128;
    dim3 grid(nxh * 2, (n_per + 63) / 64, Bb);
    bgemm_dual_kernel<<<grid, 256, 0, s>>>(P, ms, n_per, U, ldu, C, ldc, nxh);
}

// ---------------------------------------------------------------------------
// Fused node transport: la (64x64) + 10 Sinkhorn iters (potential form) +
// plan=exp write. 4 waves; wave w owns rows 16w..16w+15; lane owns a col.
// ---------------------------------------------------------------------------
__global__ __launch_bounds__(256) void la_sinkhorn64_kernel(
    const float* __restrict__ tt, float* __restrict__ n_la)
{
    const int b = blockIdx.x;
    __shared__ float Aq[64][65];
    __shared__ float Ac[64][65];
    __shared__ float m[64][65];
    __shared__ float v_s[64];
    __shared__ float part[4][64];
    const int tid = threadIdx.x;
    const int lane = tid & 63, w = tid >> 6;
    for (int idx = tid; idx < 4096; idx += 256) {
        int r = idx >> 6, s = idx & 63;
        float vq = 0.f, vc = 0.f;
        if (r < Nn) {
            vq = tt[((size_t)(2 * b) * Nn + r) * Sdim + s];
            vc = tt[((size_t)(2 * b + 1) * Nn + r) * Sdim + s];
        }
        Aq[r][s] = vq;
        Ac[r][s] = vc;
    }
    __syncthreads();
    {
        const int tx = tid & 15, ty = tid >> 4;
        float acc[4][4] = {};
        for (int s = 0; s < 64; s++) {
            float a[4], c[4];
            #pragma unroll
            for (int i = 0; i < 4; i++) a[i] = Aq[ty * 4 + i][s];
            #pragma unroll
            for (int j = 0; j < 4; j++) c[j] = Ac[tx * 4 + j][s];
            #pragma unroll
            for (int i = 0; i < 4; i++)
                #pragma unroll
                for (int j = 0; j < 4; j++)
                    acc[i][j] = fmaf(a[i], c[j], acc[i][j]);
        }
        #pragma unroll
        for (int i = 0; i < 4; i++)
            #pragma unroll
            for (int j = 0; j < 4; j++)
                m[ty * 4 + i][tx * 4 + j] = acc[i][j] * INV_TEMP;
    }
    if (tid < 64) v_s[tid] = 0.f;
    __syncthreads();
    float x[16], u[16];
    #pragma unroll
    for (int j = 0; j < 16; j++) x[j] = m[w * 16 + j][lane];
    #pragma unroll
    for (int j = 0; j < 16; j++) {
        float mx = x[j];
        #pragma unroll
        for (int d = 1; d < 64; d <<= 1) mx = fmaxf(mx, __shfl_xor(mx, d));
        u[j] = mx;
    }
    for (int it = 0; it < 10; it++) {
        float vr = v_s[lane];
        #pragma unroll
        for (int j = 0; j < 16; j++) {
            float s = __expf(x[j] - vr - u[j]);
            #pragma unroll
            for (int d = 1; d < 64; d <<= 1) s += __shfl_xor(s, d);
            u[j] += __logf(s);
        }
        float s = 0.f;
        #pragma unroll
        for (int j = 0; j < 16; j++) s += __expf(x[j] - u[j] - vr);
        part[w][lane] = s;
        __syncthreads();
        if (tid < 64) {
            float ss = part[0][tid] + part[1][tid] + part[2][tid] + part[3][tid];
            v_s[tid] += __logf(ss);
        }
        __syncthreads();
    }
    float vr = v_s[lane];
    float* g = n_la + (size_t)b * 4096;
    #pragma unroll
    for (int j = 0; j < 16; j++)
        g[(size_t)(w * 16 + j) * 64 + lane] = __expf(x[j] - u[j] - vr);
}

// la for edges (256x256): la[b][q][c] = 10 * tq[q]·tc[c], fp32 ttreal guarded.
__global__ __launch_bounds__(256) void la_gemm256_kernel(
    const float* __restrict__ tt, float* __restrict__ la)
{
    const int b = blockIdx.z;
    const int bm = blockIdx.y * 64, bn = blockIdx.x * 64;
    __shared__ float Aq[64][65];
    __shared__ float Ac[64][65];
    const int tid = threadIdx.x;
    for (int idx = tid; idx < 4096; idx += 256) {
        int r = idx >> 6, s = idx & 63;
        float vq = 0.f, vc = 0.f;
        int qr = bm + r, cr = bn + r;
        if (qr < Ee) vq = tt[((size_t)(2 * b) * Ee + qr) * Sdim + s];
        if (cr < Ee) vc = tt[((size_t)(2 * b + 1) * Ee + cr) * Sdim + s];
        Aq[r][s] = vq;
        Ac[r][s] = vc;
    }
    __syncthreads();
    const int tx = tid & 15, ty = tid >> 4;
    float acc[4][4] = {};
    for (int s = 0; s < 64; s++) {
        float a[4], c[4];
        #pragma unroll
        for (int i = 0; i < 4; i++) a[i] = Aq[ty * 4 + i][s];
        #pragma unroll
        for (int j = 0; j < 4; j++) c[j] = Ac[tx * 4 + j][s];
        #pragma unroll
        for (int i = 0; i < 4; i++)
            #pragma unroll
            for (int j = 0; j < 4; j++)
                acc[i][j] = fmaf(a[i], c[j], acc[i][j]);
    }
    #pragma unroll
    for (int i = 0; i < 4; i++)
        #pragma unroll
        for (int j = 0; j < 4; j++)
            la[((size_t)b * 256 + bm + ty * 4 + i) * 256 + bn + tx * 4 + j] = acc[i][j] * INV_TEMP;
}

// ---------------------------------------------------------------------------
// Sinkhorn 256x256, potential form, register-resident rows.
// amdgpu_waves_per_eu(4,4) in LEADING position (round-12's placement between
// `void` and __launch_bounds__ was ignored: VGPR stayed 64 with 50MB scratch).
// max=4 waves/EU -> 128-VGPR budget -> x[64]+u[16] fit, no spills.
// ---------------------------------------------------------------------------
__attribute__((amdgpu_waves_per_eu(4, 4)))
__global__ __launch_bounds__(1024) void sinkhorn256_kernel(float* __restrict__ la)
{
    const int b = blockIdx.x;
    float* g = la + (size_t)b * 65536;
    const int tid = threadIdx.x;
    const int lane = tid & 63, w = tid >> 6;
    __shared__ float v_s[256];
    __shared__ float part[16][64][5];

    float x[4][16];
    #pragma unroll
    for (int cc = 0; cc < 4; cc++)
        #pragma unroll
        for (int j = 0; j < 16; j++)
            x[cc][j] = g[(size_t)(w * 16 + j) * 256 + cc * 64 + lane];

    float u[16];
    #pragma unroll
    for (int j = 0; j < 16; j++) {
        float mx = fmaxf(fmaxf(x[0][j], x[1][j]), fmaxf(x[2][j], x[3][j]));
        #pragma unroll
        for (int d = 1; d < 64; d <<= 1) mx = fmaxf(mx, __shfl_xor(mx, d));
        u[j] = mx;
    }
    if (tid < 256) v_s[tid] = 0.f;
    __syncthreads();

    for (int it = 0; it < 10; it++) {
        float vr[4];
        #pragma unroll
        for (int cc = 0; cc < 4; cc++) vr[cc] = v_s[cc * 64 + lane];
        #pragma unroll
        for (int j = 0; j < 16; j++) {
            float s = __expf(x[0][j] - vr[0] - u[j]) + __expf(x[1][j] - vr[1] - u[j])
                    + __expf(x[2][j] - vr[2] - u[j]) + __expf(x[3][j] - vr[3] - u[j]);
            #pragma unroll
            for (int d = 1; d < 64; d <<= 1) s += __shfl_xor(s, d);
            u[j] += __logf(s);
        }
        #pragma unroll
        for (int cc = 0; cc < 4; cc++) {
            float s = 0.f;
            #pragma unroll
            for (int j = 0; j < 16; j++) s += __expf(x[cc][j] - u[j] - vr[cc]);
            part[w][lane][cc] = s;
        }
        __syncthreads();
        if (tid < 256) {
            const int cl = tid & 63, cc = tid >> 6;
            float ss = 0.f;
            #pragma unroll
            for (int w2 = 0; w2 < 16; w2++) ss += part[w2][cl][cc];
            v_s[tid] += __logf(ss);
        }
        __syncthreads();
    }
    float vr[4];
    #pragma unroll
    for (int cc = 0; cc < 4; cc++) vr[cc] = v_s[cc * 64 + lane];
    #pragma unroll
    for (int cc = 0; cc < 4; cc++)
        #pragma unroll
        for (int j = 0; j < 16; j++)
            g[(size_t)(w * 16 + j) * 256 + cc * 64 + lane] = __expf(x[cc][j] - u[j] - vr[cc]);
}

// ---------------------------------------------------------------------------
// Group-local message aggregation; P0/P1 packed in P01 (ld 512), fp32.
// ---------------------------------------------------------------------------
__global__ __launch_bounds__(256) void agg_kernel(
    const float* __restrict__ P01,
    const float* __restrict__ ec2,
    const int* __restrict__ from_idx, const int* __restrict__ to_idx,
    float* __restrict__ agg)
{
    const int gblk = blockIdx.x;
    const int d = threadIdx.x;
    __shared__ float acc[48][256];
    __shared__ int fr[192], to[192];
    #pragma unroll
    for (int n = 0; n < 48; n++) acc[n][d] = 0.f;
    if (d < 192) {
        fr[d] = from_idx[gblk * 192 + d] - gblk * 48;
        to[d] = to_idx[gblk * 192 + d] - gblk * 48;
    }
    __syncthreads();
    const int nb = gblk * 48;
    const int eb = gblk * 192;
    for (int e = 0; e < 192; e++) {
        int f = fr[e], t = to[e];
        float ee  = ec2[(size_t)(eb + e) * 256 + d];
        float p0f = P01[(size_t)(nb + f) * 512 + d];
        float p1f = P01[(size_t)(nb + f) * 512 + 256 + d];
        float p0t = P01[(size_t)(nb + t) * 512 + d];
        float p1t = P01[(size_t)(nb + t) * 512 + 256 + d];
        acc[t][d] += p0f + p1t + ee;
        acc[f][d] += p0t + p1f + ee;
    }
    __syncthreads();
    for (int n = 0; n < 48; n++) agg[(size_t)(nb + n) * 256 + d] = acc[n][d];
}

// In-place messages: m[e] <- Qs[from]+Qs[to]+2*m[e]  (used only for slot 5)
__global__ __launch_bounds__(256) void msgs_inplace_kernel(
    float* __restrict__ m, const float* __restrict__ Qs,
    const int* __restrict__ from_idx, const int* __restrict__ to_idx)
{
    const int e = blockIdx.x;
    const int d = threadIdx.x;
    const int f = from_idx[e], t = to_idx[e];
    size_t o = (size_t)e * 256 + d;
    m[o] = Qs[(size_t)f * 256 + d] + Qs[(size_t)t * 256 + d] + 2.f * m[o];
}

__global__ void diag_kernel(float* __restrict__ out, float v)
{
    out[threadIdx.x] = v;
}

// score[b] = -sum relu( ffq - plan@ffc )
__global__ __launch_bounds__(128) void score_kernel(
    const float* __restrict__ upd_node, const float* __restrict__ plan,
    float* __restrict__ out)
{
    const int b = blockIdx.x;
    const int tid = threadIdx.x;
    __shared__ float ffc[48][128];
    __shared__ float pl[64][48];
    __shared__ float red[128];
    for (int c = 0; c < 48; c++)
        ffc[c][tid] = upd_node[(size_t)((2 * b + 1) * 48 + c) * 640 + 512 + tid];
    for (int idx = tid; idx < 64 * 48; idx += 128) {
        int q = idx / 48, c = idx % 48;
        pl[q][c] = plan[(size_t)b * 4096 + q * 64 + c];
    }
    __syncthreads();
    float accv = 0.f;
    for (int q = 0; q < 64; q++) {
        float rsum = 0.f;
        #pragma unroll 8
        for (int c = 0; c < 48; c++) rsum = fmaf(pl[q][c], ffc[c][tid], rsum);
        float fq = 0.f;
        if (q < 48) fq = upd_node[(size_t)((2 * b) * 48 + q) * 640 + 512 + tid];
        accv += fmaxf(fq - rsum, 0.f);
    }
    red[tid] = accv;
    __syncthreads();
    for (int sft = 64; sft > 0; sft >>= 1) {
        if (tid < sft) red[tid] += red[tid + sft];
        __syncthreads();
    }
    if (tid == 0) out[b] = -red[0];
}

// ---------------------------------------------------------------------------
// Workspace layout (floats). Total 66,265,088 floats = 265.1 MB <= 268.4 MB.
// ---------------------------------------------------------------------------
#define OFF_UPD_NODE   0ULL
#define OFF_NODE_STORE 3932160ULL
#define OFF_EDGE_STORE 7077888ULL
#define OFF_ECOMB      32243712ULL
#define OFF_ENC_N      47972352ULL
#define OFF_ENC_E      48758784ULL
#define OFF_N_LA       51904512ULL
#define OFF_WT         52199424ULL
#define OFF_WTL        52547584ULL
#define OFF_ARENA      52895744ULL
#define TOTAL_FLOATS   66265088ULL

// bf16 weight sub-offsets (u16 from WT/WTL base)
#define WT_NIW1   0
#define WT_NIW2   65536
#define WT_EIW1   98304
#define WT_EIW2   245760
#define WT_MSG    294912
#define WT_P01    393216
#define WT_NUW1   458752
#define WT_NUW2   557056
#define WT_WSUM   589824
#define WT_ENCN   622592
#define WT_ENCE   626688
#define WT_NS1    630784
#define WT_NS2    647168
#define WT_ES1    655360
#define WT_ES2    688128

extern "C" void kernel_launch(void* const* d_in, const int* in_sizes, int n_in,
                              void* d_out, int out_size, void* d_ws, size_t ws_size,
                              hipStream_t stream)
{
    (void)in_sizes; (void)n_in; (void)out_size;
    if (ws_size < TOTAL_FLOATS * sizeof(float)) {
        diag_kernel<<<1, 64, 0, stream>>>((float*)d_out, (float)ws_size);
        return;
    }

    const float* node_features = (const float*)d_in[0];
    const float* edge_features = (const float*)d_in[1];
    const int*   from_idx      = (const int*)d_in[2];
    const int*   to_idx        = (const int*)d_in[3];
    const float* enc_node_W = (const float*)d_in[4];
    const float* enc_node_b = (const float*)d_in[5];
    const float* enc_edge_W = (const float*)d_in[6];
    const float* enc_edge_b = (const float*)d_in[7];
    const float* ni_W1 = (const float*)d_in[8];
    const float* ni_b1 = (const float*)d_in[9];
    const float* ni_W2 = (const float*)d_in[10];
    const float* ni_b2 = (const float*)d_in[11];
    const float* ei_W1 = (const float*)d_in[12];
    const float* ei_b1 = (const float*)d_in[13];
    const float* ei_W2 = (const float*)d_in[14];
    const float* ei_b2 = (const float*)d_in[15];
    const float* msg_W = (const float*)d_in[16];
    const float* msg_b = (const float*)d_in[17];
    const float* nu_W1 = (const float*)d_in[18];
    const float* nu_b1 = (const float*)d_in[19];
    const float* nu_W2 = (const float*)d_in[20];
    const float* nu_b2 = (const float*)d_in[21];
    const float* ns_W1 = (const float*)d_in[22];
    const float* ns_b1 = (const float*)d_in[23];
    const float* ns_W2 = (const float*)d_in[24];
    const float* ns_b2 = (const float*)d_in[25];
    const float* es_W1 = (const float*)d_in[26];
    const float* es_b1 = (const float*)d_in[27];
    const float* es_W2 = (const float*)d_in[28];
    const float* es_b2 = (const float*)d_in[29];

    float* ws = (float*)d_ws;
    float* upd_node   = ws + OFF_UPD_NODE;
    float* node_store = ws + OFF_NODE_STORE;
    float* edge_store = ws + OFF_EDGE_STORE;
    float* ecomb      = ws + OFF_ECOMB;
    float* enc_n      = ws + OFF_ENC_N;
    float* enc_e      = ws + OFF_ENC_E;
    float* n_la       = ws + OFF_N_LA;
    u16* WT  = (u16*)(ws + OFF_WT);
    u16* WTL = (u16*)(ws + OFF_WTL);
    float* arena      = ws + OFF_ARENA;

    // Phase-A arena carve (ehid dead before ec2 is written -> alias;
    // A_ec2 survives past phase A: at transport time it holds slot-5's ec2)
    float* A_hidden = arena;                  // [0, 1.57M)   VN x 256
    float* A_hcomb  = arena + 1572864;        // [1.57, 2.36M) VN x 128
    float* A_ehid   = arena + 2359296;        // [2.36, 11.80M) VE x 384
    float* A_ec2    = arena + 2359296;        // [2.36, 8.65M) VE x 256 (alias)
    float* A_P01    = arena + 8650752;        // [8.65, 11.80M) VN x 512
    float* A_aggb   = arena + 11796480;       // [11.80, 13.37M) VN x 256
    // Phase-B carve (ordering-checked against A_ec2 liveness)
    float* B_Qs       = arena;                // VN x 256
    float* B_thid_e   = arena + 8650752;      // VE x 64
    float* B_ttreal_e = arena + 10223616;     // VE x 64
    float* B_ela      = arena + 2359296;      // 64 x 256 x 256
    float* B_msgs     = arena + 6553600;      // VE x 256
    float* B_thid_n   = arena + 12058624;     // VN x 64
    float* B_ttreal_n = arena + 12451840;     // VN x 64

    // --- one-shot weight prep ---
    prep_kernel<<<(696320 + 255) / 256, 256, 0, stream>>>(
        ni_W1, ni_W2, ei_W1, ei_W2, msg_W, nu_W1, nu_W2,
        enc_node_W, enc_edge_W, ns_W1, ns_W2, es_W1, es_W2, WT, WTL);

    // --- encoders ---
    gemmM(stream, node_features, 32, 32, nullptr, 0, 0, WT + WT_ENCN, WTL + WT_ENCN, 32,
          enc_node_b, enc_n, 128, VNn, 128, 128, false);
    gemmM(stream, edge_features, 32, 32, nullptr, 0, 0, WT + WT_ENCE, WTL + WT_ENCE, 32,
          enc_edge_b, enc_e, 128, VEe, 128, 128, false);

    for (int k = 0; k < 3; k++) {
        if (k == 0) {
            // edge_store == 0 for ALL p at k=0 -> shared e_comb/ec2, once.
            gemmM(stream, enc_e, 128, 128, nullptr, 0, 0,
                  WT + WT_EIW1, WTL + WT_EIW1, 384, ei_b1,
                  A_ehid, 384, VEe, 384, 384, true);
            gemmM(stream, A_ehid, 384, 384, nullptr, 0, 0, WT + WT_EIW2, WTL + WT_EIW2, 384,
                  ei_b2, ecomb, 128, VEe, 128, 128, false);
            gemmM(stream, ecomb, 128, 128, nullptr, 0, 0,
                  WT + WT_MSG + 256, WTL + WT_MSG + 256, 384,
                  msg_b, A_ec2, 256, VEe, 256, 256, false);
        }
        for (int p = 1; p <= 5; p++) {
            const bool hs = (k > 0) && (p > 1);
            // h_comb = mlp2([h, node_store slot p-1], ni)
            if (p == 1)
                gemmM(stream, enc_n, 128, 128,
                      hs ? node_store + (size_t)(p - 2) * 128 : nullptr, 512, hs ? 128 : 0,
                      WT + WT_NIW1, WTL + WT_NIW1, 256, ni_b1,
                      A_hidden, 256, VNn, 256, 256, true);
            else
                gemmM(stream, upd_node + (size_t)(p - 2) * 128, 640, 128,
                      hs ? node_store + (size_t)(p - 2) * 128 : nullptr, 512, hs ? 128 : 0,
                      WT + WT_NIW1, WTL + WT_NIW1, 256, ni_b1,
                      A_hidden, 256, VNn, 256, 256, true);
            gemmM(stream, A_hidden, 256, 256, nullptr, 0, 0, WT + WT_NIW2, WTL + WT_NIW2, 256,
                  ni_b2, A_hcomb, 128, VNn, 128, 128, false);
            if (k > 0) {
                if (p == 1) {
                    // store slot 0 == 0 -> e_comb == ECOMB slot 0 (valid);
                    // only refresh ec2 into A_ec2.
                    gemmM(stream, ecomb, 128, 128, nullptr, 0, 0,
                          WT + WT_MSG + 256, WTL + WT_MSG + 256, 384,
                          msg_b, A_ec2, 256, VEe, 256, 256, false);
                } else {
                    float* ec_slot = ecomb + (size_t)(p - 1) * VEe * 128;
                    gemmM(stream, enc_e, 128, 128,
                          edge_store + (size_t)(p - 2) * 256, 1024, 256,
                          WT + WT_EIW1, WTL + WT_EIW1, 384, ei_b1,
                          A_ehid, 384, VEe, 384, 384, true);
                    gemmM(stream, A_ehid, 384, 384, nullptr, 0, 0,
                          WT + WT_EIW2, WTL + WT_EIW2, 384,
                          ei_b2, ec_slot, 128, VEe, 128, 128, false);
                    gemmM(stream, ec_slot, 128, 128, nullptr, 0, 0,
                          WT + WT_MSG + 256, WTL + WT_MSG + 256, 384,
                          msg_b, A_ec2, 256, VEe, 256, 256, false);
                }
            }
            // P01 = h_comb @ [W0|W1]
            gemmM(stream, A_hcomb, 128, 128, nullptr, 0, 0, WT + WT_P01, WTL + WT_P01, 128,
                  nullptr, A_P01, 512, VNn, 512, 512, false);
            agg_kernel<<<NGg, 256, 0, stream>>>(A_P01, A_ec2, from_idx, to_idx, A_aggb);
            // h = mlp2([h_comb, agg], nu) -> upd_node slot p
            gemmM(stream, A_hcomb, 128, 128, A_aggb, 256, 256, WT + WT_NUW1, WTL + WT_NUW1, 384,
                  nu_b1, A_hidden, 256, VNn, 256, 256, true);
            gemmM(stream, A_hidden, 256, 256, nullptr, 0, 0, WT + WT_NUW2, WTL + WT_NUW2, 256,
                  nu_b2, upd_node + (size_t)(p - 1) * 128, 640, VNn, 128, 128, false);
        }
        // ---- node transport (fused la + sinkhorn) ----
        gemmM(stream, upd_node + 512, 640, 128, nullptr, 0, 0, WT + WT_NS1, WTL + WT_NS1, 128,
              ns_b1, B_thid_n, 64, VNn, 128, 64, true);
        gemmM(stream, B_thid_n, 64, 64, nullptr, 0, 0, WT + WT_NS2, WTL + WT_NS2, 64,
              ns_b2, B_ttreal_n, 64, VNn, 128, 64, false);
        la_sinkhorn64_kernel<<<Bb, 256, 0, stream>>>(B_ttreal_n, n_la);
        if (k < 2) {
            bgemmDual(stream, n_la, 64, 48, upd_node, 640, node_store, 512, 512);
            // ---- edge transport ----
            // slot 5: A_ec2 already holds slot-5's ec2. msgs in place.
            gemmM(stream, upd_node + 512, 640, 128, nullptr, 0, 0,
                  WT + WT_WSUM, WTL + WT_WSUM, 128,
                  nullptr, B_Qs, 256, VNn, 256, 256, false);
            msgs_inplace_kernel<<<VEe, 256, 0, stream>>>(A_ec2, B_Qs, from_idx, to_idx);
            gemmM(stream, A_ec2, 256, 256, nullptr, 0, 0, WT + WT_ES1, WTL + WT_ES1, 256,
                  es_b1, B_thid_e, 64, VEe, 128, 64, true);
            gemmM(stream, B_thid_e, 64, 64, nullptr, 0, 0, WT + WT_ES2, WTL + WT_ES2, 64,
                  es_b2, B_ttreal_e, 64, VEe, 128, 64, false);
            la_gemm256_kernel<<<dim3(4, 4, Bb), 256, 0, stream>>>(B_ttreal_e, B_ela);
            sinkhorn256_kernel<<<Bb, 1024, 0, stream>>>(B_ela);
            for (int sl = 1; sl <= 4; sl++) {
                const size_t ss = (k == 0) ? 0 : (size_t)(sl - 1);
                gemmM(stream, upd_node + (size_t)(sl - 1) * 128, 640, 128, nullptr, 0, 0,
                      WT + WT_WSUM, WTL + WT_WSUM, 128,
                      nullptr, B_Qs, 256, VNn, 256, 256, false);
                // fused: msgs = 2*(ecomb_ss @ Wmsg2 + msg_b) + Qs[f] + Qs[t]
                gemm_ec2msgs_kernel<<<dim3(2, VEe / 128), 256, 0, stream>>>(
                    ecomb + ss * VEe * 128,
                    WT + WT_MSG + 256, WTL + WT_MSG + 256, 384,
                    msg_b, B_Qs, from_idx, to_idx, B_msgs);
                bgemmDual(stream, B_ela, 256, 192, B_msgs, 256,
                          edge_store + (size_t)(sl - 1) * 256, 1024, 256);
            }
        }
    }
    score_kernel<<<Bb, 128, 0, stream>>>(upd_node, n_la, (float*)d_out);
}

// Round 14
// 3818.212 us; speedup vs baseline: 1.5141x; 1.0081x over previous
//
#include <hip/hip_runtime.h>
#include <cstdint>
#include <cstddef>

// Problem constants (from reference)
#define NGg   128     // 2*B
#define Bb    64
#define Nn    48
#define Ee    192
#define Sdim  64
#define VNn   6144    // NGg*Nn
#define VEe   24576   // NGg*Ee
#define INV_TEMP 10.0f

typedef unsigned short u16;
typedef __attribute__((ext_vector_type(8))) short short8;
typedef __attribute__((ext_vector_type(4))) float floatx4;

// round-to-nearest-even fp32 -> bf16
__device__ __forceinline__ u16 f2bf(float f)
{
    unsigned int u = __float_as_uint(f);
    u += 0x7FFFu + ((u >> 16) & 1u);
    return (u16)(u >> 16);
}
__device__ __forceinline__ float bf2f(u16 h)
{
    return __uint_as_float(((unsigned int)h) << 16);
}

// ---------------------------------------------------------------------------
// Split-precision bf16x3 MFMA GEMM ("emulated fp32"):
//   C = maybeReLU( (A_hi+A_lo) @ (W_hi+W_lo) + bias ),  dropping lo*lo.
// 128x128 tile, BK=32, 4 waves 2x2, wave = 4x4 mfma 16x16x32 x3.
// ---------------------------------------------------------------------------
#define TW 40
__global__ __launch_bounds__(256) void gemm_mfma_kernel(
    const float* __restrict__ A1, int lda1, int K1,
    const float* __restrict__ A2, int lda2, int K2,
    const u16* __restrict__ Wh, const u16* __restrict__ Wl, int ldwt,
    const float* __restrict__ bias,
    float* __restrict__ C, int ldc,
    int Ncap, int relu)
{
    __shared__ __align__(16) u16 Ah[128 * TW];
    __shared__ __align__(16) u16 Al[128 * TW];
    __shared__ __align__(16) u16 Bh[128 * TW];
    __shared__ __align__(16) u16 Bl[128 * TW];
    const int tid = threadIdx.x;
    const int lane = tid & 63, wave = tid >> 6;
    const int wm = wave >> 1, wn = wave & 1;
    const int bm = blockIdx.y * 128, bn = blockIdx.x * 128;
    const int K = K1 + K2;
    const int srow = tid >> 1;
    const int skoff = (tid & 1) * 16;

    floatx4 acc[4][4];
    #pragma unroll
    for (int i = 0; i < 4; i++)
        #pragma unroll
        for (int j = 0; j < 4; j++) acc[i][j] = (floatx4){0.f, 0.f, 0.f, 0.f};

    const int arow = bm + srow;
    const int brow = bn + srow;
    const int l15 = lane & 15, lq = lane >> 4;

    for (int k0 = 0; k0 < K; k0 += 32) {
        const int kk = k0 + skoff;
        const float* asrc = (kk < K1) ? (A1 + (size_t)arow * lda1 + kk)
                                      : (A2 + (size_t)arow * lda2 + (kk - K1));
        float f[16];
        ((float4*)f)[0] = ((const float4*)asrc)[0];
        ((float4*)f)[1] = ((const float4*)asrc)[1];
        ((float4*)f)[2] = ((const float4*)asrc)[2];
        ((float4*)f)[3] = ((const float4*)asrc)[3];
        u16 ph[16], pl8[16];
        #pragma unroll
        for (int q = 0; q < 16; q++) {
            u16 h = f2bf(f[q]);
            ph[q] = h;
            pl8[q] = f2bf(f[q] - bf2f(h));
        }
        *(uint4*)&Ah[srow * TW + skoff]     = *(const uint4*)&ph[0];
        *(uint4*)&Ah[srow * TW + skoff + 8] = *(const uint4*)&ph[8];
        *(uint4*)&Al[srow * TW + skoff]     = *(const uint4*)&pl8[0];
        *(uint4*)&Al[srow * TW + skoff + 8] = *(const uint4*)&pl8[8];
        const u16* bh = Wh + (size_t)brow * ldwt + kk;
        const u16* bl = Wl + (size_t)brow * ldwt + kk;
        *(uint4*)&Bh[srow * TW + skoff]     = ((const uint4*)bh)[0];
        *(uint4*)&Bh[srow * TW + skoff + 8] = ((const uint4*)bh)[1];
        *(uint4*)&Bl[srow * TW + skoff]     = ((const uint4*)bl)[0];
        *(uint4*)&Bl[srow * TW + skoff + 8] = ((const uint4*)bl)[1];
        __syncthreads();
        short8 afh[4], afl[4], bfh[4], bfl[4];
        #pragma unroll
        for (int i = 0; i < 4; i++) {
            const int ro = (wm * 64 + i * 16 + l15) * TW + lq * 8;
            afh[i] = *(const short8*)&Ah[ro];
            afl[i] = *(const short8*)&Al[ro];
        }
        #pragma unroll
        for (int j = 0; j < 4; j++) {
            const int ro = (wn * 64 + j * 16 + l15) * TW + lq * 8;
            bfh[j] = *(const short8*)&Bh[ro];
            bfl[j] = *(const short8*)&Bl[ro];
        }
        #pragma unroll
        for (int i = 0; i < 4; i++)
            #pragma unroll
            for (int j = 0; j < 4; j++) {
                acc[i][j] = __builtin_amdgcn_mfma_f32_16x16x32_bf16(afh[i], bfl[j], acc[i][j], 0, 0, 0);
                acc[i][j] = __builtin_amdgcn_mfma_f32_16x16x32_bf16(afl[i], bfh[j], acc[i][j], 0, 0, 0);
                acc[i][j] = __builtin_amdgcn_mfma_f32_16x16x32_bf16(afh[i], bfh[j], acc[i][j], 0, 0, 0);
            }
        __syncthreads();
    }
    #pragma unroll
    for (int j = 0; j < 4; j++) {
        const int col = bn + wn * 64 + j * 16 + l15;
        const bool cok = (col < Ncap);
        const float bv = (bias && cok) ? bias[col] : 0.f;
        #pragma unroll
        for (int i = 0; i < 4; i++) {
            const int row0 = bm + wm * 64 + i * 16 + lq * 4;
            #pragma unroll
            for (int r = 0; r < 4; r++) {
                float v = acc[i][j][r] + bv;
                if (relu) v = fmaxf(v, 0.f);
                if (cok) C[(size_t)(row0 + r) * ldc + col] = v;
            }
        }
    }
}

static inline void gemmM(hipStream_t s,
                         const float* A1, int lda1, int K1,
                         const float* A2, int lda2, int K2,
                         const u16* Wh, const u16* Wl, int ldwt,
                         const float* bias,
                         float* C, int ldc, int M, int Ngrid, int Ncap, bool relu)
{
    dim3 grid(Ngrid / 128, M / 128);
    gemm_mfma_kernel<<<grid, 256, 0, s>>>(A1, lda1, K1, A2, lda2, K2, Wh, Wl, ldwt,
                                          bias, C, ldc, Ncap, relu ? 1 : 0);
}

// ---------------------------------------------------------------------------
// Fused ec2+msgs GEMM (edge transport): for edge row e,
//   out[e][col] = 2*( (ecomb[e]@Wmsg2)[col] + msg_b[col] )
//                 + Qs[from[e]][col] + Qs[to[e]][col]
// ---------------------------------------------------------------------------
__global__ __launch_bounds__(256) void gemm_ec2msgs_kernel(
    const float* __restrict__ A,
    const u16* __restrict__ Wh, const u16* __restrict__ Wl, int ldwt,
    const float* __restrict__ bias,
    const float* __restrict__ Qs,
    const int* __restrict__ from_idx, const int* __restrict__ to_idx,
    float* __restrict__ M)
{
    __shared__ __align__(16) u16 Ah[128 * TW];
    __shared__ __align__(16) u16 Al[128 * TW];
    __shared__ __align__(16) u16 Bh[128 * TW];
    __shared__ __align__(16) u16 Bl[128 * TW];
    const int tid = threadIdx.x;
    const int lane = tid & 63, wave = tid >> 6;
    const int wm = wave >> 1, wn = wave & 1;
    const int bm = blockIdx.y * 128, bn = blockIdx.x * 128;
    const int srow = tid >> 1;
    const int skoff = (tid & 1) * 16;

    floatx4 acc[4][4];
    #pragma unroll
    for (int i = 0; i < 4; i++)
        #pragma unroll
        for (int j = 0; j < 4; j++) acc[i][j] = (floatx4){0.f, 0.f, 0.f, 0.f};

    const int arow = bm + srow;
    const int brow = bn + srow;
    const int l15 = lane & 15, lq = lane >> 4;

    for (int k0 = 0; k0 < 128; k0 += 32) {
        const int kk = k0 + skoff;
        const float* asrc = A + (size_t)arow * 128 + kk;
        float f[16];
        ((float4*)f)[0] = ((const float4*)asrc)[0];
        ((float4*)f)[1] = ((const float4*)asrc)[1];
        ((float4*)f)[2] = ((const float4*)asrc)[2];
        ((float4*)f)[3] = ((const float4*)asrc)[3];
        u16 ph[16], pl8[16];
        #pragma unroll
        for (int q = 0; q < 16; q++) {
            u16 h = f2bf(f[q]);
            ph[q] = h;
            pl8[q] = f2bf(f[q] - bf2f(h));
        }
        *(uint4*)&Ah[srow * TW + skoff]     = *(const uint4*)&ph[0];
        *(uint4*)&Ah[srow * TW + skoff + 8] = *(const uint4*)&ph[8];
        *(uint4*)&Al[srow * TW + skoff]     = *(const uint4*)&pl8[0];
        *(uint4*)&Al[srow * TW + skoff + 8] = *(const uint4*)&pl8[8];
        const u16* bh = Wh + (size_t)brow * ldwt + kk;
        const u16* bl = Wl + (size_t)brow * ldwt + kk;
        *(uint4*)&Bh[srow * TW + skoff]     = ((const uint4*)bh)[0];
        *(uint4*)&Bh[srow * TW + skoff + 8] = ((const uint4*)bh)[1];
        *(uint4*)&Bl[srow * TW + skoff]     = ((const uint4*)bl)[0];
        *(uint4*)&Bl[srow * TW + skoff + 8] = ((const uint4*)bl)[1];
        __syncthreads();
        short8 afh[4], afl[4], bfh[4], bfl[4];
        #pragma unroll
        for (int i = 0; i < 4; i++) {
            const int ro = (wm * 64 + i * 16 + l15) * TW + lq * 8;
            afh[i] = *(const short8*)&Ah[ro];
            afl[i] = *(const short8*)&Al[ro];
        }
        #pragma unroll
        for (int j = 0; j < 4; j++) {
            const int ro = (wn * 64 + j * 16 + l15) * TW + lq * 8;
            bfh[j] = *(const short8*)&Bh[ro];
            bfl[j] = *(const short8*)&Bl[ro];
        }
        #pragma unroll
        for (int i = 0; i < 4; i++)
            #pragma unroll
            for (int j = 0; j < 4; j++) {
                acc[i][j] = __builtin_amdgcn_mfma_f32_16x16x32_bf16(afh[i], bfl[j], acc[i][j], 0, 0, 0);
                acc[i][j] = __builtin_amdgcn_mfma_f32_16x16x32_bf16(afl[i], bfh[j], acc[i][j], 0, 0, 0);
                acc[i][j] = __builtin_amdgcn_mfma_f32_16x16x32_bf16(afh[i], bfh[j], acc[i][j], 0, 0, 0);
            }
        __syncthreads();
    }
    #pragma unroll
    for (int i = 0; i < 4; i++) {
        #pragma unroll
        for (int r = 0; r < 4; r++) {
            const int row = bm + wm * 64 + i * 16 + lq * 4 + r;
            const int fi = from_idx[row], ti = to_idx[row];
            #pragma unroll
            for (int j = 0; j < 4; j++) {
                const int col = bn + wn * 64 + j * 16 + l15;
                float v = 2.f * (acc[i][j][r] + bias[col])
                        + Qs[(size_t)fi * 256 + col] + Qs[(size_t)ti * 256 + col];
                M[(size_t)row * 256 + col] = v;
            }
        }
    }
}

// ---------------------------------------------------------------------------
// One-shot weight prep (all transposed hi/lo bf16 planes; Wsum inline).
// ---------------------------------------------------------------------------
__global__ __launch_bounds__(256) void prep_kernel(
    const float* __restrict__ niW1, const float* __restrict__ niW2,
    const float* __restrict__ eiW1, const float* __restrict__ eiW2,
    const float* __restrict__ msgW, const float* __restrict__ nuW1,
    const float* __restrict__ nuW2, const float* __restrict__ encnW,
    const float* __restrict__ enceW, const float* __restrict__ nsW1,
    const float* __restrict__ nsW2, const float* __restrict__ esW1,
    const float* __restrict__ esW2,
    u16* __restrict__ WT, u16* __restrict__ WTL)
{
    int idx = blockIdx.x * 256 + threadIdx.x;
    if (idx >= 696320) return;
    const float* src; int base, N, Npad, ldk, noff = 0, wtoff;
    int wsum = 0;
    if      (idx < 65536)  { src = niW1;  base = 0;      N = 256; Npad = 256; ldk = 256; wtoff = 0; }
    else if (idx < 98304)  { src = niW2;  base = 65536;  N = 128; Npad = 128; ldk = 256; wtoff = 65536; }
    else if (idx < 245760) { src = eiW1;  base = 98304;  N = 384; Npad = 384; ldk = 384; wtoff = 98304; }
    else if (idx < 294912) { src = eiW2;  base = 245760; N = 128; Npad = 128; ldk = 384; wtoff = 245760; }
    else if (idx < 393216) { src = msgW;  base = 294912; N = 256; Npad = 256; ldk = 384; wtoff = 294912; }
    else if (idx < 425984) { src = msgW;  base = 393216; N = 256; Npad = 256; ldk = 128; wtoff = 393216; }
    else if (idx < 458752) { src = msgW + 32768; base = 425984; N = 256; Npad = 256; ldk = 128; noff = 256; wtoff = 393216; }
    else if (idx < 557056) { src = nuW1;  base = 458752; N = 256; Npad = 256; ldk = 384; wtoff = 458752; }
    else if (idx < 589824) { src = nuW2;  base = 557056; N = 128; Npad = 128; ldk = 256; wtoff = 557056; }
    else if (idx < 622592) { src = msgW;  base = 589824; N = 256; Npad = 256; ldk = 128; wtoff = 589824; wsum = 1; }
    else if (idx < 626688) { src = encnW; base = 622592; N = 128; Npad = 128; ldk = 32;  wtoff = 622592; }
    else if (idx < 630784) { src = enceW; base = 626688; N = 128; Npad = 128; ldk = 32;  wtoff = 626688; }
    else if (idx < 647168) { src = nsW1;  base = 630784; N = 64;  Npad = 128; ldk = 128; wtoff = 630784; }
    else if (idx < 655360) { src = nsW2;  base = 647168; N = 64;  Npad = 128; ldk = 64;  wtoff = 647168; }
    else if (idx < 688128) { src = esW1;  base = 655360; N = 64;  Npad = 128; ldk = 256; wtoff = 655360; }
    else                   { src = esW2;  base = 688128; N = 64;  Npad = 128; ldk = 64;  wtoff = 688128; }
    int rel = idx - base;
    int k = rel / Npad, n = rel % Npad;
    float v = 0.f;
    if (n < N) {
        v = src[(size_t)k * N + n];
        if (wsum) v += src[32768 + (size_t)k * N + n];
    }
    u16 h = f2bf(v);
    size_t o = (size_t)wtoff + (size_t)(noff + n) * ldk + k;
    WT[o] = h;
    WTL[o] = f2bf(v - bf2f(h));
}

// ---------------------------------------------------------------------------
// Dual batched MFMA plan-GEMM: qi (transp=0) + ci (transp=1) in one launch.
// ---------------------------------------------------------------------------
__global__ __launch_bounds__(256) void bgemm_dual_kernel(
    const float* __restrict__ P, int ms, int n_per,
    const float* __restrict__ U, int ldu,
    float* __restrict__ C, int ldc, int nxh)
{
    __shared__ __align__(16) u16 Ah[64 * TW];
    __shared__ __align__(16) u16 Al[64 * TW];
    __shared__ __align__(16) u16 Bh[128 * TW];
    __shared__ __align__(16) u16 Bl[128 * TW];
    const int b = blockIdx.z;
    const float* Pb = P + (size_t)b * ms * ms;
    const int bxr = blockIdx.x;
    const int transp = (bxr >= nxh) ? 1 : 0;
    const int bn = (bxr - transp * nxh) * 128;
    const int qbase = (2 * b) * n_per, cbase = (2 * b + 1) * n_per;
    const int obase = transp ? cbase : qbase;
    const int ibase = transp ? qbase : cbase;
    const int bm = blockIdx.y * 64;
    const int tid = threadIdx.x, lane = tid & 63, wave = tid >> 6;
    const int wm = wave >> 1, wn = wave & 1;
    const int l15 = lane & 15, lq = lane >> 4;
    const int sar = tid >> 2, sak = (tid & 3) * 8;
    const int sbn = tid >> 1, sbk = (tid & 1) * 16;
    const int Kpad = (n_per + 31) & ~31;

    floatx4 acc[2][4];
    #pragma unroll
    for (int i = 0; i < 2; i++)
        #pragma unroll
        for (int j = 0; j < 4; j++) acc[i][j] = (floatx4){0.f, 0.f, 0.f, 0.f};

    for (int k0 = 0; k0 < Kpad; k0 += 32) {
        {
            u16 ph[8], pl8[8];
            const int m = bm + sar;
            #pragma unroll
            for (int i = 0; i < 8; i++) {
                int kk = k0 + sak + i;
                float v = 0.f;
                if (kk < n_per && m < n_per)
                    v = transp ? Pb[(size_t)kk * ms + m] : Pb[(size_t)m * ms + kk];
                u16 h = f2bf(v);
                ph[i] = h; pl8[i] = f2bf(v - bf2f(h));
            }
            *(uint4*)&Ah[sar * TW + sak] = *(const uint4*)&ph[0];
            *(uint4*)&Al[sar * TW + sak] = *(const uint4*)&pl8[0];
        }
        {
            u16 qh[16], ql[16];
            #pragma unroll
            for (int i = 0; i < 16; i++) {
                int kk = k0 + sbk + i;
                float v = 0.f;
                if (kk < n_per) v = U[(size_t)(ibase + kk) * ldu + bn + sbn];
                u16 h = f2bf(v);
                qh[i] = h; ql[i] = f2bf(v - bf2f(h));
            }
            *(uint4*)&Bh[sbn * TW + sbk]     = *(const uint4*)&qh[0];
            *(uint4*)&Bh[sbn * TW + sbk + 8] = *(const uint4*)&qh[8];
            *(uint4*)&Bl[sbn * TW + sbk]     = *(const uint4*)&ql[0];
            *(uint4*)&Bl[sbn * TW + sbk + 8] = *(const uint4*)&ql[8];
        }
        __syncthreads();
        short8 afh[2], afl[2], bfh[4], bfl[4];
        #pragma unroll
        for (int i = 0; i < 2; i++) {
            const int ro = (wm * 32 + i * 16 + l15) * TW + lq * 8;
            afh[i] = *(const short8*)&Ah[ro];
            afl[i] = *(const short8*)&Al[ro];
        }
        #pragma unroll
        for (int j = 0; j < 4; j++) {
            const int ro = (wn * 64 + j * 16 + l15) * TW + lq * 8;
            bfh[j] = *(const short8*)&Bh[ro];
            bfl[j] = *(const short8*)&Bl[ro];
        }
        #pragma unroll
        for (int i = 0; i < 2; i++)
            #pragma unroll
            for (int j = 0; j < 4; j++) {
                acc[i][j] = __builtin_amdgcn_mfma_f32_16x16x32_bf16(afh[i], bfl[j], acc[i][j], 0, 0, 0);
                acc[i][j] = __builtin_amdgcn_mfma_f32_16x16x32_bf16(afl[i], bfh[j], acc[i][j], 0, 0, 0);
                acc[i][j] = __builtin_amdgcn_mfma_f32_16x16x32_bf16(afh[i], bfh[j], acc[i][j], 0, 0, 0);
            }
        __syncthreads();
    }
    #pragma unroll
    for (int j = 0; j < 4; j++) {
        const int col = bn + wn * 64 + j * 16 + l15;
        #pragma unroll
        for (int i = 0; i < 2; i++) {
            const int row0 = bm + wm * 32 + i * 16 + lq * 4;
            #pragma unroll
            for (int r = 0; r < 4; r++) {
                const int m = row0 + r;
                if (m < n_per)
                    C[(size_t)(obase + m) * ldc + col] = acc[i][j][r];
            }
        }
    }
}

static inline void bgemmDual(hipStream_t s, const float* P, int ms, int n_per,
                             const float* U, int ldu, float* C, int ldc, int N)
{
    int nxh = N / 128;
    dim3 grid(nxh * 2, (n_per + 63) / 64, Bb);
    bgemm_dual_kernel<<<grid, 256, 0, s>>>(P, ms, n_per, U, ldu, C, ldc, nxh);
}

// ---------------------------------------------------------------------------
// Fused node transport: la (64x64) + 10 Sinkhorn iters (potential form) +
// plan=exp write. 4 waves; wave w owns rows 16w..16w+15; lane owns a col.
// ---------------------------------------------------------------------------
__global__ __launch_bounds__(256) void la_sinkhorn64_kernel(
    const float* __restrict__ tt, float* __restrict__ n_la)
{
    const int b = blockIdx.x;
    __shared__ float Aq[64][65];
    __shared__ float Ac[64][65];
    __shared__ float m[64][65];
    __shared__ float v_s[64];
    __shared__ float part[4][64];
    const int tid = threadIdx.x;
    const int lane = tid & 63, w = tid >> 6;
    for (int idx = tid; idx < 4096; idx += 256) {
        int r = idx >> 6, s = idx & 63;
        float vq = 0.f, vc = 0.f;
        if (r < Nn) {
            vq = tt[((size_t)(2 * b) * Nn + r) * Sdim + s];
            vc = tt[((size_t)(2 * b + 1) * Nn + r) * Sdim + s];
        }
        Aq[r][s] = vq;
        Ac[r][s] = vc;
    }
    __syncthreads();
    {
        const int tx = tid & 15, ty = tid >> 4;
        float acc[4][4] = {};
        for (int s = 0; s < 64; s++) {
            float a[4], c[4];
            #pragma unroll
            for (int i = 0; i < 4; i++) a[i] = Aq[ty * 4 + i][s];
            #pragma unroll
            for (int j = 0; j < 4; j++) c[j] = Ac[tx * 4 + j][s];
            #pragma unroll
            for (int i = 0; i < 4; i++)
                #pragma unroll
                for (int j = 0; j < 4; j++)
                    acc[i][j] = fmaf(a[i], c[j], acc[i][j]);
        }
        #pragma unroll
        for (int i = 0; i < 4; i++)
            #pragma unroll
            for (int j = 0; j < 4; j++)
                m[ty * 4 + i][tx * 4 + j] = acc[i][j] * INV_TEMP;
    }
    if (tid < 64) v_s[tid] = 0.f;
    __syncthreads();
    float x[16], u[16];
    #pragma unroll
    for (int j = 0; j < 16; j++) x[j] = m[w * 16 + j][lane];
    #pragma unroll
    for (int j = 0; j < 16; j++) {
        float mx = x[j];
        #pragma unroll
        for (int d = 1; d < 64; d <<= 1) mx = fmaxf(mx, __shfl_xor(mx, d));
        u[j] = mx;
    }
    for (int it = 0; it < 10; it++) {
        float vr = v_s[lane];
        #pragma unroll
        for (int j = 0; j < 16; j++) {
            float s = __expf(x[j] - vr - u[j]);
            #pragma unroll
            for (int d = 1; d < 64; d <<= 1) s += __shfl_xor(s, d);
            u[j] += __logf(s);
        }
        float s = 0.f;
        #pragma unroll
        for (int j = 0; j < 16; j++) s += __expf(x[j] - u[j] - vr);
        part[w][lane] = s;
        __syncthreads();
        if (tid < 64) {
            float ss = part[0][tid] + part[1][tid] + part[2][tid] + part[3][tid];
            v_s[tid] += __logf(ss);
        }
        __syncthreads();
    }
    float vr = v_s[lane];
    float* g = n_la + (size_t)b * 4096;
    #pragma unroll
    for (int j = 0; j < 16; j++)
        g[(size_t)(w * 16 + j) * 64 + lane] = __expf(x[j] - u[j] - vr);
}

// la for edges (256x256): la[b][q][c] = 10 * tq[q]·tc[c], fp32 ttreal guarded.
__global__ __launch_bounds__(256) void la_gemm256_kernel(
    const float* __restrict__ tt, float* __restrict__ la)
{
    const int b = blockIdx.z;
    const int bm = blockIdx.y * 64, bn = blockIdx.x * 64;
    __shared__ float Aq[64][65];
    __shared__ float Ac[64][65];
    const int tid = threadIdx.x;
    for (int idx = tid; idx < 4096; idx += 256) {
        int r = idx >> 6, s = idx & 63;
        float vq = 0.f, vc = 0.f;
        int qr = bm + r, cr = bn + r;
        if (qr < Ee) vq = tt[((size_t)(2 * b) * Ee + qr) * Sdim + s];
        if (cr < Ee) vc = tt[((size_t)(2 * b + 1) * Ee + cr) * Sdim + s];
        Aq[r][s] = vq;
        Ac[r][s] = vc;
    }
    __syncthreads();
    const int tx = tid & 15, ty = tid >> 4;
    float acc[4][4] = {};
    for (int s = 0; s < 64; s++) {
        float a[4], c[4];
        #pragma unroll
        for (int i = 0; i < 4; i++) a[i] = Aq[ty * 4 + i][s];
        #pragma unroll
        for (int j = 0; j < 4; j++) c[j] = Ac[tx * 4 + j][s];
        #pragma unroll
        for (int i = 0; i < 4; i++)
            #pragma unroll
            for (int j = 0; j < 4; j++)
                acc[i][j] = fmaf(a[i], c[j], acc[i][j]);
    }
    #pragma unroll
    for (int i = 0; i < 4; i++)
        #pragma unroll
        for (int j = 0; j < 4; j++)
            la[((size_t)b * 256 + bm + ty * 4 + i) * 256 + bn + tx * 4 + j] = acc[i][j] * INV_TEMP;
}

// ---------------------------------------------------------------------------
// Sinkhorn 256x256, single-pass streaming form (fits 64 VGPRs, no spills).
// Identity: with e_j = exp(x_j - v - u_old_j), s_j = sum(e_j):
//   u_new_j = u_old_j + log(s_j)  and  exp(x_j - u_new_j - v) = e_j / s_j,
// so the column partial reuses the row-pass exponentials -> ONE x-read per
// iteration, streamed from (per-XCD resident) L2. Wave w owns rows
// 16w..16w+15; lane owns cols 4*lane..4*lane+3 (coalesced float4 row reads).
// ---------------------------------------------------------------------------
__global__ __launch_bounds__(1024) void sinkhorn256_kernel(float* __restrict__ la)
{
    const int b = blockIdx.x;
    float* g = la + (size_t)b * 65536;
    const int tid = threadIdx.x;
    const int lane = tid & 63, w = tid >> 6;
    __shared__ float v_s[256];
    __shared__ float part[16][64][5];  // [wave][lane][q], stride-5 pad

    float u[16];
    // init: u[j] = rowmax(x)
    #pragma unroll
    for (int j = 0; j < 16; j++) {
        float4 xv = ((const float4*)(g + (size_t)(w * 16 + j) * 256))[lane];
        float mx = fmaxf(fmaxf(xv.x, xv.y), fmaxf(xv.z, xv.w));
        #pragma unroll
        for (int d = 1; d < 64; d <<= 1) mx = fmaxf(mx, __shfl_xor(mx, d));
        u[j] = mx;
    }
    if (tid < 256) v_s[tid] = 0.f;
    __syncthreads();

    for (int it = 0; it < 10; it++) {
        const float4 vr = *(const float4*)&v_s[4 * lane];
        float cp0 = 0.f, cp1 = 0.f, cp2 = 0.f, cp3 = 0.f;
        #pragma unroll
        for (int j = 0; j < 16; j++) {
            float4 xv = ((const float4*)(g + (size_t)(w * 16 + j) * 256))[lane];
            float e0 = __expf(xv.x - vr.x - u[j]);
            float e1 = __expf(xv.y - vr.y - u[j]);
            float e2 = __expf(xv.z - vr.z - u[j]);
            float e3 = __expf(xv.w - vr.w - u[j]);
            float s = e0 + e1 + e2 + e3;
            #pragma unroll
            for (int d = 1; d < 64; d <<= 1) s += __shfl_xor(s, d);
            u[j] += __logf(s);
            const float inv = 1.f / s;
            cp0 = fmaf(e0, inv, cp0);
            cp1 = fmaf(e1, inv, cp1);
            cp2 = fmaf(e2, inv, cp2);
            cp3 = fmaf(e3, inv, cp3);
        }
        *(float4*)&part[w][lane][0] = (float4){cp0, cp1, cp2, cp3};
        __syncthreads();
        if (tid < 256) {
            const int cl = tid >> 2, cq = tid & 3;
            float ss = 0.f;
            #pragma unroll
            for (int w2 = 0; w2 < 16; w2++) ss += part[w2][cl][cq];
            v_s[tid] += __logf(ss);
        }
        __syncthreads();
    }
    // plan = exp(x - u - v_final)
    const float4 vr = *(const float4*)&v_s[4 * lane];
    #pragma unroll
    for (int j = 0; j < 16; j++) {
        float4* rp = (float4*)(g + (size_t)(w * 16 + j) * 256) + lane;
        float4 xv = *rp;
        float4 o;
        o.x = __expf(xv.x - u[j] - vr.x);
        o.y = __expf(xv.y - u[j] - vr.y);
        o.z = __expf(xv.z - u[j] - vr.z);
        o.w = __expf(xv.w - u[j] - vr.w);
        *rp = o;
    }
}

// ---------------------------------------------------------------------------
// Group-local message aggregation; P0/P1 packed in P01 (ld 512), fp32.
// ---------------------------------------------------------------------------
__global__ __launch_bounds__(256) void agg_kernel(
    const float* __restrict__ P01,
    const float* __restrict__ ec2,
    const int* __restrict__ from_idx, const int* __restrict__ to_idx,
    float* __restrict__ agg)
{
    const int gblk = blockIdx.x;
    const int d = threadIdx.x;
    __shared__ float acc[48][256];
    __shared__ int fr[192], to[192];
    #pragma unroll
    for (int n = 0; n < 48; n++) acc[n][d] = 0.f;
    if (d < 192) {
        fr[d] = from_idx[gblk * 192 + d] - gblk * 48;
        to[d] = to_idx[gblk * 192 + d] - gblk * 48;
    }
    __syncthreads();
    const int nb = gblk * 48;
    const int eb = gblk * 192;
    for (int e = 0; e < 192; e++) {
        int f = fr[e], t = to[e];
        float ee  = ec2[(size_t)(eb + e) * 256 + d];
        float p0f = P01[(size_t)(nb + f) * 512 + d];
        float p1f = P01[(size_t)(nb + f) * 512 + 256 + d];
        float p0t = P01[(size_t)(nb + t) * 512 + d];
        float p1t = P01[(size_t)(nb + t) * 512 + 256 + d];
        acc[t][d] += p0f + p1t + ee;
        acc[f][d] += p0t + p1f + ee;
    }
    __syncthreads();
    for (int n = 0; n < 48; n++) agg[(size_t)(nb + n) * 256 + d] = acc[n][d];
}

// In-place messages: m[e] <- Qs[from]+Qs[to]+2*m[e]  (used only for slot 5)
__global__ __launch_bounds__(256) void msgs_inplace_kernel(
    float* __restrict__ m, const float* __restrict__ Qs,
    const int* __restrict__ from_idx, const int* __restrict__ to_idx)
{
    const int e = blockIdx.x;
    const int d = threadIdx.x;
    const int f = from_idx[e], t = to_idx[e];
    size_t o = (size_t)e * 256 + d;
    m[o] = Qs[(size_t)f * 256 + d] + Qs[(size_t)t * 256 + d] + 2.f * m[o];
}

__global__ void diag_kernel(float* __restrict__ out, float v)
{
    out[threadIdx.x] = v;
}

// score[b] = -sum relu( ffq - plan@ffc )
__global__ __launch_bounds__(128) void score_kernel(
    const float* __restrict__ upd_node, const float* __restrict__ plan,
    float* __restrict__ out)
{
    const int b = blockIdx.x;
    const int tid = threadIdx.x;
    __shared__ float ffc[48][128];
    __shared__ float pl[64][48];
    __shared__ float red[128];
    for (int c = 0; c < 48; c++)
        ffc[c][tid] = upd_node[(size_t)((2 * b + 1) * 48 + c) * 640 + 512 + tid];
    for (int idx = tid; idx < 64 * 48; idx += 128) {
        int q = idx / 48, c = idx % 48;
        pl[q][c] = plan[(size_t)b * 4096 + q * 64 + c];
    }
    __syncthreads();
    float accv = 0.f;
    for (int q = 0; q < 64; q++) {
        float rsum = 0.f;
        #pragma unroll 8
        for (int c = 0; c < 48; c++) rsum = fmaf(pl[q][c], ffc[c][tid], rsum);
        float fq = 0.f;
        if (q < 48) fq = upd_node[(size_t)((2 * b) * 48 + q) * 640 + 512 + tid];
        accv += fmaxf(fq - rsum, 0.f);
    }
    red[tid] = accv;
    __syncthreads();
    for (int sft = 64; sft > 0; sft >>= 1) {
        if (tid < sft) red[tid] += red[tid + sft];
        __syncthreads();
    }
    if (tid == 0) out[b] = -red[0];
}

// ---------------------------------------------------------------------------
// Workspace layout (floats). Total 66,265,088 floats = 265.1 MB <= 268.4 MB.
// ---------------------------------------------------------------------------
#define OFF_UPD_NODE   0ULL
#define OFF_NODE_STORE 3932160ULL
#define OFF_EDGE_STORE 7077888ULL
#define OFF_ECOMB      32243712ULL
#define OFF_ENC_N      47972352ULL
#define OFF_ENC_E      48758784ULL
#define OFF_N_LA       51904512ULL
#define OFF_WT         52199424ULL
#define OFF_WTL        52547584ULL
#define OFF_ARENA      52895744ULL
#define TOTAL_FLOATS   66265088ULL

// bf16 weight sub-offsets (u16 from WT/WTL base)
#define WT_NIW1   0
#define WT_NIW2   65536
#define WT_EIW1   98304
#define WT_EIW2   245760
#define WT_MSG    294912
#define WT_P01    393216
#define WT_NUW1   458752
#define WT_NUW2   557056
#define WT_WSUM   589824
#define WT_ENCN   622592
#define WT_ENCE   626688
#define WT_NS1    630784
#define WT_NS2    647168
#define WT_ES1    655360
#define WT_ES2    688128

extern "C" void kernel_launch(void* const* d_in, const int* in_sizes, int n_in,
                              void* d_out, int out_size, void* d_ws, size_t ws_size,
                              hipStream_t stream)
{
    (void)in_sizes; (void)n_in; (void)out_size;
    if (ws_size < TOTAL_FLOATS * sizeof(float)) {
        diag_kernel<<<1, 64, 0, stream>>>((float*)d_out, (float)ws_size);
        return;
    }

    const float* node_features = (const float*)d_in[0];
    const float* edge_features = (const float*)d_in[1];
    const int*   from_idx      = (const int*)d_in[2];
    const int*   to_idx        = (const int*)d_in[3];
    const float* enc_node_W = (const float*)d_in[4];
    const float* enc_node_b = (const float*)d_in[5];
    const float* enc_edge_W = (const float*)d_in[6];
    const float* enc_edge_b = (const float*)d_in[7];
    const float* ni_W1 = (const float*)d_in[8];
    const float* ni_b1 = (const float*)d_in[9];
    const float* ni_W2 = (const float*)d_in[10];
    const float* ni_b2 = (const float*)d_in[11];
    const float* ei_W1 = (const float*)d_in[12];
    const float* ei_b1 = (const float*)d_in[13];
    const float* ei_W2 = (const float*)d_in[14];
    const float* ei_b2 = (const float*)d_in[15];
    const float* msg_W = (const float*)d_in[16];
    const float* msg_b = (const float*)d_in[17];
    const float* nu_W1 = (const float*)d_in[18];
    const float* nu_b1 = (const float*)d_in[19];
    const float* nu_W2 = (const float*)d_in[20];
    const float* nu_b2 = (const float*)d_in[21];
    const float* ns_W1 = (const float*)d_in[22];
    const float* ns_b1 = (const float*)d_in[23];
    const float* ns_W2 = (const float*)d_in[24];
    const float* ns_b2 = (const float*)d_in[25];
    const float* es_W1 = (const float*)d_in[26];
    const float* es_b1 = (const float*)d_in[27];
    const float* es_W2 = (const float*)d_in[28];
    const float* es_b2 = (const float*)d_in[29];

    float* ws = (float*)d_ws;
    float* upd_node   = ws + OFF_UPD_NODE;
    float* node_store = ws + OFF_NODE_STORE;
    float* edge_store = ws + OFF_EDGE_STORE;
    float* ecomb      = ws + OFF_ECOMB;
    float* enc_n      = ws + OFF_ENC_N;
    float* enc_e      = ws + OFF_ENC_E;
    float* n_la       = ws + OFF_N_LA;
    u16* WT  = (u16*)(ws + OFF_WT);
    u16* WTL = (u16*)(ws + OFF_WTL);
    float* arena      = ws + OFF_ARENA;

    // Phase-A arena carve
    float* A_hidden = arena;                  // [0, 1.57M)   VN x 256
    float* A_hcomb  = arena + 1572864;        // [1.57, 2.36M) VN x 128
    float* A_ehid   = arena + 2359296;        // [2.36, 11.80M) VE x 384
    float* A_ec2    = arena + 2359296;        // [2.36, 8.65M) VE x 256 (alias)
    float* A_P01    = arena + 8650752;        // [8.65, 11.80M) VN x 512
    float* A_aggb   = arena + 11796480;       // [11.80, 13.37M) VN x 256
    // Phase-B carve (ordering-checked against A_ec2 liveness)
    float* B_Qs       = arena;                // VN x 256
    float* B_thid_e   = arena + 8650752;      // VE x 64
    float* B_ttreal_e = arena + 10223616;     // VE x 64
    float* B_ela      = arena + 2359296;      // 64 x 256 x 256
    float* B_msgs     = arena + 6553600;      // VE x 256
    float* B_thid_n   = arena + 12058624;     // VN x 64
    float* B_ttreal_n = arena + 12451840;     // VN x 64

    // --- one-shot weight prep ---
    prep_kernel<<<(696320 + 255) / 256, 256, 0, stream>>>(
        ni_W1, ni_W2, ei_W1, ei_W2, msg_W, nu_W1, nu_W2,
        enc_node_W, enc_edge_W, ns_W1, ns_W2, es_W1, es_W2, WT, WTL);

    // --- encoders ---
    gemmM(stream, node_features, 32, 32, nullptr, 0, 0, WT + WT_ENCN, WTL + WT_ENCN, 32,
          enc_node_b, enc_n, 128, VNn, 128, 128, false);
    gemmM(stream, edge_features, 32, 32, nullptr, 0, 0, WT + WT_ENCE, WTL + WT_ENCE, 32,
          enc_edge_b, enc_e, 128, VEe, 128, 128, false);

    for (int k = 0; k < 3; k++) {
        if (k == 0) {
            // edge_store == 0 for ALL p at k=0 -> shared e_comb/ec2, once.
            gemmM(stream, enc_e, 128, 128, nullptr, 0, 0,
                  WT + WT_EIW1, WTL + WT_EIW1, 384, ei_b1,
                  A_ehid, 384, VEe, 384, 384, true);
            gemmM(stream, A_ehid, 384, 384, nullptr, 0, 0, WT + WT_EIW2, WTL + WT_EIW2, 384,
                  ei_b2, ecomb, 128, VEe, 128, 128, false);
            gemmM(stream, ecomb, 128, 128, nullptr, 0, 0,
                  WT + WT_MSG + 256, WTL + WT_MSG + 256, 384,
                  msg_b, A_ec2, 256, VEe, 256, 256, false);
        }
        for (int p = 1; p <= 5; p++) {
            const bool hs = (k > 0) && (p > 1);
            // h_comb = mlp2([h, node_store slot p-1], ni)
            if (p == 1)
                gemmM(stream, enc_n, 128, 128,
                      hs ? node_store + (size_t)(p - 2) * 128 : nullptr, 512, hs ? 128 : 0,
                      WT + WT_NIW1, WTL + WT_NIW1, 256, ni_b1,
                      A_hidden, 256, VNn, 256, 256, true);
            else
                gemmM(stream, upd_node + (size_t)(p - 2) * 128, 640, 128,
                      hs ? node_store + (size_t)(p - 2) * 128 : nullptr, 512, hs ? 128 : 0,
                      WT + WT_NIW1, WTL + WT_NIW1, 256, ni_b1,
                      A_hidden, 256, VNn, 256, 256, true);
            gemmM(stream, A_hidden, 256, 256, nullptr, 0, 0, WT + WT_NIW2, WTL + WT_NIW2, 256,
                  ni_b2, A_hcomb, 128, VNn, 128, 128, false);
            if (k > 0) {
                if (p == 1) {
                    // store slot 0 == 0 -> e_comb == ECOMB slot 0 (valid);
                    // only refresh ec2 into A_ec2.
                    gemmM(stream, ecomb, 128, 128, nullptr, 0, 0,
                          WT + WT_MSG + 256, WTL + WT_MSG + 256, 384,
                          msg_b, A_ec2, 256, VEe, 256, 256, false);
                } else {
                    float* ec_slot = ecomb + (size_t)(p - 1) * VEe * 128;
                    gemmM(stream, enc_e, 128, 128,
                          edge_store + (size_t)(p - 2) * 256, 1024, 256,
                          WT + WT_EIW1, WTL + WT_EIW1, 384, ei_b1,
                          A_ehid, 384, VEe, 384, 384, true);
                    gemmM(stream, A_ehid, 384, 384, nullptr, 0, 0,
                          WT + WT_EIW2, WTL + WT_EIW2, 384,
                          ei_b2, ec_slot, 128, VEe, 128, 128, false);
                    gemmM(stream, ec_slot, 128, 128, nullptr, 0, 0,
                          WT + WT_MSG + 256, WTL + WT_MSG + 256, 384,
                          msg_b, A_ec2, 256, VEe, 256, 256, false);
                }
            }
            // P01 = h_comb @ [W0|W1]
            gemmM(stream, A_hcomb, 128, 128, nullptr, 0, 0, WT + WT_P01, WTL + WT_P01, 128,
                  nullptr, A_P01, 512, VNn, 512, 512, false);
            agg_kernel<<<NGg, 256, 0, stream>>>(A_P01, A_ec2, from_idx, to_idx, A_aggb);
            // h = mlp2([h_comb, agg], nu) -> upd_node slot p
            gemmM(stream, A_hcomb, 128, 128, A_aggb, 256, 256, WT + WT_NUW1, WTL + WT_NUW1, 384,
                  nu_b1, A_hidden, 256, VNn, 256, 256, true);
            gemmM(stream, A_hidden, 256, 256, nullptr, 0, 0, WT + WT_NUW2, WTL + WT_NUW2, 256,
                  nu_b2, upd_node + (size_t)(p - 1) * 128, 640, VNn, 128, 128, false);
        }
        // ---- node transport (fused la + sinkhorn) ----
        gemmM(stream, upd_node + 512, 640, 128, nullptr, 0, 0, WT + WT_NS1, WTL + WT_NS1, 128,
              ns_b1, B_thid_n, 64, VNn, 128, 64, true);
        gemmM(stream, B_thid_n, 64, 64, nullptr, 0, 0, WT + WT_NS2, WTL + WT_NS2, 64,
              ns_b2, B_ttreal_n, 64, VNn, 128, 64, false);
        la_sinkhorn64_kernel<<<Bb, 256, 0, stream>>>(B_ttreal_n, n_la);
        if (k < 2) {
            bgemmDual(stream, n_la, 64, 48, upd_node, 640, node_store, 512, 512);
            // ---- edge transport ----
            // slot 5: A_ec2 already holds slot-5's ec2. msgs in place.
            gemmM(stream, upd_node + 512, 640, 128, nullptr, 0, 0,
                  WT + WT_WSUM, WTL + WT_WSUM, 128,
                  nullptr, B_Qs, 256, VNn, 256, 256, false);
            msgs_inplace_kernel<<<VEe, 256, 0, stream>>>(A_ec2, B_Qs, from_idx, to_idx);
            gemmM(stream, A_ec2, 256, 256, nullptr, 0, 0, WT + WT_ES1, WTL + WT_ES1, 256,
                  es_b1, B_thid_e, 64, VEe, 128, 64, true);
            gemmM(stream, B_thid_e, 64, 64, nullptr, 0, 0, WT + WT_ES2, WTL + WT_ES2, 64,
                  es_b2, B_ttreal_e, 64, VEe, 128, 64, false);
            la_gemm256_kernel<<<dim3(4, 4, Bb), 256, 0, stream>>>(B_ttreal_e, B_ela);
            sinkhorn256_kernel<<<Bb, 1024, 0, stream>>>(B_ela);
            for (int sl = 1; sl <= 4; sl++) {
                const size_t ss = (k == 0) ? 0 : (size_t)(sl - 1);
                gemmM(stream, upd_node + (size_t)(sl - 1) * 128, 640, 128, nullptr, 0, 0,
                      WT + WT_WSUM, WTL + WT_WSUM, 128,
                      nullptr, B_Qs, 256, VNn, 256, 256, false);
                // fused: msgs = 2*(ecomb_ss @ Wmsg2 + msg_b) + Qs[f] + Qs[t]
                gemm_ec2msgs_kernel<<<dim3(2, VEe / 128), 256, 0, stream>>>(
                    ecomb + ss * VEe * 128,
                    WT + WT_MSG + 256, WTL + WT_MSG + 256, 384,
                    msg_b, B_Qs, from_idx, to_idx, B_msgs);
                bgemmDual(stream, B_ela, 256, 192, B_msgs, 256,
                          edge_store + (size_t)(sl - 1) * 256, 1024, 256);
            }
        }
    }
    score_kernel<<<Bb, 128, 0, stream>>>(upd_node, n_la, (float*)d_out);
}